// Round 2
// baseline (990.635 us; speedup 1.0000x reference)
//
#include <hip/hip_runtime.h>
#include <math.h>

// ================= Threefry-2x32 (JAX-compatible) =================
// Random123 KAT: tf2x32(0,0,0,0) -> (0x6b200159, 0x99ba4efe)
__host__ __device__ __forceinline__ unsigned rotl32(unsigned v, int d){
  return (v << d) | (v >> (32 - d));
}

__host__ __device__ __forceinline__ void tf2x32(unsigned k0, unsigned k1,
                                                unsigned c0, unsigned c1,
                                                unsigned &o0, unsigned &o1)
{
  unsigned ks2 = k0 ^ k1 ^ 0x1BD11BDAu;
  unsigned x0 = c0 + k0, x1 = c1 + k1;
#define TFR(r) x0 += x1; x1 = rotl32(x1, r); x1 ^= x0;
  TFR(13) TFR(15) TFR(26) TFR(6)
  x0 += k1;  x1 += ks2 + 1u;
  TFR(17) TFR(29) TFR(16) TFR(24)
  x0 += ks2; x1 += k0 + 2u;
  TFR(13) TFR(15) TFR(26) TFR(6)
  x0 += k0;  x1 += k1 + 3u;
  TFR(17) TFR(29) TFR(16) TFR(24)
  x0 += k1;  x1 += ks2 + 4u;
  TFR(13) TFR(15) TFR(26) TFR(6)
  x0 += ks2; x1 += k0 + 5u;
#undef TFR
  o0 = x0; o1 = x1;
}

// PRNG mode: 1 = jax_threefry_partitionable=True (JAX >= 0.5 default).
// Partitionable random_bits for bit_width<=32 returns bits1 ^ bits2 (XOR of
// both threefry output words) — jax/_src/prng.py _threefry_random_bits_partitionable.
// If bench fails with absmax O(10) and all-else-correct, flip to 0 (legacy).
#define PRNG_PART 1

// ================= CSR build =================
__global__ __launch_bounds__(256) void k_count(const int* __restrict__ dst,
                                               int* __restrict__ cnt, int E)
{
  int e = blockIdx.x * 256 + threadIdx.x;
  if (e < E) atomicAdd(&cnt[dst[e]], 1);
}

__global__ __launch_bounds__(256) void k_dinv(const int* __restrict__ cnt,
                                              float* __restrict__ dinv, int N)
{
  int v = blockIdx.x * 256 + threadIdx.x;
  if (v < N) dinv[v] = rsqrtf((float)cnt[v] + 1.0f);
}

__global__ __launch_bounds__(256) void k_blocksum(const int* __restrict__ cnt,
                                                  int* __restrict__ bsum, int N)
{
  __shared__ int sh[256];
  int t = threadIdx.x;
  int base = blockIdx.x * 1024 + t * 4;
  int s = 0;
  #pragma unroll
  for (int j = 0; j < 4; j++){ int i = base + j; if (i < N) s += cnt[i]; }
  sh[t] = s; __syncthreads();
  for (int off = 128; off; off >>= 1){
    if (t < off) sh[t] += sh[t + off];
    __syncthreads();
  }
  if (t == 0) bsum[blockIdx.x] = sh[0];
}

__global__ __launch_bounds__(256) void k_scansums(const int* __restrict__ bsum,
                                                  int* __restrict__ boff,
                                                  int* __restrict__ rowstart,
                                                  int NB, int N)
{
  __shared__ int sh[256];
  int t = threadIdx.x;
  int v = (t < NB) ? bsum[t] : 0;
  sh[t] = v; __syncthreads();
  for (int off = 1; off < 256; off <<= 1){
    int x = sh[t];
    int y = (t >= off) ? sh[t - off] : 0;
    __syncthreads();
    sh[t] = x + y;
    __syncthreads();
  }
  if (t < NB) boff[t] = sh[t] - v;          // exclusive prefix
  if (t == NB - 1) rowstart[N] = sh[t];     // total (= E)
}

__global__ __launch_bounds__(256) void k_scanfinal(const int* __restrict__ cnt,
                                                   const int* __restrict__ boff,
                                                   int* __restrict__ rowstart, int N)
{
  __shared__ int sh[256];
  int t = threadIdx.x;
  int base = blockIdx.x * 1024 + t * 4;
  int c0 = 0, c1 = 0, c2 = 0, c3 = 0;
  if (base + 0 < N) c0 = cnt[base + 0];
  if (base + 1 < N) c1 = cnt[base + 1];
  if (base + 2 < N) c2 = cnt[base + 2];
  if (base + 3 < N) c3 = cnt[base + 3];
  int s = c0 + c1 + c2 + c3;
  sh[t] = s; __syncthreads();
  for (int off = 1; off < 256; off <<= 1){
    int x = sh[t];
    int y = (t >= off) ? sh[t - off] : 0;
    __syncthreads();
    sh[t] = x + y;
    __syncthreads();
  }
  int excl = sh[t] - s + boff[blockIdx.x];
  if (base + 0 < N) rowstart[base + 0] = excl;
  if (base + 1 < N) rowstart[base + 1] = excl + c0;
  if (base + 2 < N) rowstart[base + 2] = excl + c0 + c1;
  if (base + 3 < N) rowstart[base + 3] = excl + c0 + c1 + c2;
}

__global__ __launch_bounds__(256) void k_fill(const int* __restrict__ src,
                                              const int* __restrict__ dst,
                                              const int* __restrict__ rowstart,
                                              int* __restrict__ cursor,
                                              int* __restrict__ csr, int E)
{
  int e = blockIdx.x * 256 + threadIdx.x;
  if (e >= E) return;
  int d = dst[e];
  int pos = atomicAdd(&cursor[d], 1);
  csr[rowstart[d] + pos] = src[e];
}

// ================= GEMM: out[N x Cact] = A[N x 128] @ W[128 x Cact] =================
// 64x64 tile per block, 256 threads, 4x4 micro-tile/thread, 64 KB LDS (2 blocks/CU).
// A tile stored xor-rotated (phys col = (k + 4*row) & 127) to avoid stride-128
// 4-way bank conflicts on the b128 fragment reads.
__device__ __forceinline__ int aidx(int row, int col){
  return row * 128 + ((col + 4 * row) & 127);
}

__global__ __launch_bounds__(256) void k_gemm64(const float* __restrict__ A,
                                                const float* __restrict__ W,
                                                float* __restrict__ out,
                                                int N, int Cact)
{
  __shared__ float Wl[128 * 64];
  __shared__ float Al[64 * 128];
  const int t = threadIdx.x;
  const int rowBase = blockIdx.x * 64;
  const int colBase = blockIdx.y * 64;

  // stage W tile (128 x 64), zero-pad cols >= Cact
  for (int idx = t; idx < 128 * 64; idx += 256){
    int k = idx >> 6, cl = idx & 63, col = colBase + cl;
    Wl[idx] = (col < Cact) ? W[k * Cact + col] : 0.f;
  }
  // stage A tile (64 x 128), swizzled
  {
    int tr = t >> 5, tc = (t & 31) * 4;
    #pragma unroll
    for (int i = 0; i < 8; i++){
      int lr = tr + i * 8, gr = rowBase + lr;
      float4 v = make_float4(0.f, 0.f, 0.f, 0.f);
      if (gr < N) v = *reinterpret_cast<const float4*>(&A[(size_t)gr * 128 + tc]);
      *reinterpret_cast<float4*>(&Al[aidx(lr, tc)]) = v;
    }
  }
  __syncthreads();

  const int tx = t & 15, ty = t >> 4;
  float4 acc[4];
  #pragma unroll
  for (int i = 0; i < 4; i++) acc[i] = make_float4(0.f, 0.f, 0.f, 0.f);

#define FMA4(ACC, S, V) \
  ACC.x = fmaf(S, V.x, ACC.x); ACC.y = fmaf(S, V.y, ACC.y); \
  ACC.z = fmaf(S, V.z, ACC.z); ACC.w = fmaf(S, V.w, ACC.w);

  for (int k = 0; k < 128; k += 4){
    float4 a[4], w[4];
    #pragma unroll
    for (int i = 0; i < 4; i++)
      a[i] = *reinterpret_cast<const float4*>(&Al[aidx(ty + 16 * i, k)]);
    #pragma unroll
    for (int kk = 0; kk < 4; kk++)
      w[kk] = *reinterpret_cast<const float4*>(&Wl[(k + kk) * 64 + tx * 4]);
    #pragma unroll
    for (int i = 0; i < 4; i++){
      FMA4(acc[i], a[i].x, w[0]);
      FMA4(acc[i], a[i].y, w[1]);
      FMA4(acc[i], a[i].z, w[2]);
      FMA4(acc[i], a[i].w, w[3]);
    }
  }
#undef FMA4

  int cb = colBase + tx * 4;
  if (cb + 4 <= Cact){
    #pragma unroll
    for (int i = 0; i < 4; i++){
      int gr = rowBase + ty + 16 * i;
      if (gr < N)
        *reinterpret_cast<float4*>(&out[(size_t)gr * Cact + cb]) = acc[i];
    }
  }
}

// ================= GCN aggregation =================
// One wave per node, lane owns 2 channels (C=128). out = sum_e dinv[s]*dinv[v]*hw[s]
//                                                      + dinv[v]^2*hw[v] + bias
__global__ __launch_bounds__(256) void k_agg128(const float* __restrict__ hw,
                                                const int* __restrict__ rs,
                                                const int* __restrict__ csr,
                                                const float* __restrict__ dinv,
                                                const float* __restrict__ bias,
                                                float* __restrict__ out, int N)
{
  int v = blockIdx.x * 4 + threadIdx.y;
  if (v >= N) return;
  int lane = threadIdx.x;
  const float2* hw2 = reinterpret_cast<const float2*>(hw);
  float dv = dinv[v];
  float2 h = hw2[(size_t)v * 64 + lane];
  float acx = h.x * dv * dv, acy = h.y * dv * dv;
  int e0 = rs[v], e1 = rs[v + 1];
  for (int i = e0; i < e1; i++){
    int s = csr[i];
    float w = dinv[s] * dv;
    float2 m = hw2[(size_t)s * 64 + lane];
    acx = fmaf(w, m.x, acx);
    acy = fmaf(w, m.y, acy);
  }
  float2 bb = reinterpret_cast<const float2*>(bias)[lane];
  float2 o; o.x = acx + bb.x; o.y = acy + bb.y;
  reinterpret_cast<float2*>(out)[(size_t)v * 64 + lane] = o;
}

__global__ __launch_bounds__(256) void k_agg40(const float* __restrict__ hw,
                                               const int* __restrict__ rs,
                                               const int* __restrict__ csr,
                                               const float* __restrict__ dinv,
                                               const float* __restrict__ bias,
                                               float* __restrict__ out, int N)
{
  int v = blockIdx.x * 4 + threadIdx.y;
  if (v >= N) return;
  int lane = threadIdx.x;
  float dv = dinv[v];
  float acc = 0.f;
  if (lane < 40) acc = hw[(size_t)v * 40 + lane] * dv * dv;
  int e0 = rs[v], e1 = rs[v + 1];
  for (int i = e0; i < e1; i++){
    int s = csr[i];
    float w = dinv[s] * dv;
    if (lane < 40) acc = fmaf(w, hw[(size_t)s * 40 + lane], acc);
  }
  if (lane < 40) out[(size_t)v * 40 + lane] = acc + bias[lane];
}

// ================= BatchNorm (training) =================
__global__ __launch_bounds__(128) void k_bnstats(const float* __restrict__ h,
                                                 float* __restrict__ sums,
                                                 float* __restrict__ sumsq, int N)
{
  int c = threadIdx.x;
  float s = 0.f, q = 0.f;
  for (int r = blockIdx.x; r < N; r += gridDim.x){
    float v = h[(size_t)r * 128 + c];
    s += v;
    q = fmaf(v, v, q);
  }
  atomicAdd(&sums[c], s);
  atomicAdd(&sumsq[c], q);
}

__global__ __launch_bounds__(128) void k_bnfinal(const float* __restrict__ sums,
                                                 const float* __restrict__ sumsq,
                                                 const float* __restrict__ g,
                                                 const float* __restrict__ be,
                                                 float* __restrict__ scale,
                                                 float* __restrict__ shiftv, int N)
{
  int c = threadIdx.x;
  float inv = 1.0f / (float)N;
  float mean = sums[c] * inv;
  float var = fmaxf(sumsq[c] * inv - mean * mean, 0.f);
  float rstd = rsqrtf(var + 1e-5f);
  float sc = g[c] * rstd;
  scale[c] = sc;
  shiftv[c] = be[c] - mean * sc;
}

// BN affine + ReLU + dropout(0.5) with exact JAX threefry mask.
// Thread handles 4 channels of one row (float4).
__global__ __launch_bounds__(256) void k_bnrd(float* __restrict__ h,
                                              const float* __restrict__ scale,
                                              const float* __restrict__ shiftv,
                                              unsigned k0, unsigned k1, int N)
{
  int t = blockIdx.x * 256 + threadIdx.x;
  if (t >= N * 32) return;
  int r = t >> 5, c = (t & 31) * 4;
  float4 a = *reinterpret_cast<const float4*>(&h[(size_t)r * 128 + c]);
  float* ap = &a.x;
  unsigned base = (unsigned)r * 128u + (unsigned)c;
#if PRNG_PART
  #pragma unroll
  for (int j = 0; j < 4; j++){
    unsigned w0, w1;
    tf2x32(k0, k1, 0u, base + (unsigned)j, w0, w1);
    unsigned bits = w0 ^ w1;   // partitionable 32-bit random_bits = bits1 ^ bits2
    float va = fmaf(ap[j], scale[c + j], shiftv[c + j]);
    va = fmaxf(va, 0.f);
    ap[j] = (bits & 0x80000000u) ? 0.f : va * 2.f;
  }
#else
  const unsigned H = (unsigned)(N * 64);  // N*128/2
  #pragma unroll
  for (int j = 0; j < 4; j++){
    unsigned jj = base + (unsigned)j;
    unsigned w0, w1, bits;
    if (jj < H){ tf2x32(k0, k1, jj, jj + H, w0, w1); bits = w0; }
    else       { tf2x32(k0, k1, jj - H, jj, w0, w1); bits = w1; }
    float va = fmaf(ap[j], scale[c + j], shiftv[c + j]);
    va = fmaxf(va, 0.f);
    ap[j] = (bits & 0x80000000u) ? 0.f : va * 2.f;
  }
#endif
  *reinterpret_cast<float4*>(&h[(size_t)r * 128 + c]) = a;
}

// ================= log_softmax (C=40), in place =================
__global__ __launch_bounds__(256) void k_lsm(float* __restrict__ out, int N)
{
  int v = blockIdx.x * 4 + threadIdx.y;
  if (v >= N) return;
  int lane = threadIdx.x;
  float x = (lane < 40) ? out[(size_t)v * 40 + lane] : -INFINITY;
  float m = x;
  #pragma unroll
  for (int off = 32; off; off >>= 1) m = fmaxf(m, __shfl_xor(m, off));
  float e = (lane < 40) ? expf(x - m) : 0.f;
  float ssum = e;
  #pragma unroll
  for (int off = 32; off; off >>= 1) ssum += __shfl_xor(ssum, off);
  if (lane < 40) out[(size_t)v * 40 + lane] = x - m - logf(ssum);
}

// ================= launch =================
extern "C" void kernel_launch(void* const* d_in, const int* in_sizes, int n_in,
                              void* d_out, int out_size, void* d_ws, size_t ws_size,
                              hipStream_t stream)
{
  const float* x  = (const float*)d_in[0];
  const int* ei   = (const int*)d_in[1];
  const float* W1 = (const float*)d_in[2];
  const float* b1 = (const float*)d_in[3];
  const float* g1 = (const float*)d_in[4];
  const float* be1= (const float*)d_in[5];
  const float* W2 = (const float*)d_in[6];
  const float* b2 = (const float*)d_in[7];
  const float* g2 = (const float*)d_in[8];
  const float* be2= (const float*)d_in[9];
  const float* W3 = (const float*)d_in[10];
  const float* b3 = (const float*)d_in[11];
  float* out = (float*)d_out;

  const int N = in_sizes[0] / 128;
  const int E = in_sizes[1] / 2;
  const int* srcv = ei;
  const int* dstv = ei + E;

  // workspace carve-up (~108 MB total)
  char* ws = (char*)d_ws;
  size_t off = 0;
  auto take = [&](size_t bytes) -> void* {
    void* p = ws + off;
    off = (off + bytes + 255) & ~(size_t)255;
    return p;
  };
  int*   cnt      = (int*)  take((size_t)N * 4);
  int*   cursor   = (int*)  take((size_t)N * 4);
  int*   rowstart = (int*)  take((size_t)(N + 1) * 4);
  int*   csr      = (int*)  take((size_t)E * 4);
  float* dinv     = (float*)take((size_t)N * 4);
  int*   bsum     = (int*)  take(256 * 4);
  int*   boff     = (int*)  take(256 * 4);
  float* sums     = (float*)take(128 * 4);
  float* sumsq    = (float*)take(128 * 4);
  float* scale    = (float*)take(128 * 4);
  float* shiftv   = (float*)take(128 * 4);
  float* bufA     = (float*)take((size_t)N * 128 * 4);
  float* bufB     = (float*)take((size_t)N * 128 * 4);
  (void)ws_size; (void)n_in; (void)out_size;

  // dropout subkeys for jax.random.split(jax.random.key(42), 2) on host
  unsigned l1k0, l1k1, l2k0, l2k1;
#if PRNG_PART
  tf2x32(0u, 42u, 0u, 0u, l1k0, l1k1);   // dk[0] = both words of tf(key,(0,0))
  tf2x32(0u, 42u, 0u, 1u, l2k0, l2k1);   // dk[1] = both words of tf(key,(0,1))
#else
  unsigned a0, a1, c0, c1;
  tf2x32(0u, 42u, 0u, 2u, a0, a1);       // pair (0,2)
  tf2x32(0u, 42u, 1u, 3u, c0, c1);       // pair (1,3)
  l1k0 = a0; l1k1 = c0;                  // dk[0] = (w0 p0, w0 p1)
  l2k0 = a1; l2k1 = c1;                  // dk[1] = (w1 p0, w1 p1)
#endif

  const int NB = (N + 1023) / 1024;
  dim3 wgrid((N + 3) / 4), wblk(64, 4);

  // ---- graph structure (recomputed every call; ws is poisoned) ----
  hipMemsetAsync(cnt, 0, (size_t)N * 4, stream);
  hipMemsetAsync(cursor, 0, (size_t)N * 4, stream);
  k_count<<<(E + 255) / 256, 256, 0, stream>>>(dstv, cnt, E);
  k_dinv<<<(N + 255) / 256, 256, 0, stream>>>(cnt, dinv, N);
  k_blocksum<<<NB, 256, 0, stream>>>(cnt, bsum, N);
  k_scansums<<<1, 256, 0, stream>>>(bsum, boff, rowstart, NB, N);
  k_scanfinal<<<NB, 256, 0, stream>>>(cnt, boff, rowstart, N);
  k_fill<<<(E + 255) / 256, 256, 0, stream>>>(srcv, dstv, rowstart, cursor, csr, E);

  dim3 ggrid((N + 63) / 64, 2);

  // ---- layer 1 ----
  k_gemm64<<<ggrid, 256, 0, stream>>>(x, W1, bufA, N, 128);
  k_agg128<<<wgrid, wblk, 0, stream>>>(bufA, rowstart, csr, dinv, b1, bufB, N);
  hipMemsetAsync(sums, 0, 128 * 4, stream);
  hipMemsetAsync(sumsq, 0, 128 * 4, stream);
  k_bnstats<<<1024, 128, 0, stream>>>(bufB, sums, sumsq, N);
  k_bnfinal<<<1, 128, 0, stream>>>(sums, sumsq, g1, be1, scale, shiftv, N);
  k_bnrd<<<(N * 32 + 255) / 256, 256, 0, stream>>>(bufB, scale, shiftv, l1k0, l1k1, N);

  // ---- layer 2 ----
  k_gemm64<<<ggrid, 256, 0, stream>>>(bufB, W2, bufA, N, 128);
  k_agg128<<<wgrid, wblk, 0, stream>>>(bufA, rowstart, csr, dinv, b2, bufB, N);
  hipMemsetAsync(sums, 0, 128 * 4, stream);
  hipMemsetAsync(sumsq, 0, 128 * 4, stream);
  k_bnstats<<<1024, 128, 0, stream>>>(bufB, sums, sumsq, N);
  k_bnfinal<<<1, 128, 0, stream>>>(sums, sumsq, g2, be2, scale, shiftv, N);
  k_bnrd<<<(N * 32 + 255) / 256, 256, 0, stream>>>(bufB, scale, shiftv, l2k0, l2k1, N);

  // ---- layer 3 + log_softmax ----
  dim3 ggrid3((N + 63) / 64, 1);
  k_gemm64<<<ggrid3, 256, 0, stream>>>(bufB, W3, bufA, N, 40);
  k_agg40<<<wgrid, wblk, 0, stream>>>(bufA, rowstart, csr, dinv, b3, out, N);
  k_lsm<<<wgrid, wblk, 0, stream>>>(out, N);
}

// Round 3
// 680.119 us; speedup vs baseline: 1.4566x; 1.4566x over previous
//
#include <hip/hip_runtime.h>
#include <math.h>

typedef __attribute__((ext_vector_type(8))) short bf16x8;
typedef __attribute__((ext_vector_type(4))) float f32x4;

__device__ __forceinline__ float bfbits2f(unsigned short b){
  return __uint_as_float(((unsigned)b) << 16);
}
__device__ __forceinline__ unsigned short f2bfbits(float f){
  unsigned u = __float_as_uint(f);
  unsigned r = u + 0x7fffu + ((u >> 16) & 1u);
  return (unsigned short)(r >> 16);
}

// ================= Threefry-2x32 (JAX partitionable) =================
__host__ __device__ __forceinline__ unsigned rotl32(unsigned v, int d){
  return (v << d) | (v >> (32 - d));
}
__host__ __device__ __forceinline__ void tf2x32(unsigned k0, unsigned k1,
                                                unsigned c0, unsigned c1,
                                                unsigned &o0, unsigned &o1)
{
  unsigned ks2 = k0 ^ k1 ^ 0x1BD11BDAu;
  unsigned x0 = c0 + k0, x1 = c1 + k1;
#define TFR(r) x0 += x1; x1 = rotl32(x1, r); x1 ^= x0;
  TFR(13) TFR(15) TFR(26) TFR(6)
  x0 += k1;  x1 += ks2 + 1u;
  TFR(17) TFR(29) TFR(16) TFR(24)
  x0 += ks2; x1 += k0 + 2u;
  TFR(13) TFR(15) TFR(26) TFR(6)
  x0 += k0;  x1 += k1 + 3u;
  TFR(17) TFR(29) TFR(16) TFR(24)
  x0 += k1;  x1 += ks2 + 4u;
  TFR(13) TFR(15) TFR(26) TFR(6)
  x0 += ks2; x1 += k0 + 5u;
#undef TFR
  o0 = x0; o1 = x1;
}

// ================= CSR build =================
__global__ __launch_bounds__(256) void k_count(const int* __restrict__ dst,
                                               int* __restrict__ cnt, int E)
{
  int e = blockIdx.x * 256 + threadIdx.x;
  if (e < E) atomicAdd(&cnt[dst[e]], 1);
}

__global__ __launch_bounds__(256) void k_blocksum(const int* __restrict__ cnt,
                                                  int* __restrict__ bsum, int N)
{
  __shared__ int sh[256];
  int t = threadIdx.x;
  int base = blockIdx.x * 1024 + t * 4;
  int s = 0;
  #pragma unroll
  for (int j = 0; j < 4; j++){ int i = base + j; if (i < N) s += cnt[i]; }
  sh[t] = s; __syncthreads();
  for (int off = 128; off; off >>= 1){
    if (t < off) sh[t] += sh[t + off];
    __syncthreads();
  }
  if (t == 0) bsum[blockIdx.x] = sh[0];
}

__global__ __launch_bounds__(256) void k_scansums(const int* __restrict__ bsum,
                                                  int* __restrict__ boff,
                                                  int* __restrict__ rowstart,
                                                  int NB, int N)
{
  __shared__ int sh[256];
  int t = threadIdx.x;
  int v = (t < NB) ? bsum[t] : 0;
  sh[t] = v; __syncthreads();
  for (int off = 1; off < 256; off <<= 1){
    int x = sh[t];
    int y = (t >= off) ? sh[t - off] : 0;
    __syncthreads();
    sh[t] = x + y;
    __syncthreads();
  }
  if (t < NB) boff[t] = sh[t] - v;
  if (t == NB - 1) rowstart[N] = sh[t];
}

// scan finalize + dinv (fused: cnt already in registers)
__global__ __launch_bounds__(256) void k_scanfinal(const int* __restrict__ cnt,
                                                   const int* __restrict__ boff,
                                                   int* __restrict__ rowstart,
                                                   float* __restrict__ dinv, int N)
{
  __shared__ int sh[256];
  int t = threadIdx.x;
  int base = blockIdx.x * 1024 + t * 4;
  int c0 = 0, c1 = 0, c2 = 0, c3 = 0;
  if (base + 0 < N) c0 = cnt[base + 0];
  if (base + 1 < N) c1 = cnt[base + 1];
  if (base + 2 < N) c2 = cnt[base + 2];
  if (base + 3 < N) c3 = cnt[base + 3];
  int s = c0 + c1 + c2 + c3;
  sh[t] = s; __syncthreads();
  for (int off = 1; off < 256; off <<= 1){
    int x = sh[t];
    int y = (t >= off) ? sh[t - off] : 0;
    __syncthreads();
    sh[t] = x + y;
    __syncthreads();
  }
  int excl = sh[t] - s + boff[blockIdx.x];
  if (base + 0 < N){ rowstart[base+0] = excl;          dinv[base+0] = rsqrtf((float)c0 + 1.f); }
  if (base + 1 < N){ rowstart[base+1] = excl+c0;       dinv[base+1] = rsqrtf((float)c1 + 1.f); }
  if (base + 2 < N){ rowstart[base+2] = excl+c0+c1;    dinv[base+2] = rsqrtf((float)c2 + 1.f); }
  if (base + 3 < N){ rowstart[base+3] = excl+c0+c1+c2; dinv[base+3] = rsqrtf((float)c3 + 1.f); }
}

__global__ __launch_bounds__(256) void k_fill(const int* __restrict__ src,
                                              const int* __restrict__ dst,
                                              const int* __restrict__ rowstart,
                                              int* __restrict__ cursor,
                                              int* __restrict__ csr, int E)
{
  int e = blockIdx.x * 256 + threadIdx.x;
  if (e >= E) return;
  int d = dst[e];
  int pos = atomicAdd(&cursor[d], 1);
  csr[rowstart[d] + pos] = src[e];
}

// ================= weight transpose: WT[n][k] bf16, row stride 136 =================
__global__ __launch_bounds__(256) void k_wt(const float* __restrict__ W1,
                                            const float* __restrict__ W2,
                                            const float* __restrict__ W3,
                                            unsigned short* __restrict__ WT1,
                                            unsigned short* __restrict__ WT2,
                                            unsigned short* __restrict__ WT3)
{
  const float* W; unsigned short* WT; int Cout, Cpad;
  if (blockIdx.x == 0){ W = W1; WT = WT1; Cout = 128; Cpad = 128; }
  else if (blockIdx.x == 1){ W = W2; WT = WT2; Cout = 128; Cpad = 128; }
  else { W = W3; WT = WT3; Cout = 40; Cpad = 48; }
  int tot = Cpad * 136;
  for (int i = threadIdx.x; i < tot; i += 256){
    int n = i / 136, k = i - n * 136;
    float v = (k < 128 && n < Cout) ? W[k * Cout + n] : 0.f;
    WT[i] = f2bfbits(v);
  }
}

// ================= MFMA GEMM =================
// out[row][col] = (sum_k A[row][k] * W[k][col]) * dinv[row], bf16 store.
// Block: 256 thr = 4 waves x 32 rows = 128 rows. NT = col-tiles of 16.
// WT staged in LDS [NT*16][136] bf16 (pad 8 shorts -> bank-conflict-free b128).
// A-operand frag: lane holds A[m=lane&15][k=quad*8+j] (j=0..7, 16B contiguous).
// B-operand frag: lane holds W[k=quad*8+j][n=lane&15] = WT[n][k...k+8] contiguous.
// C/D: col=lane&15, row=quad*4+reg (m89-verified).
template<int NT, bool AF32>
__global__ __launch_bounds__(256) void k_gemm_mfma(const void* __restrict__ Ap,
                                                   const unsigned short* __restrict__ WT,
                                                   const float* __restrict__ dinv,
                                                   unsigned short* __restrict__ outb,
                                                   int N, int Cout)
{
  __shared__ unsigned short Wl[NT * 16 * 136];
  const int t = threadIdx.x;
  {
    const uint4* s4 = (const uint4*)WT;
    uint4* d4 = (uint4*)Wl;
    const int tot = NT * 16 * 136 / 8;
    for (int i = t; i < tot; i += 256) d4[i] = s4[i];
  }
  __syncthreads();

  const int w = t >> 6, l = t & 63;
  const int lm = l & 15, q = l >> 4;
  const long rb0 = (long)blockIdx.x * 128 + w * 32;

  f32x4 acc[2][NT];
  #pragma unroll
  for (int rt = 0; rt < 2; rt++)
    #pragma unroll
    for (int nt = 0; nt < NT; nt++){
      acc[rt][nt][0] = 0.f; acc[rt][nt][1] = 0.f;
      acc[rt][nt][2] = 0.f; acc[rt][nt][3] = 0.f;
    }

  #pragma unroll
  for (int kt = 0; kt < 4; kt++){
    const int koff = kt * 32 + q * 8;
    bf16x8 a[2];
    #pragma unroll
    for (int rt = 0; rt < 2; rt++){
      long row = rb0 + rt * 16 + lm;
      if (row >= N) row = N - 1;     // clamp; value discarded at store
      if (AF32){
        const float* ap = (const float*)Ap + row * 128 + koff;
        float4 f0 = *(const float4*)ap;
        float4 f1 = *(const float4*)(ap + 4);
        bf16x8 v;
        v[0] = (short)f2bfbits(f0.x); v[1] = (short)f2bfbits(f0.y);
        v[2] = (short)f2bfbits(f0.z); v[3] = (short)f2bfbits(f0.w);
        v[4] = (short)f2bfbits(f1.x); v[5] = (short)f2bfbits(f1.y);
        v[6] = (short)f2bfbits(f1.z); v[7] = (short)f2bfbits(f1.w);
        a[rt] = v;
      } else {
        a[rt] = *(const bf16x8*)((const unsigned short*)Ap + row * 128 + koff);
      }
    }
    #pragma unroll
    for (int nt = 0; nt < NT; nt++){
      bf16x8 b = *(const bf16x8*)(&Wl[(nt * 16 + lm) * 136 + koff]);
      acc[0][nt] = __builtin_amdgcn_mfma_f32_16x16x32_bf16(a[0], b, acc[0][nt], 0, 0, 0);
      acc[1][nt] = __builtin_amdgcn_mfma_f32_16x16x32_bf16(a[1], b, acc[1][nt], 0, 0, 0);
    }
  }

  #pragma unroll
  for (int rt = 0; rt < 2; rt++){
    #pragma unroll
    for (int r = 0; r < 4; r++){
      long row = rb0 + rt * 16 + q * 4 + r;
      if (row < N){
        float dv = dinv[row];
        #pragma unroll
        for (int nt = 0; nt < NT; nt++){
          int col = nt * 16 + lm;
          if (col < Cout)
            outb[row * Cout + col] = f2bfbits(acc[rt][nt][r] * dv);
        }
      }
    }
  }
}

// ================= aggregation (128 ch, bf16, rows pre-scaled by dinv) ===========
// out[v] = dinv[v] * ( hw'[v] + sum_{s in nbr(v)} hw'[s] ),  hw' = dinv[.]*hw
__global__ __launch_bounds__(256) void k_agg128b(const unsigned short* __restrict__ hw,
                                                 const int* __restrict__ rs,
                                                 const int* __restrict__ csr,
                                                 const float* __restrict__ dinv,
                                                 unsigned short* __restrict__ outb,
                                                 int N)
{
  int v = blockIdx.x * 4 + threadIdx.y;
  if (v >= N) return;
  int lane = threadIdx.x;
  const unsigned* h2 = (const unsigned*)hw;
  unsigned self = h2[(size_t)v * 64 + lane];
  float acx = bfbits2f((unsigned short)(self & 0xffffu));
  float acy = bfbits2f((unsigned short)(self >> 16));
  int e0 = rs[v], e1 = rs[v + 1];
  int i = e0;
  for (; i + 2 <= e1; i += 2){
    int s0 = csr[i], s1 = csr[i + 1];
    unsigned m0 = h2[(size_t)s0 * 64 + lane];
    unsigned m1 = h2[(size_t)s1 * 64 + lane];
    acx += bfbits2f((unsigned short)(m0 & 0xffffu)) + bfbits2f((unsigned short)(m1 & 0xffffu));
    acy += bfbits2f((unsigned short)(m0 >> 16))     + bfbits2f((unsigned short)(m1 >> 16));
  }
  if (i < e1){
    int s0 = csr[i];
    unsigned m0 = h2[(size_t)s0 * 64 + lane];
    acx += bfbits2f((unsigned short)(m0 & 0xffffu));
    acy += bfbits2f((unsigned short)(m0 >> 16));
  }
  float dv = dinv[v];
  acx *= dv; acy *= dv;
  ((unsigned*)outb)[(size_t)v * 64 + lane] =
      (unsigned)f2bfbits(acx) | ((unsigned)f2bfbits(acy) << 16);
}

// ================= BatchNorm =================
__global__ __launch_bounds__(128) void k_bnstatsb(const unsigned short* __restrict__ h,
                                                  float* __restrict__ sums,
                                                  float* __restrict__ sumsq, int N)
{
  int c = threadIdx.x;
  float s = 0.f, qq = 0.f;
  for (int r = blockIdx.x; r < N; r += gridDim.x){
    float v = bfbits2f(h[(size_t)r * 128 + c]);
    s += v; qq = fmaf(v, v, qq);
  }
  atomicAdd(&sums[c], s);
  atomicAdd(&sumsq[c], qq);
}

__global__ __launch_bounds__(128) void k_bnfinal(const float* __restrict__ sums,
                                                 const float* __restrict__ sumsq,
                                                 const float* __restrict__ g,
                                                 const float* __restrict__ be,
                                                 float* __restrict__ scale,
                                                 float* __restrict__ shiftv, int N)
{
  int c = threadIdx.x;
  float inv = 1.0f / (float)N;
  float mean = sums[c] * inv;
  float var = fmaxf(sumsq[c] * inv - mean * mean, 0.f);
  float rstd = rsqrtf(var + 1e-5f);
  float sc = g[c] * rstd;
  scale[c] = sc;
  shiftv[c] = be[c] - mean * sc;
}

// BN affine + ReLU + dropout; thread = 2 channels (one packed u32), bf16 in/out.
__global__ __launch_bounds__(256) void k_bnrdb(const unsigned short* __restrict__ in,
                                               unsigned short* __restrict__ out,
                                               const float* __restrict__ scale,
                                               const float* __restrict__ shiftv,
                                               unsigned k0, unsigned k1, long total2)
{
  long t = (long)blockIdx.x * 256 + threadIdx.x;   // over N*64
  if (t >= total2) return;
  int c = ((int)(t & 63)) * 2;
  unsigned u = ((const unsigned*)in)[t];
  unsigned idx = (unsigned)(t * 2);                // = r*128 + c
  float v0 = fmaf(bfbits2f((unsigned short)(u & 0xffffu)), scale[c],     shiftv[c]);
  float v1 = fmaf(bfbits2f((unsigned short)(u >> 16)),     scale[c + 1], shiftv[c + 1]);
  v0 = fmaxf(v0, 0.f); v1 = fmaxf(v1, 0.f);
  unsigned w0, w1;
  tf2x32(k0, k1, 0u, idx,      w0, w1); unsigned b0 = w0 ^ w1;
  tf2x32(k0, k1, 0u, idx + 1u, w0, w1); unsigned b1 = w0 ^ w1;
  v0 = (b0 & 0x80000000u) ? 0.f : v0 * 2.f;
  v1 = (b1 & 0x80000000u) ? 0.f : v1 * 2.f;
  ((unsigned*)out)[t] = (unsigned)f2bfbits(v0) | ((unsigned)f2bfbits(v1) << 16);
}

// ============ layer-3 aggregation (40 ch bf16 pre-scaled) + bias + log_softmax ======
__global__ __launch_bounds__(256) void k_agg40lsm(const unsigned short* __restrict__ hw,
                                                  const int* __restrict__ rs,
                                                  const int* __restrict__ csr,
                                                  const float* __restrict__ dinv,
                                                  const float* __restrict__ b3,
                                                  float* __restrict__ out, int N)
{
  int v = blockIdx.x * 4 + threadIdx.y;
  if (v >= N) return;
  int lane = threadIdx.x;
  const unsigned* h2 = (const unsigned*)hw;        // row = 20 u32 (80 B)
  float acx = 0.f, acy = 0.f;
  bool act = (lane < 20);
  if (act){
    unsigned u = h2[(size_t)v * 20 + lane];
    acx = bfbits2f((unsigned short)(u & 0xffffu));
    acy = bfbits2f((unsigned short)(u >> 16));
  }
  int e0 = rs[v], e1 = rs[v + 1];
  int i = e0;
  for (; i + 2 <= e1; i += 2){
    int s0 = csr[i], s1 = csr[i + 1];
    if (act){
      unsigned u0 = h2[(size_t)s0 * 20 + lane];
      unsigned u1 = h2[(size_t)s1 * 20 + lane];
      acx += bfbits2f((unsigned short)(u0 & 0xffffu)) + bfbits2f((unsigned short)(u1 & 0xffffu));
      acy += bfbits2f((unsigned short)(u0 >> 16))     + bfbits2f((unsigned short)(u1 >> 16));
    }
  }
  if (i < e1 && act){
    int s0 = csr[i];
    unsigned u0 = h2[(size_t)s0 * 20 + lane];
    acx += bfbits2f((unsigned short)(u0 & 0xffffu));
    acy += bfbits2f((unsigned short)(u0 >> 16));
  }
  float dv = dinv[v];
  float x0 = act ? fmaf(acx, dv, b3[2 * lane])     : -INFINITY;
  float x1 = act ? fmaf(acy, dv, b3[2 * lane + 1]) : -INFINITY;
  float m = fmaxf(x0, x1);
  #pragma unroll
  for (int off = 32; off; off >>= 1) m = fmaxf(m, __shfl_xor(m, off));
  float e = act ? (expf(x0 - m) + expf(x1 - m)) : 0.f;
  #pragma unroll
  for (int off = 32; off; off >>= 1) e += __shfl_xor(e, off);
  float lse = m + logf(e);
  if (act){
    float2 o; o.x = x0 - lse; o.y = x1 - lse;
    *reinterpret_cast<float2*>(out + (size_t)v * 40 + 2 * lane) = o;
  }
}

// ================= launch =================
extern "C" void kernel_launch(void* const* d_in, const int* in_sizes, int n_in,
                              void* d_out, int out_size, void* d_ws, size_t ws_size,
                              hipStream_t stream)
{
  const float* x  = (const float*)d_in[0];
  const int* ei   = (const int*)d_in[1];
  const float* W1 = (const float*)d_in[2];
  const float* g1 = (const float*)d_in[4];
  const float* be1= (const float*)d_in[5];
  const float* W2 = (const float*)d_in[6];
  const float* g2 = (const float*)d_in[8];
  const float* be2= (const float*)d_in[9];
  const float* W3 = (const float*)d_in[10];
  const float* b3 = (const float*)d_in[11];
  float* out = (float*)d_out;
  // b1, b2 unused: per-channel constants cancel exactly in training-mode BN.

  const int N = in_sizes[0] / 128;
  const int E = in_sizes[1] / 2;
  const int* srcv = ei;
  const int* dstv = ei + E;

  char* ws = (char*)d_ws;
  size_t off = 0;
  auto take = [&](size_t bytes) -> void* {
    void* p = ws + off;
    off = (off + bytes + 255) & ~(size_t)255;
    return p;
  };
  int*   cnt      = (int*)  take((size_t)2 * N * 4);   // cnt | cursor, one memset
  int*   cursor   = cnt + N;
  int*   rowstart = (int*)  take((size_t)(N + 1) * 4);
  int*   csr      = (int*)  take((size_t)E * 4);
  float* dinv     = (float*)take((size_t)N * 4);
  int*   bsum     = (int*)  take(256 * 4);
  int*   boff     = (int*)  take(256 * 4);
  float* sums     = (float*)take(256 * 4);             // sums | sumsq, one memset
  float* sumsq    = sums + 128;
  float* scale    = (float*)take(128 * 4);
  float* shiftv   = (float*)take(128 * 4);
  unsigned short* WT1 = (unsigned short*)take(128 * 136 * 2);
  unsigned short* WT2 = (unsigned short*)take(128 * 136 * 2);
  unsigned short* WT3 = (unsigned short*)take(48 * 136 * 2);
  unsigned short* bufX = (unsigned short*)take((size_t)N * 128 * 2);
  unsigned short* bufY = (unsigned short*)take((size_t)N * 128 * 2);
  (void)ws_size; (void)n_in; (void)out_size;

  // dropout subkeys: jax.random.split(key(42), 2), partitionable fold
  unsigned l1k0, l1k1, l2k0, l2k1;
  tf2x32(0u, 42u, 0u, 0u, l1k0, l1k1);
  tf2x32(0u, 42u, 0u, 1u, l2k0, l2k1);

  const int NB = (N + 1023) / 1024;
  dim3 wgrid((N + 3) / 4), wblk(64, 4);
  const int ggrid = (N + 127) / 128;
  const long total2 = (long)N * 64;
  const int bnrdg = (int)((total2 + 255) / 256);

  // ---- graph structure ----
  hipMemsetAsync(cnt, 0, (size_t)2 * N * 4, stream);
  k_count<<<(E + 255) / 256, 256, 0, stream>>>(dstv, cnt, E);
  k_blocksum<<<NB, 256, 0, stream>>>(cnt, bsum, N);
  k_scansums<<<1, 256, 0, stream>>>(bsum, boff, rowstart, NB, N);
  k_scanfinal<<<NB, 256, 0, stream>>>(cnt, boff, rowstart, dinv, N);
  k_fill<<<(E + 255) / 256, 256, 0, stream>>>(srcv, dstv, rowstart, cursor, csr, E);
  k_wt<<<3, 256, 0, stream>>>(W1, W2, W3, WT1, WT2, WT3);

  // ---- layer 1 ----
  k_gemm_mfma<8, true><<<ggrid, 256, 0, stream>>>(x, WT1, dinv, bufX, N, 128);
  k_agg128b<<<wgrid, wblk, 0, stream>>>(bufX, rowstart, csr, dinv, bufY, N);
  hipMemsetAsync(sums, 0, 256 * 4, stream);
  k_bnstatsb<<<1024, 128, 0, stream>>>(bufY, sums, sumsq, N);
  k_bnfinal<<<1, 128, 0, stream>>>(sums, sumsq, g1, be1, scale, shiftv, N);
  k_bnrdb<<<bnrdg, 256, 0, stream>>>(bufY, bufX, scale, shiftv, l1k0, l1k1, total2);

  // ---- layer 2 ----
  k_gemm_mfma<8, false><<<ggrid, 256, 0, stream>>>(bufX, WT2, dinv, bufY, N, 128);
  k_agg128b<<<wgrid, wblk, 0, stream>>>(bufY, rowstart, csr, dinv, bufX, N);
  hipMemsetAsync(sums, 0, 256 * 4, stream);
  k_bnstatsb<<<1024, 128, 0, stream>>>(bufX, sums, sumsq, N);
  k_bnfinal<<<1, 128, 0, stream>>>(sums, sumsq, g2, be2, scale, shiftv, N);
  k_bnrdb<<<bnrdg, 256, 0, stream>>>(bufX, bufY, scale, shiftv, l2k0, l2k1, total2);

  // ---- layer 3 + log_softmax ----
  k_gemm_mfma<3, false><<<ggrid, 256, 0, stream>>>(bufY, WT3, dinv, bufX, N, 40);
  k_agg40lsm<<<wgrid, wblk, 0, stream>>>(bufX, rowstart, csr, dinv, b3, out, N);
}

// Round 4
// 621.599 us; speedup vs baseline: 1.5937x; 1.0941x over previous
//
#include <hip/hip_runtime.h>
#include <math.h>

typedef __attribute__((ext_vector_type(8))) short bf16x8;
typedef __attribute__((ext_vector_type(4))) float f32x4;

__device__ __forceinline__ float bfbits2f(unsigned short b){
  return __uint_as_float(((unsigned)b) << 16);
}
__device__ __forceinline__ unsigned short f2bfbits(float f){
  unsigned u = __float_as_uint(f);
  unsigned r = u + 0x7fffu + ((u >> 16) & 1u);
  return (unsigned short)(r >> 16);
}

// ================= Threefry-2x32 (JAX partitionable) =================
__host__ __device__ __forceinline__ unsigned rotl32(unsigned v, int d){
  return (v << d) | (v >> (32 - d));
}
__host__ __device__ __forceinline__ void tf2x32(unsigned k0, unsigned k1,
                                                unsigned c0, unsigned c1,
                                                unsigned &o0, unsigned &o1)
{
  unsigned ks2 = k0 ^ k1 ^ 0x1BD11BDAu;
  unsigned x0 = c0 + k0, x1 = c1 + k1;
#define TFR(r) x0 += x1; x1 = rotl32(x1, r); x1 ^= x0;
  TFR(13) TFR(15) TFR(26) TFR(6)
  x0 += k1;  x1 += ks2 + 1u;
  TFR(17) TFR(29) TFR(16) TFR(24)
  x0 += ks2; x1 += k0 + 2u;
  TFR(13) TFR(15) TFR(26) TFR(6)
  x0 += k0;  x1 += k1 + 3u;
  TFR(17) TFR(29) TFR(16) TFR(24)
  x0 += k1;  x1 += ks2 + 4u;
  TFR(13) TFR(15) TFR(26) TFR(6)
  x0 += ks2; x1 += k0 + 5u;
#undef TFR
  o0 = x0; o1 = x1;
}

// ================= CSR build =================
__global__ __launch_bounds__(256) void k_count(const int* __restrict__ dst,
                                               int* __restrict__ cnt, int E)
{
  int e = blockIdx.x * 256 + threadIdx.x;
  if (e < E) atomicAdd(&cnt[dst[e]], 1);
}

__global__ __launch_bounds__(256) void k_blocksum(const int* __restrict__ cnt,
                                                  int* __restrict__ bsum, int N)
{
  __shared__ int sh[256];
  int t = threadIdx.x;
  int base = blockIdx.x * 1024 + t * 4;
  int s = 0;
  #pragma unroll
  for (int j = 0; j < 4; j++){ int i = base + j; if (i < N) s += cnt[i]; }
  sh[t] = s; __syncthreads();
  for (int off = 128; off; off >>= 1){
    if (t < off) sh[t] += sh[t + off];
    __syncthreads();
  }
  if (t == 0) bsum[blockIdx.x] = sh[0];
}

__global__ __launch_bounds__(256) void k_scansums(const int* __restrict__ bsum,
                                                  int* __restrict__ boff,
                                                  int* __restrict__ rowstart,
                                                  int NB, int N)
{
  __shared__ int sh[256];
  int t = threadIdx.x;
  int v = (t < NB) ? bsum[t] : 0;
  sh[t] = v; __syncthreads();
  for (int off = 1; off < 256; off <<= 1){
    int x = sh[t];
    int y = (t >= off) ? sh[t - off] : 0;
    __syncthreads();
    sh[t] = x + y;
    __syncthreads();
  }
  if (t < NB) boff[t] = sh[t] - v;
  if (t == NB - 1) rowstart[N] = sh[t];
}

// scan finalize + dinv (fused)
__global__ __launch_bounds__(256) void k_scanfinal(const int* __restrict__ cnt,
                                                   const int* __restrict__ boff,
                                                   int* __restrict__ rowstart,
                                                   float* __restrict__ dinv, int N)
{
  __shared__ int sh[256];
  int t = threadIdx.x;
  int base = blockIdx.x * 1024 + t * 4;
  int c0 = 0, c1 = 0, c2 = 0, c3 = 0;
  if (base + 0 < N) c0 = cnt[base + 0];
  if (base + 1 < N) c1 = cnt[base + 1];
  if (base + 2 < N) c2 = cnt[base + 2];
  if (base + 3 < N) c3 = cnt[base + 3];
  int s = c0 + c1 + c2 + c3;
  sh[t] = s; __syncthreads();
  for (int off = 1; off < 256; off <<= 1){
    int x = sh[t];
    int y = (t >= off) ? sh[t - off] : 0;
    __syncthreads();
    sh[t] = x + y;
    __syncthreads();
  }
  int excl = sh[t] - s + boff[blockIdx.x];
  if (base + 0 < N){ rowstart[base+0] = excl;          dinv[base+0] = rsqrtf((float)c0 + 1.f); }
  if (base + 1 < N){ rowstart[base+1] = excl+c0;       dinv[base+1] = rsqrtf((float)c1 + 1.f); }
  if (base + 2 < N){ rowstart[base+2] = excl+c0+c1;    dinv[base+2] = rsqrtf((float)c2 + 1.f); }
  if (base + 3 < N){ rowstart[base+3] = excl+c0+c1+c2; dinv[base+3] = rsqrtf((float)c3 + 1.f); }
}

__global__ __launch_bounds__(256) void k_fill(const int* __restrict__ src,
                                              const int* __restrict__ dst,
                                              const int* __restrict__ rowstart,
                                              int* __restrict__ cursor,
                                              int* __restrict__ csr, int E)
{
  int e = blockIdx.x * 256 + threadIdx.x;
  if (e >= E) return;
  int d = dst[e];
  int pos = atomicAdd(&cursor[d], 1);
  csr[rowstart[d] + pos] = src[e];
}

// ================= weight transpose: WT[n][k] bf16, row stride 136 =================
__global__ __launch_bounds__(256) void k_wt(const float* __restrict__ W1,
                                            const float* __restrict__ W2,
                                            const float* __restrict__ W3,
                                            unsigned short* __restrict__ WT1,
                                            unsigned short* __restrict__ WT2,
                                            unsigned short* __restrict__ WT3)
{
  const float* W; unsigned short* WT; int Cout, Cpad;
  if (blockIdx.x == 0){ W = W1; WT = WT1; Cout = 128; Cpad = 128; }
  else if (blockIdx.x == 1){ W = W2; WT = WT2; Cout = 128; Cpad = 128; }
  else { W = W3; WT = WT3; Cout = 40; Cpad = 48; }
  int tot = Cpad * 136;
  for (int i = threadIdx.x; i < tot; i += 256){
    int n = i / 136, k = i - n * 136;
    float v = (k < 128 && n < Cout) ? W[k * Cout + n] : 0.f;
    WT[i] = f2bfbits(v);
  }
}

// ================= MFMA GEMM =================
// out[row][col] = (sum_k A[row][k] * W[k][col]) * dinv[row], bf16 store.
// Block: 256 thr = 4 waves x 32 rows = 128 rows. NT = col-tiles of 16.
template<int NT, bool AF32>
__global__ __launch_bounds__(256) void k_gemm_mfma(const void* __restrict__ Ap,
                                                   const unsigned short* __restrict__ WT,
                                                   const float* __restrict__ dinv,
                                                   unsigned short* __restrict__ outb,
                                                   int N, int Cout)
{
  __shared__ unsigned short Wl[NT * 16 * 136];
  const int t = threadIdx.x;
  {
    const uint4* s4 = (const uint4*)WT;
    uint4* d4 = (uint4*)Wl;
    const int tot = NT * 16 * 136 / 8;
    for (int i = t; i < tot; i += 256) d4[i] = s4[i];
  }
  __syncthreads();

  const int w = t >> 6, l = t & 63;
  const int lm = l & 15, q = l >> 4;
  const long rb0 = (long)blockIdx.x * 128 + w * 32;

  f32x4 acc[2][NT];
  #pragma unroll
  for (int rt = 0; rt < 2; rt++)
    #pragma unroll
    for (int nt = 0; nt < NT; nt++){
      acc[rt][nt][0] = 0.f; acc[rt][nt][1] = 0.f;
      acc[rt][nt][2] = 0.f; acc[rt][nt][3] = 0.f;
    }

  #pragma unroll
  for (int kt = 0; kt < 4; kt++){
    const int koff = kt * 32 + q * 8;
    bf16x8 a[2];
    #pragma unroll
    for (int rt = 0; rt < 2; rt++){
      long row = rb0 + rt * 16 + lm;
      if (row >= N) row = N - 1;     // clamp; value discarded at store
      if (AF32){
        const float* ap = (const float*)Ap + row * 128 + koff;
        float4 f0 = *(const float4*)ap;
        float4 f1 = *(const float4*)(ap + 4);
        bf16x8 v;
        v[0] = (short)f2bfbits(f0.x); v[1] = (short)f2bfbits(f0.y);
        v[2] = (short)f2bfbits(f0.z); v[3] = (short)f2bfbits(f0.w);
        v[4] = (short)f2bfbits(f1.x); v[5] = (short)f2bfbits(f1.y);
        v[6] = (short)f2bfbits(f1.z); v[7] = (short)f2bfbits(f1.w);
        a[rt] = v;
      } else {
        a[rt] = *(const bf16x8*)((const unsigned short*)Ap + row * 128 + koff);
      }
    }
    #pragma unroll
    for (int nt = 0; nt < NT; nt++){
      bf16x8 b = *(const bf16x8*)(&Wl[(nt * 16 + lm) * 136 + koff]);
      acc[0][nt] = __builtin_amdgcn_mfma_f32_16x16x32_bf16(a[0], b, acc[0][nt], 0, 0, 0);
      acc[1][nt] = __builtin_amdgcn_mfma_f32_16x16x32_bf16(a[1], b, acc[1][nt], 0, 0, 0);
    }
  }

  #pragma unroll
  for (int rt = 0; rt < 2; rt++){
    #pragma unroll
    for (int r = 0; r < 4; r++){
      long row = rb0 + rt * 16 + q * 4 + r;
      if (row < N){
        float dv = dinv[row];
        #pragma unroll
        for (int nt = 0; nt < NT; nt++){
          int col = nt * 16 + lm;
          if (col < Cout)
            outb[row * Cout + col] = f2bfbits(acc[rt][nt][r] * dv);
        }
      }
    }
  }
}

// ================= aggregation (128 ch, bf16, rows pre-scaled by dinv) ===========
// out[v] = dinv[v] * ( hw'[v] + sum_{s in nbr(v)} hw'[s] ),  hw' = dinv[.]*hw
#define ACC2(U) do{ unsigned _u = (U); \
  acx += bfbits2f((unsigned short)(_u & 0xffffu)); \
  acy += bfbits2f((unsigned short)(_u >> 16)); }while(0)

__global__ __launch_bounds__(256) void k_agg128b(const unsigned short* __restrict__ hw,
                                                 const int* __restrict__ rs,
                                                 const int* __restrict__ csr,
                                                 const float* __restrict__ dinv,
                                                 unsigned short* __restrict__ outb,
                                                 int N)
{
  int v = blockIdx.x * 4 + threadIdx.y;
  if (v >= N) return;
  int lane = threadIdx.x;
  const unsigned* h2 = (const unsigned*)hw;
  float acx = 0.f, acy = 0.f;
  ACC2(h2[(size_t)v * 64 + lane]);
  int e0 = rs[v], e1 = rs[v + 1];
  int i = e0;
  for (; i + 4 <= e1; i += 4){
    int s0 = csr[i], s1 = csr[i+1], s2 = csr[i+2], s3 = csr[i+3];
    unsigned m0 = h2[(size_t)s0 * 64 + lane];
    unsigned m1 = h2[(size_t)s1 * 64 + lane];
    unsigned m2 = h2[(size_t)s2 * 64 + lane];
    unsigned m3 = h2[(size_t)s3 * 64 + lane];
    ACC2(m0); ACC2(m1); ACC2(m2); ACC2(m3);
  }
  for (; i < e1; i++){
    ACC2(h2[(size_t)csr[i] * 64 + lane]);
  }
  float dv = dinv[v];
  acx *= dv; acy *= dv;
  ((unsigned*)outb)[(size_t)v * 64 + lane] =
      (unsigned)f2bfbits(acx) | ((unsigned)f2bfbits(acy) << 16);
}

// ================= BatchNorm =================
__global__ __launch_bounds__(128) void k_bnstatsb(const unsigned short* __restrict__ h,
                                                  float* __restrict__ sums,
                                                  float* __restrict__ sumsq, int N)
{
  int c = threadIdx.x;
  float s = 0.f, qq = 0.f;
  for (int r = blockIdx.x; r < N; r += gridDim.x){
    float v = bfbits2f(h[(size_t)r * 128 + c]);
    s += v; qq = fmaf(v, v, qq);
  }
  atomicAdd(&sums[c], s);
  atomicAdd(&sumsq[c], qq);
}

__global__ __launch_bounds__(128) void k_bnfinal(const float* __restrict__ sums,
                                                 const float* __restrict__ sumsq,
                                                 const float* __restrict__ g,
                                                 const float* __restrict__ be,
                                                 float* __restrict__ scale,
                                                 float* __restrict__ shiftv, int N)
{
  int c = threadIdx.x;
  float inv = 1.0f / (float)N;
  float mean = sums[c] * inv;
  float var = fmaxf(sumsq[c] * inv - mean * mean, 0.f);
  float rstd = rsqrtf(var + 1e-5f);
  float sc = g[c] * rstd;
  scale[c] = sc;
  shiftv[c] = be[c] - mean * sc;
}

// BN affine + ReLU + dropout; thread = 2 channels (one packed u32), bf16 in/out.
__global__ __launch_bounds__(256) void k_bnrdb(const unsigned short* __restrict__ in,
                                               unsigned short* __restrict__ out,
                                               const float* __restrict__ scale,
                                               const float* __restrict__ shiftv,
                                               unsigned k0, unsigned k1, long total2)
{
  long t = (long)blockIdx.x * 256 + threadIdx.x;   // over N*64
  if (t >= total2) return;
  int c = ((int)(t & 63)) * 2;
  unsigned u = ((const unsigned*)in)[t];
  unsigned idx = (unsigned)(t * 2);                // = r*128 + c
  float v0 = fmaf(bfbits2f((unsigned short)(u & 0xffffu)), scale[c],     shiftv[c]);
  float v1 = fmaf(bfbits2f((unsigned short)(u >> 16)),     scale[c + 1], shiftv[c + 1]);
  v0 = fmaxf(v0, 0.f); v1 = fmaxf(v1, 0.f);
  unsigned w0, w1;
  tf2x32(k0, k1, 0u, idx,      w0, w1); unsigned b0 = w0 ^ w1;
  tf2x32(k0, k1, 0u, idx + 1u, w0, w1); unsigned b1 = w0 ^ w1;
  v0 = (b0 & 0x80000000u) ? 0.f : v0 * 2.f;
  v1 = (b1 & 0x80000000u) ? 0.f : v1 * 2.f;
  ((unsigned*)out)[t] = (unsigned)f2bfbits(v0) | ((unsigned)f2bfbits(v1) << 16);
}

// ============ layer-3 agg (40 ch bf16 pre-scaled) + bias + log_softmax ============
// Two nodes per wave: node = 32-lane half, 20 active sublanes (one u32 = 2 ch each).
__global__ __launch_bounds__(256) void k_agg40lsm(const unsigned short* __restrict__ hw,
                                                  const int* __restrict__ rs,
                                                  const int* __restrict__ csr,
                                                  const float* __restrict__ dinv,
                                                  const float* __restrict__ b3,
                                                  float* __restrict__ out, int N)
{
  int half = (threadIdx.x >> 5) & 1;
  int sl = threadIdx.x & 31;
  int v = blockIdx.x * 8 + threadIdx.y * 2 + half;
  bool nact = (v < N);
  bool act = nact && (sl < 20);
  const unsigned* h2 = (const unsigned*)hw;        // row = 20 u32 (80 B)
  float acx = 0.f, acy = 0.f, dv = 1.f;
  if (act){
    dv = dinv[v];
    ACC2(h2[(size_t)v * 20 + sl]);
    int e0 = rs[v], e1 = rs[v + 1];
    int i = e0;
    for (; i + 4 <= e1; i += 4){
      int s0 = csr[i], s1 = csr[i+1], s2 = csr[i+2], s3 = csr[i+3];
      unsigned u0 = h2[(size_t)s0 * 20 + sl];
      unsigned u1 = h2[(size_t)s1 * 20 + sl];
      unsigned u2 = h2[(size_t)s2 * 20 + sl];
      unsigned u3 = h2[(size_t)s3 * 20 + sl];
      ACC2(u0); ACC2(u1); ACC2(u2); ACC2(u3);
    }
    for (; i < e1; i++){
      ACC2(h2[(size_t)csr[i] * 20 + sl]);
    }
  }
  float x0 = act ? fmaf(acx, dv, b3[2 * sl])     : -INFINITY;
  float x1 = act ? fmaf(acy, dv, b3[2 * sl + 1]) : -INFINITY;
  float m = fmaxf(x0, x1);
  #pragma unroll
  for (int off = 16; off; off >>= 1) m = fmaxf(m, __shfl_xor(m, off, 32));
  float e = act ? (expf(x0 - m) + expf(x1 - m)) : 0.f;
  #pragma unroll
  for (int off = 16; off; off >>= 1) e += __shfl_xor(e, off, 32);
  float lse = m + logf(e);
  if (act){
    float2 o; o.x = x0 - lse; o.y = x1 - lse;
    *reinterpret_cast<float2*>(out + (size_t)v * 40 + 2 * sl) = o;
  }
}

// ================= launch =================
extern "C" void kernel_launch(void* const* d_in, const int* in_sizes, int n_in,
                              void* d_out, int out_size, void* d_ws, size_t ws_size,
                              hipStream_t stream)
{
  const float* x  = (const float*)d_in[0];
  const int* ei   = (const int*)d_in[1];
  const float* W1 = (const float*)d_in[2];
  const float* g1 = (const float*)d_in[4];
  const float* be1= (const float*)d_in[5];
  const float* W2 = (const float*)d_in[6];
  const float* g2 = (const float*)d_in[8];
  const float* be2= (const float*)d_in[9];
  const float* W3 = (const float*)d_in[10];
  const float* b3 = (const float*)d_in[11];
  float* out = (float*)d_out;
  // b1, b2 unused: per-channel constants cancel exactly in training-mode BN.

  const int N = in_sizes[0] / 128;
  const int E = in_sizes[1] / 2;
  const int* srcv = ei;
  const int* dstv = ei + E;

  char* ws = (char*)d_ws;
  size_t off = 0;
  auto take = [&](size_t bytes) -> void* {
    void* p = ws + off;
    off = (off + bytes + 255) & ~(size_t)255;
    return p;
  };
  int*   cnt      = (int*)  take((size_t)2 * N * 4);   // cnt | cursor, one memset
  int*   cursor   = cnt + N;
  int*   rowstart = (int*)  take((size_t)(N + 1) * 4);
  int*   csr      = (int*)  take((size_t)E * 4);
  float* dinv     = (float*)take((size_t)N * 4);
  int*   bsum     = (int*)  take(256 * 4);
  int*   boff     = (int*)  take(256 * 4);
  float* sums     = (float*)take(256 * 4);             // sums | sumsq, one memset
  float* sumsq    = sums + 128;
  float* scale    = (float*)take(128 * 4);
  float* shiftv   = (float*)take(128 * 4);
  unsigned short* WT1 = (unsigned short*)take(128 * 136 * 2);
  unsigned short* WT2 = (unsigned short*)take(128 * 136 * 2);
  unsigned short* WT3 = (unsigned short*)take(48 * 136 * 2);
  unsigned short* bufX = (unsigned short*)take((size_t)N * 128 * 2);
  unsigned short* bufY = (unsigned short*)take((size_t)N * 128 * 2);
  (void)ws_size; (void)n_in; (void)out_size;

  // dropout subkeys: jax.random.split(key(42), 2), partitionable fold
  unsigned l1k0, l1k1, l2k0, l2k1;
  tf2x32(0u, 42u, 0u, 0u, l1k0, l1k1);
  tf2x32(0u, 42u, 0u, 1u, l2k0, l2k1);

  const int NB = (N + 1023) / 1024;
  dim3 wgrid((N + 3) / 4), wblk(64, 4);
  dim3 wgrid8((N + 7) / 8);
  const int ggrid = (N + 127) / 128;
  const long total2 = (long)N * 64;
  const int bnrdg = (int)((total2 + 255) / 256);

  // ---- graph structure ----
  hipMemsetAsync(cnt, 0, (size_t)2 * N * 4, stream);
  k_count<<<(E + 255) / 256, 256, 0, stream>>>(dstv, cnt, E);
  k_blocksum<<<NB, 256, 0, stream>>>(cnt, bsum, N);
  k_scansums<<<1, 256, 0, stream>>>(bsum, boff, rowstart, NB, N);
  k_scanfinal<<<NB, 256, 0, stream>>>(cnt, boff, rowstart, dinv, N);
  k_fill<<<(E + 255) / 256, 256, 0, stream>>>(srcv, dstv, rowstart, cursor, csr, E);
  k_wt<<<3, 256, 0, stream>>>(W1, W2, W3, WT1, WT2, WT3);

  // ---- layer 1 ----
  k_gemm_mfma<8, true><<<ggrid, 256, 0, stream>>>(x, WT1, dinv, bufX, N, 128);
  k_agg128b<<<wgrid, wblk, 0, stream>>>(bufX, rowstart, csr, dinv, bufY, N);
  hipMemsetAsync(sums, 0, 256 * 4, stream);
  k_bnstatsb<<<512, 128, 0, stream>>>(bufY, sums, sumsq, N);
  k_bnfinal<<<1, 128, 0, stream>>>(sums, sumsq, g1, be1, scale, shiftv, N);
  k_bnrdb<<<bnrdg, 256, 0, stream>>>(bufY, bufX, scale, shiftv, l1k0, l1k1, total2);

  // ---- layer 2 ----
  k_gemm_mfma<8, false><<<ggrid, 256, 0, stream>>>(bufX, WT2, dinv, bufY, N, 128);
  k_agg128b<<<wgrid, wblk, 0, stream>>>(bufY, rowstart, csr, dinv, bufX, N);
  hipMemsetAsync(sums, 0, 256 * 4, stream);
  k_bnstatsb<<<512, 128, 0, stream>>>(bufX, sums, sumsq, N);
  k_bnfinal<<<1, 128, 0, stream>>>(sums, sumsq, g2, be2, scale, shiftv, N);
  k_bnrdb<<<bnrdg, 256, 0, stream>>>(bufX, bufY, scale, shiftv, l2k0, l2k1, total2);

  // ---- layer 3 + log_softmax ----
  k_gemm_mfma<3, false><<<ggrid, 256, 0, stream>>>(bufY, WT3, dinv, bufX, N, 40);
  k_agg40lsm<<<wgrid8, wblk, 0, stream>>>(bufX, rowstart, csr, dinv, b3, out, N);
}

// Round 5
// 566.210 us; speedup vs baseline: 1.7496x; 1.0978x over previous
//
#include <hip/hip_runtime.h>
#include <math.h>

typedef __attribute__((ext_vector_type(8))) short bf16x8;
typedef __attribute__((ext_vector_type(4))) float f32x4;

__device__ __forceinline__ float bfbits2f(unsigned short b){
  return __uint_as_float(((unsigned)b) << 16);
}
__device__ __forceinline__ unsigned short f2bfbits(float f){
  unsigned u = __float_as_uint(f);
  unsigned r = u + 0x7fffu + ((u >> 16) & 1u);
  return (unsigned short)(r >> 16);
}

// ================= Threefry-2x32 (JAX partitionable) =================
__host__ __device__ __forceinline__ unsigned rotl32(unsigned v, int d){
  return (v << d) | (v >> (32 - d));
}
__host__ __device__ __forceinline__ void tf2x32(unsigned k0, unsigned k1,
                                                unsigned c0, unsigned c1,
                                                unsigned &o0, unsigned &o1)
{
  unsigned ks2 = k0 ^ k1 ^ 0x1BD11BDAu;
  unsigned x0 = c0 + k0, x1 = c1 + k1;
#define TFR(r) x0 += x1; x1 = rotl32(x1, r); x1 ^= x0;
  TFR(13) TFR(15) TFR(26) TFR(6)
  x0 += k1;  x1 += ks2 + 1u;
  TFR(17) TFR(29) TFR(16) TFR(24)
  x0 += ks2; x1 += k0 + 2u;
  TFR(13) TFR(15) TFR(26) TFR(6)
  x0 += k0;  x1 += k1 + 3u;
  TFR(17) TFR(29) TFR(16) TFR(24)
  x0 += k1;  x1 += ks2 + 4u;
  TFR(13) TFR(15) TFR(26) TFR(6)
  x0 += ks2; x1 += k0 + 5u;
#undef TFR
  o0 = x0; o1 = x1;
}

// ================= CSR build =================
// count + per-edge position (removes the atomic from the fill pass)
__global__ __launch_bounds__(256) void k_countpos(const int* __restrict__ dst,
                                                  int* __restrict__ cnt,
                                                  int* __restrict__ pos, int E)
{
  int g = blockIdx.x * 256 + threadIdx.x;
  int base = g * 4;
  if (base + 3 < E){
    int4 d = ((const int4*)dst)[g];
    int4 p;
    p.x = atomicAdd(&cnt[d.x], 1);
    p.y = atomicAdd(&cnt[d.y], 1);
    p.z = atomicAdd(&cnt[d.z], 1);
    p.w = atomicAdd(&cnt[d.w], 1);
    ((int4*)pos)[g] = p;
  } else {
    for (int j = 0; j < 4; j++){
      int e = base + j;
      if (e < E) pos[e] = atomicAdd(&cnt[dst[e]], 1);
    }
  }
}

__global__ __launch_bounds__(256) void k_blocksum(const int* __restrict__ cnt,
                                                  int* __restrict__ bsum, int N)
{
  __shared__ int sh[256];
  int t = threadIdx.x;
  int base = blockIdx.x * 1024 + t * 4;
  int s = 0;
  #pragma unroll
  for (int j = 0; j < 4; j++){ int i = base + j; if (i < N) s += cnt[i]; }
  sh[t] = s; __syncthreads();
  for (int off = 128; off; off >>= 1){
    if (t < off) sh[t] += sh[t + off];
    __syncthreads();
  }
  if (t == 0) bsum[blockIdx.x] = sh[0];
}

__global__ __launch_bounds__(256) void k_scansums(const int* __restrict__ bsum,
                                                  int* __restrict__ boff,
                                                  int* __restrict__ rowstart,
                                                  int NB, int N)
{
  __shared__ int sh[256];
  int t = threadIdx.x;
  int v = (t < NB) ? bsum[t] : 0;
  sh[t] = v; __syncthreads();
  for (int off = 1; off < 256; off <<= 1){
    int x = sh[t];
    int y = (t >= off) ? sh[t - off] : 0;
    __syncthreads();
    sh[t] = x + y;
    __syncthreads();
  }
  if (t < NB) boff[t] = sh[t] - v;
  if (t == NB - 1) rowstart[N] = sh[t];
}

// scan finalize + dinv (fused)
__global__ __launch_bounds__(256) void k_scanfinal(const int* __restrict__ cnt,
                                                   const int* __restrict__ boff,
                                                   int* __restrict__ rowstart,
                                                   float* __restrict__ dinv, int N)
{
  __shared__ int sh[256];
  int t = threadIdx.x;
  int base = blockIdx.x * 1024 + t * 4;
  int c0 = 0, c1 = 0, c2 = 0, c3 = 0;
  if (base + 0 < N) c0 = cnt[base + 0];
  if (base + 1 < N) c1 = cnt[base + 1];
  if (base + 2 < N) c2 = cnt[base + 2];
  if (base + 3 < N) c3 = cnt[base + 3];
  int s = c0 + c1 + c2 + c3;
  sh[t] = s; __syncthreads();
  for (int off = 1; off < 256; off <<= 1){
    int x = sh[t];
    int y = (t >= off) ? sh[t - off] : 0;
    __syncthreads();
    sh[t] = x + y;
    __syncthreads();
  }
  int excl = sh[t] - s + boff[blockIdx.x];
  if (base + 0 < N){ rowstart[base+0] = excl;          dinv[base+0] = rsqrtf((float)c0 + 1.f); }
  if (base + 1 < N){ rowstart[base+1] = excl+c0;       dinv[base+1] = rsqrtf((float)c1 + 1.f); }
  if (base + 2 < N){ rowstart[base+2] = excl+c0+c1;    dinv[base+2] = rsqrtf((float)c2 + 1.f); }
  if (base + 3 < N){ rowstart[base+3] = excl+c0+c1+c2; dinv[base+3] = rsqrtf((float)c3 + 1.f); }
}

// atomic-free fill: csr[rowstart[d] + pos[e]] = src[e]
__global__ __launch_bounds__(256) void k_fill(const int* __restrict__ src,
                                              const int* __restrict__ dst,
                                              const int* __restrict__ pos,
                                              const int* __restrict__ rowstart,
                                              int* __restrict__ csr, int E)
{
  int g = blockIdx.x * 256 + threadIdx.x;
  int base = g * 4;
  if (base + 3 < E){
    int4 d = ((const int4*)dst)[g];
    int4 p = ((const int4*)pos)[g];
    int4 s = ((const int4*)src)[g];
    int r0 = rowstart[d.x], r1 = rowstart[d.y], r2 = rowstart[d.z], r3 = rowstart[d.w];
    csr[r0 + p.x] = s.x;
    csr[r1 + p.y] = s.y;
    csr[r2 + p.z] = s.z;
    csr[r3 + p.w] = s.w;
  } else {
    for (int j = 0; j < 4; j++){
      int e = base + j;
      if (e < E) csr[rowstart[dst[e]] + pos[e]] = src[e];
    }
  }
}

// ================= weight transpose: WT[n][k] bf16, row stride 136 =================
__global__ __launch_bounds__(256) void k_wt(const float* __restrict__ W1,
                                            const float* __restrict__ W2,
                                            const float* __restrict__ W3,
                                            unsigned short* __restrict__ WT1,
                                            unsigned short* __restrict__ WT2,
                                            unsigned short* __restrict__ WT3)
{
  const float* W; unsigned short* WT; int Cout, Cpad;
  if (blockIdx.x == 0){ W = W1; WT = WT1; Cout = 128; Cpad = 128; }
  else if (blockIdx.x == 1){ W = W2; WT = WT2; Cout = 128; Cpad = 128; }
  else { W = W3; WT = WT3; Cout = 40; Cpad = 48; }
  int tot = Cpad * 136;
  for (int i = threadIdx.x; i < tot; i += 256){
    int n = i / 136, k = i - n * 136;
    float v = (k < 128 && n < Cout) ? W[k * Cout + n] : 0.f;
    WT[i] = f2bfbits(v);
  }
}

// ================= MFMA GEMM (optionally fused BN+ReLU+dropout on A) =========
// MODE 0: A fp32 raw (layer 1). MODE 1: A bf16 raw. MODE 2: A bf16 + BN/ReLU/dropout.
// out[row][col] = (sum_k f(A[row][k]) * W[k][col]) * dinv[row], bf16 store.
template<int NT, int MODE>
__global__ __launch_bounds__(256) void k_gemm_mfma(const void* __restrict__ Ap,
                                                   const unsigned short* __restrict__ WT,
                                                   const float* __restrict__ dinv,
                                                   const float* __restrict__ sums,
                                                   const float* __restrict__ sumsq,
                                                   const float* __restrict__ g,
                                                   const float* __restrict__ be,
                                                   unsigned k0, unsigned k1, float invN,
                                                   unsigned short* __restrict__ outb,
                                                   int N, int Cout)
{
  __shared__ unsigned short Wl[NT * 16 * 136];
  __shared__ float bnS[128], bnB[128];
  const int t = threadIdx.x;
  {
    const uint4* s4 = (const uint4*)WT;
    uint4* d4 = (uint4*)Wl;
    const int tot = NT * 16 * 136 / 8;
    for (int i = t; i < tot; i += 256) d4[i] = s4[i];
  }
  if (MODE == 2 && t < 128){
    float mean = sums[t] * invN;
    float var = fmaxf(sumsq[t] * invN - mean * mean, 0.f);
    float rstd = rsqrtf(var + 1e-5f);
    float sc = g[t] * rstd;
    bnS[t] = sc;
    bnB[t] = be[t] - mean * sc;
  }
  __syncthreads();

  const int w = t >> 6, l = t & 63;
  const int lm = l & 15, q = l >> 4;
  const long rb0 = (long)blockIdx.x * 128 + w * 32;

  f32x4 acc[2][NT];
  #pragma unroll
  for (int rt = 0; rt < 2; rt++)
    #pragma unroll
    for (int nt = 0; nt < NT; nt++){
      acc[rt][nt][0] = 0.f; acc[rt][nt][1] = 0.f;
      acc[rt][nt][2] = 0.f; acc[rt][nt][3] = 0.f;
    }

  #pragma unroll
  for (int kt = 0; kt < 4; kt++){
    const int koff = kt * 32 + q * 8;
    bf16x8 a[2];
    #pragma unroll
    for (int rt = 0; rt < 2; rt++){
      long row = rb0 + rt * 16 + lm;
      if (row >= N) row = N - 1;     // clamp; value discarded at store
      if (MODE == 0){
        const float* ap = (const float*)Ap + row * 128 + koff;
        float4 f0 = *(const float4*)ap;
        float4 f1 = *(const float4*)(ap + 4);
        bf16x8 v;
        v[0] = (short)f2bfbits(f0.x); v[1] = (short)f2bfbits(f0.y);
        v[2] = (short)f2bfbits(f0.z); v[3] = (short)f2bfbits(f0.w);
        v[4] = (short)f2bfbits(f1.x); v[5] = (short)f2bfbits(f1.y);
        v[6] = (short)f2bfbits(f1.z); v[7] = (short)f2bfbits(f1.w);
        a[rt] = v;
      } else if (MODE == 1){
        a[rt] = *(const bf16x8*)((const unsigned short*)Ap + row * 128 + koff);
      } else {
        bf16x8 raw = *(const bf16x8*)((const unsigned short*)Ap + row * 128 + koff);
        unsigned idxb = (unsigned)row * 128u + (unsigned)koff;
        bf16x8 v;
        #pragma unroll
        for (int j = 0; j < 8; j++){
          float f = bfbits2f((unsigned short)raw[j]);
          f = fmaf(f, bnS[koff + j], bnB[koff + j]);
          f = fmaxf(f, 0.f);
          unsigned w0, w1;
          tf2x32(k0, k1, 0u, idxb + (unsigned)j, w0, w1);
          f = ((w0 ^ w1) & 0x80000000u) ? 0.f : f * 2.f;
          v[j] = (short)f2bfbits(f);
        }
        a[rt] = v;
      }
    }
    #pragma unroll
    for (int nt = 0; nt < NT; nt++){
      bf16x8 b = *(const bf16x8*)(&Wl[(nt * 16 + lm) * 136 + koff]);
      acc[0][nt] = __builtin_amdgcn_mfma_f32_16x16x32_bf16(a[0], b, acc[0][nt], 0, 0, 0);
      acc[1][nt] = __builtin_amdgcn_mfma_f32_16x16x32_bf16(a[1], b, acc[1][nt], 0, 0, 0);
    }
  }

  #pragma unroll
  for (int rt = 0; rt < 2; rt++){
    #pragma unroll
    for (int r = 0; r < 4; r++){
      long row = rb0 + rt * 16 + q * 4 + r;
      if (row < N){
        float dv = dinv[row];
        #pragma unroll
        for (int nt = 0; nt < NT; nt++){
          int col = nt * 16 + lm;
          if (col < Cout)
            outb[row * Cout + col] = f2bfbits(acc[rt][nt][r] * dv);
        }
      }
    }
  }
}

// ================= aggregation (128 ch, bf16, rows pre-scaled by dinv) ===========
// 2 nodes per wave: node = 32-lane half, sublane owns 4 channels (uint2).
// out[v] = dinv[v] * ( hw'[v] + sum_{s in nbr(v)} hw'[s] )
#define ACC4(U) do{ uint2 _u = (U); \
  a0 += bfbits2f((unsigned short)(_u.x & 0xffffu)); \
  a1 += bfbits2f((unsigned short)(_u.x >> 16)); \
  a2 += bfbits2f((unsigned short)(_u.y & 0xffffu)); \
  a3 += bfbits2f((unsigned short)(_u.y >> 16)); }while(0)

__global__ __launch_bounds__(256) void k_agg128b(const unsigned short* __restrict__ hw,
                                                 const int* __restrict__ rs,
                                                 const int* __restrict__ csr,
                                                 const float* __restrict__ dinv,
                                                 unsigned short* __restrict__ outb,
                                                 int N)
{
  int half = (threadIdx.x >> 5) & 1;
  int sl = threadIdx.x & 31;
  int v = blockIdx.x * 8 + threadIdx.y * 2 + half;
  if (v >= N) return;
  const uint2* h4 = (const uint2*)hw;              // row = 32 uint2 (256 B)
  float a0 = 0.f, a1 = 0.f, a2 = 0.f, a3 = 0.f;
  ACC4(h4[(size_t)v * 32 + sl]);
  int e0 = rs[v], e1 = rs[v + 1];
  int i = e0;
  for (; i + 4 <= e1; i += 4){
    int s0 = csr[i], s1 = csr[i+1], s2 = csr[i+2], s3 = csr[i+3];
    uint2 m0 = h4[(size_t)s0 * 32 + sl];
    uint2 m1 = h4[(size_t)s1 * 32 + sl];
    uint2 m2 = h4[(size_t)s2 * 32 + sl];
    uint2 m3 = h4[(size_t)s3 * 32 + sl];
    ACC4(m0); ACC4(m1); ACC4(m2); ACC4(m3);
  }
  for (; i < e1; i++){
    ACC4(h4[(size_t)csr[i] * 32 + sl]);
  }
  float dv = dinv[v];
  a0 *= dv; a1 *= dv; a2 *= dv; a3 *= dv;
  uint2 o;
  o.x = (unsigned)f2bfbits(a0) | ((unsigned)f2bfbits(a1) << 16);
  o.y = (unsigned)f2bfbits(a2) | ((unsigned)f2bfbits(a3) << 16);
  ((uint2*)outb)[(size_t)v * 32 + sl] = o;
}

// ================= BatchNorm stats =================
__global__ __launch_bounds__(128) void k_bnstatsb(const unsigned short* __restrict__ h,
                                                  float* __restrict__ sums,
                                                  float* __restrict__ sumsq, int N)
{
  int c = threadIdx.x;
  float s = 0.f, qq = 0.f;
  for (int r = blockIdx.x; r < N; r += gridDim.x){
    float v = bfbits2f(h[(size_t)r * 128 + c]);
    s += v; qq = fmaf(v, v, qq);
  }
  atomicAdd(&sums[c], s);
  atomicAdd(&sumsq[c], qq);
}

// ============ layer-3 agg (40 ch bf16 pre-scaled) + bias + log_softmax ============
#define ACC2(U) do{ unsigned _u = (U); \
  acx += bfbits2f((unsigned short)(_u & 0xffffu)); \
  acy += bfbits2f((unsigned short)(_u >> 16)); }while(0)

__global__ __launch_bounds__(256) void k_agg40lsm(const unsigned short* __restrict__ hw,
                                                  const int* __restrict__ rs,
                                                  const int* __restrict__ csr,
                                                  const float* __restrict__ dinv,
                                                  const float* __restrict__ b3,
                                                  float* __restrict__ out, int N)
{
  int half = (threadIdx.x >> 5) & 1;
  int sl = threadIdx.x & 31;
  int v = blockIdx.x * 8 + threadIdx.y * 2 + half;
  bool nact = (v < N);
  bool act = nact && (sl < 20);
  const unsigned* h2 = (const unsigned*)hw;        // row = 20 u32 (80 B)
  float acx = 0.f, acy = 0.f, dv = 1.f;
  if (act){
    dv = dinv[v];
    ACC2(h2[(size_t)v * 20 + sl]);
    int e0 = rs[v], e1 = rs[v + 1];
    int i = e0;
    for (; i + 4 <= e1; i += 4){
      int s0 = csr[i], s1 = csr[i+1], s2 = csr[i+2], s3 = csr[i+3];
      unsigned u0 = h2[(size_t)s0 * 20 + sl];
      unsigned u1 = h2[(size_t)s1 * 20 + sl];
      unsigned u2 = h2[(size_t)s2 * 20 + sl];
      unsigned u3 = h2[(size_t)s3 * 20 + sl];
      ACC2(u0); ACC2(u1); ACC2(u2); ACC2(u3);
    }
    for (; i < e1; i++){
      ACC2(h2[(size_t)csr[i] * 20 + sl]);
    }
  }
  float x0 = act ? fmaf(acx, dv, b3[2 * sl])     : -INFINITY;
  float x1 = act ? fmaf(acy, dv, b3[2 * sl + 1]) : -INFINITY;
  float m = fmaxf(x0, x1);
  #pragma unroll
  for (int off = 16; off; off >>= 1) m = fmaxf(m, __shfl_xor(m, off, 32));
  float e = act ? (expf(x0 - m) + expf(x1 - m)) : 0.f;
  #pragma unroll
  for (int off = 16; off; off >>= 1) e += __shfl_xor(e, off, 32);
  float lse = m + logf(e);
  if (act){
    float2 o; o.x = x0 - lse; o.y = x1 - lse;
    *reinterpret_cast<float2*>(out + (size_t)v * 40 + 2 * sl) = o;
  }
}

// ================= launch =================
extern "C" void kernel_launch(void* const* d_in, const int* in_sizes, int n_in,
                              void* d_out, int out_size, void* d_ws, size_t ws_size,
                              hipStream_t stream)
{
  const float* x  = (const float*)d_in[0];
  const int* ei   = (const int*)d_in[1];
  const float* W1 = (const float*)d_in[2];
  const float* g1 = (const float*)d_in[4];
  const float* be1= (const float*)d_in[5];
  const float* W2 = (const float*)d_in[6];
  const float* g2 = (const float*)d_in[8];
  const float* be2= (const float*)d_in[9];
  const float* W3 = (const float*)d_in[10];
  const float* b3 = (const float*)d_in[11];
  float* out = (float*)d_out;
  // b1, b2 unused: per-channel constants cancel exactly in training-mode BN.

  const int N = in_sizes[0] / 128;
  const int E = in_sizes[1] / 2;
  const int* srcv = ei;
  const int* dstv = ei + E;

  char* ws = (char*)d_ws;
  size_t off = 0;
  auto take = [&](size_t bytes) -> void* {
    void* p = ws + off;
    off = (off + bytes + 255) & ~(size_t)255;
    return p;
  };
  int*   cnt      = (int*)  take((size_t)N * 4);
  int*   pos      = (int*)  take((size_t)E * 4);
  int*   rowstart = (int*)  take((size_t)(N + 1) * 4);
  int*   csr      = (int*)  take((size_t)E * 4);
  float* dinv     = (float*)take((size_t)N * 4);
  int*   bsum     = (int*)  take(256 * 4);
  int*   boff     = (int*)  take(256 * 4);
  float* sums     = (float*)take(256 * 4);             // sums | sumsq, one memset
  float* sumsq    = sums + 128;
  unsigned short* WT1 = (unsigned short*)take(128 * 136 * 2);
  unsigned short* WT2 = (unsigned short*)take(128 * 136 * 2);
  unsigned short* WT3 = (unsigned short*)take(48 * 136 * 2);
  unsigned short* bufX = (unsigned short*)take((size_t)N * 128 * 2);
  unsigned short* bufY = (unsigned short*)take((size_t)N * 128 * 2);
  (void)ws_size; (void)n_in; (void)out_size;

  // dropout subkeys: jax.random.split(key(42), 2), partitionable fold
  unsigned l1k0, l1k1, l2k0, l2k1;
  tf2x32(0u, 42u, 0u, 0u, l1k0, l1k1);
  tf2x32(0u, 42u, 0u, 1u, l2k0, l2k1);

  const float invN = 1.0f / (float)N;
  const int NB = (N + 1023) / 1024;
  dim3 wgrid8((N + 7) / 8), wblk(64, 4);
  const int ggrid = (N + 127) / 128;
  const int egrid = (E + 1023) / 1024;

  // ---- graph structure ----
  hipMemsetAsync(cnt, 0, (size_t)N * 4, stream);
  k_countpos<<<egrid, 256, 0, stream>>>(dstv, cnt, pos, E);
  k_blocksum<<<NB, 256, 0, stream>>>(cnt, bsum, N);
  k_scansums<<<1, 256, 0, stream>>>(bsum, boff, rowstart, NB, N);
  k_scanfinal<<<NB, 256, 0, stream>>>(cnt, boff, rowstart, dinv, N);
  k_fill<<<egrid, 256, 0, stream>>>(srcv, dstv, pos, rowstart, csr, E);
  k_wt<<<3, 256, 0, stream>>>(W1, W2, W3, WT1, WT2, WT3);

  // ---- layer 1 ----
  k_gemm_mfma<8, 0><<<ggrid, 256, 0, stream>>>(x, WT1, dinv,
      nullptr, nullptr, nullptr, nullptr, 0u, 0u, invN, bufX, N, 128);
  k_agg128b<<<wgrid8, wblk, 0, stream>>>(bufX, rowstart, csr, dinv, bufY, N);
  hipMemsetAsync(sums, 0, 256 * 4, stream);
  k_bnstatsb<<<512, 128, 0, stream>>>(bufY, sums, sumsq, N);

  // ---- layer 2 (BN1+ReLU+dropout fused into A-load) ----
  k_gemm_mfma<8, 2><<<ggrid, 256, 0, stream>>>(bufY, WT2, dinv,
      sums, sumsq, g1, be1, l1k0, l1k1, invN, bufX, N, 128);
  k_agg128b<<<wgrid8, wblk, 0, stream>>>(bufX, rowstart, csr, dinv, bufY, N);
  hipMemsetAsync(sums, 0, 256 * 4, stream);
  k_bnstatsb<<<512, 128, 0, stream>>>(bufY, sums, sumsq, N);

  // ---- layer 3 (BN2+ReLU+dropout fused) + log_softmax ----
  k_gemm_mfma<3, 2><<<ggrid, 256, 0, stream>>>(bufY, WT3, dinv,
      sums, sumsq, g2, be2, l2k0, l2k1, invN, bufX, N, 40);
  k_agg40lsm<<<wgrid8, wblk, 0, stream>>>(bufX, rowstart, csr, dinv, b3, out, N);
}

// Round 6
// 540.346 us; speedup vs baseline: 1.8333x; 1.0479x over previous
//
#include <hip/hip_runtime.h>
#include <math.h>

typedef __attribute__((ext_vector_type(8))) short bf16x8;
typedef __attribute__((ext_vector_type(4))) float f32x4;

__device__ __forceinline__ float bfbits2f(unsigned short b){
  return __uint_as_float(((unsigned)b) << 16);
}
__device__ __forceinline__ unsigned short f2bfbits(float f){
  unsigned u = __float_as_uint(f);
  unsigned r = u + 0x7fffu + ((u >> 16) & 1u);
  return (unsigned short)(r >> 16);
}

// ================= Threefry-2x32 (JAX partitionable) =================
__host__ __device__ __forceinline__ unsigned rotl32(unsigned v, int d){
  return (v << d) | (v >> (32 - d));
}
__host__ __device__ __forceinline__ void tf2x32(unsigned k0, unsigned k1,
                                                unsigned c0, unsigned c1,
                                                unsigned &o0, unsigned &o1)
{
  unsigned ks2 = k0 ^ k1 ^ 0x1BD11BDAu;
  unsigned x0 = c0 + k0, x1 = c1 + k1;
#define TFR(r) x0 += x1; x1 = rotl32(x1, r); x1 ^= x0;
  TFR(13) TFR(15) TFR(26) TFR(6)
  x0 += k1;  x1 += ks2 + 1u;
  TFR(17) TFR(29) TFR(16) TFR(24)
  x0 += ks2; x1 += k0 + 2u;
  TFR(13) TFR(15) TFR(26) TFR(6)
  x0 += k0;  x1 += k1 + 3u;
  TFR(17) TFR(29) TFR(16) TFR(24)
  x0 += k1;  x1 += ks2 + 4u;
  TFR(13) TFR(15) TFR(26) TFR(6)
  x0 += ks2; x1 += k0 + 5u;
#undef TFR
  o0 = x0; o1 = x1;
}

// ================= CSR build =================
__global__ __launch_bounds__(256) void k_countpos(const int* __restrict__ dst,
                                                  int* __restrict__ cnt,
                                                  int* __restrict__ pos, int E)
{
  int g = blockIdx.x * 256 + threadIdx.x;
  int base = g * 4;
  if (base + 3 < E){
    int4 d = ((const int4*)dst)[g];
    int4 p;
    p.x = atomicAdd(&cnt[d.x], 1);
    p.y = atomicAdd(&cnt[d.y], 1);
    p.z = atomicAdd(&cnt[d.z], 1);
    p.w = atomicAdd(&cnt[d.w], 1);
    ((int4*)pos)[g] = p;
  } else {
    for (int j = 0; j < 4; j++){
      int e = base + j;
      if (e < E) pos[e] = atomicAdd(&cnt[dst[e]], 1);
    }
  }
}

__global__ __launch_bounds__(256) void k_blocksum(const int* __restrict__ cnt,
                                                  int* __restrict__ bsum, int N)
{
  __shared__ int sh[256];
  int t = threadIdx.x;
  int base = blockIdx.x * 1024 + t * 4;
  int s = 0;
  #pragma unroll
  for (int j = 0; j < 4; j++){ int i = base + j; if (i < N) s += cnt[i]; }
  sh[t] = s; __syncthreads();
  for (int off = 128; off; off >>= 1){
    if (t < off) sh[t] += sh[t + off];
    __syncthreads();
  }
  if (t == 0) bsum[blockIdx.x] = sh[0];
}

__global__ __launch_bounds__(256) void k_scansums(const int* __restrict__ bsum,
                                                  int* __restrict__ boff,
                                                  int* __restrict__ rowstart,
                                                  int NB, int N)
{
  __shared__ int sh[256];
  int t = threadIdx.x;
  int v = (t < NB) ? bsum[t] : 0;
  sh[t] = v; __syncthreads();
  for (int off = 1; off < 256; off <<= 1){
    int x = sh[t];
    int y = (t >= off) ? sh[t - off] : 0;
    __syncthreads();
    sh[t] = x + y;
    __syncthreads();
  }
  if (t < NB) boff[t] = sh[t] - v;
  if (t == NB - 1) rowstart[N] = sh[t];
}

__global__ __launch_bounds__(256) void k_scanfinal(const int* __restrict__ cnt,
                                                   const int* __restrict__ boff,
                                                   int* __restrict__ rowstart,
                                                   float* __restrict__ dinv, int N)
{
  __shared__ int sh[256];
  int t = threadIdx.x;
  int base = blockIdx.x * 1024 + t * 4;
  int c0 = 0, c1 = 0, c2 = 0, c3 = 0;
  if (base + 0 < N) c0 = cnt[base + 0];
  if (base + 1 < N) c1 = cnt[base + 1];
  if (base + 2 < N) c2 = cnt[base + 2];
  if (base + 3 < N) c3 = cnt[base + 3];
  int s = c0 + c1 + c2 + c3;
  sh[t] = s; __syncthreads();
  for (int off = 1; off < 256; off <<= 1){
    int x = sh[t];
    int y = (t >= off) ? sh[t - off] : 0;
    __syncthreads();
    sh[t] = x + y;
    __syncthreads();
  }
  int excl = sh[t] - s + boff[blockIdx.x];
  if (base + 0 < N){ rowstart[base+0] = excl;          dinv[base+0] = rsqrtf((float)c0 + 1.f); }
  if (base + 1 < N){ rowstart[base+1] = excl+c0;       dinv[base+1] = rsqrtf((float)c1 + 1.f); }
  if (base + 2 < N){ rowstart[base+2] = excl+c0+c1;    dinv[base+2] = rsqrtf((float)c2 + 1.f); }
  if (base + 3 < N){ rowstart[base+3] = excl+c0+c1+c2; dinv[base+3] = rsqrtf((float)c3 + 1.f); }
}

__global__ __launch_bounds__(256) void k_fill(const int* __restrict__ src,
                                              const int* __restrict__ dst,
                                              const int* __restrict__ pos,
                                              const int* __restrict__ rowstart,
                                              int* __restrict__ csr, int E)
{
  int g = blockIdx.x * 256 + threadIdx.x;
  int base = g * 4;
  if (base + 3 < E){
    int4 d = ((const int4*)dst)[g];
    int4 p = ((const int4*)pos)[g];
    int4 s = ((const int4*)src)[g];
    int r0 = rowstart[d.x], r1 = rowstart[d.y], r2 = rowstart[d.z], r3 = rowstart[d.w];
    csr[r0 + p.x] = s.x;
    csr[r1 + p.y] = s.y;
    csr[r2 + p.z] = s.z;
    csr[r3 + p.w] = s.w;
  } else {
    for (int j = 0; j < 4; j++){
      int e = base + j;
      if (e < E) csr[rowstart[dst[e]] + pos[e]] = src[e];
    }
  }
}

// ================= weight transpose: WT[n][k] bf16, row stride 136 =================
__global__ __launch_bounds__(256) void k_wt(const float* __restrict__ W1,
                                            const float* __restrict__ W2,
                                            const float* __restrict__ W3,
                                            unsigned short* __restrict__ WT1,
                                            unsigned short* __restrict__ WT2,
                                            unsigned short* __restrict__ WT3)
{
  const float* W; unsigned short* WT; int Cout, Cpad;
  if (blockIdx.x == 0){ W = W1; WT = WT1; Cout = 128; Cpad = 128; }
  else if (blockIdx.x == 1){ W = W2; WT = WT2; Cout = 128; Cpad = 128; }
  else { W = W3; WT = WT3; Cout = 40; Cpad = 48; }
  int tot = Cpad * 136;
  for (int i = threadIdx.x; i < tot; i += 256){
    int n = i / 136, k = i - n * 136;
    float v = (k < 128 && n < Cout) ? W[k * Cout + n] : 0.f;
    WT[i] = f2bfbits(v);
  }
}

// ================= MFMA GEMM, LDS-staged A =================
// MODE 0: A fp32 raw (layer 1). MODE 2: A bf16 + fused BN/ReLU/dropout.
// Tile: 64 rows x NT*16 cols; 256 thr = 4 waves x 16 rows.
// A staged in LDS as 16-B chunks, phys chunk = c ^ (r&15)  (conflict-free-ish:
// frag read has r&15==lm -> 2-way bank aliasing = free).
template<int NT, int MODE>
__global__ __launch_bounds__(256) void k_gemm_mfma(const void* __restrict__ Ap,
                                                   const unsigned short* __restrict__ WT,
                                                   const float* __restrict__ dinv,
                                                   const float* __restrict__ sums,
                                                   const float* __restrict__ sumsq,
                                                   const float* __restrict__ g,
                                                   const float* __restrict__ be,
                                                   unsigned k0, unsigned k1, float invN,
                                                   unsigned short* __restrict__ outb,
                                                   int N, int Cout)
{
  __shared__ uint4 Wl4[NT * 16 * 17];          // NT*16 rows x 136 shorts
  __shared__ uint4 Al4[64 * 16];               // 64 rows x 16 chunks (swizzled)
  __shared__ float bnS[128], bnB[128];
  unsigned short* Wl = (unsigned short*)Wl4;
  const int t = threadIdx.x;
  const long rb0 = (long)blockIdx.x * 64;

  {
    const uint4* s4 = (const uint4*)WT;
    const int tot = NT * 16 * 17;
    for (int i = t; i < tot; i += 256) Wl4[i] = s4[i];
  }
  if (MODE == 2 && t < 128){
    float mean = sums[t] * invN;
    float var = fmaxf(sumsq[t] * invN - mean * mean, 0.f);
    float rstd = rsqrtf(var + 1e-5f);
    float sc = g[t] * rstd;
    bnS[t] = sc;
    bnB[t] = be[t] - mean * sc;
  }
  if (MODE == 2) __syncthreads();              // bnS/bnB ready for staging

  // ---- stage A: 1024 chunks, coalesced global reads, swizzled LDS writes ----
  #pragma unroll
  for (int i = 0; i < 4; i++){
    int idx = i * 256 + t;
    int r = idx >> 4, c = idx & 15;
    long grow = rb0 + r;
    uint4 chunk = make_uint4(0u, 0u, 0u, 0u);
    if (grow < N){
      if (MODE == 0){
        const float* ap = (const float*)Ap + grow * 128 + c * 8;
        float4 f0 = *(const float4*)ap;
        float4 f1 = *(const float4*)(ap + 4);
        chunk.x = (unsigned)f2bfbits(f0.x) | ((unsigned)f2bfbits(f0.y) << 16);
        chunk.y = (unsigned)f2bfbits(f0.z) | ((unsigned)f2bfbits(f0.w) << 16);
        chunk.z = (unsigned)f2bfbits(f1.x) | ((unsigned)f2bfbits(f1.y) << 16);
        chunk.w = (unsigned)f2bfbits(f1.z) | ((unsigned)f2bfbits(f1.w) << 16);
      } else {
        uint4 raw = *(const uint4*)((const unsigned short*)Ap + grow * 128 + c * 8);
        unsigned idxb = (unsigned)grow * 128u + (unsigned)(c * 8);
        const unsigned* rw = &raw.x;
        unsigned* cw = &chunk.x;
        #pragma unroll
        for (int h = 0; h < 4; h++){
          int ch = c * 8 + 2 * h;
          float f0 = bfbits2f((unsigned short)(rw[h] & 0xffffu));
          float f1 = bfbits2f((unsigned short)(rw[h] >> 16));
          f0 = fmaxf(fmaf(f0, bnS[ch],     bnB[ch]),     0.f);
          f1 = fmaxf(fmaf(f1, bnS[ch + 1], bnB[ch + 1]), 0.f);
          unsigned w0, w1;
          tf2x32(k0, k1, 0u, idxb + 2u * h,      w0, w1);
          f0 = ((w0 ^ w1) & 0x80000000u) ? 0.f : f0 * 2.f;
          tf2x32(k0, k1, 0u, idxb + 2u * h + 1u, w0, w1);
          f1 = ((w0 ^ w1) & 0x80000000u) ? 0.f : f1 * 2.f;
          cw[h] = (unsigned)f2bfbits(f0) | ((unsigned)f2bfbits(f1) << 16);
        }
      }
    }
    Al4[r * 16 + (c ^ (r & 15))] = chunk;
  }
  __syncthreads();

  const int w = t >> 6, l = t & 63;
  const int lm = l & 15, q = l >> 4;

  f32x4 acc[NT];
  #pragma unroll
  for (int nt = 0; nt < NT; nt++){
    acc[nt][0] = 0.f; acc[nt][1] = 0.f; acc[nt][2] = 0.f; acc[nt][3] = 0.f;
  }

  const int arow = w * 16 + lm;
  #pragma unroll
  for (int kt = 0; kt < 4; kt++){
    const int koff = kt * 32 + q * 8;
    bf16x8 a = *(const bf16x8*)&((const unsigned short*)Al4)[arow * 128 + (((kt * 4 + q) ^ lm) * 8)];
    #pragma unroll
    for (int nt = 0; nt < NT; nt++){
      bf16x8 b = *(const bf16x8*)(&Wl[(nt * 16 + lm) * 136 + koff]);
      acc[nt] = __builtin_amdgcn_mfma_f32_16x16x32_bf16(a, b, acc[nt], 0, 0, 0);
    }
  }

  #pragma unroll
  for (int r = 0; r < 4; r++){
    long row = rb0 + w * 16 + q * 4 + r;
    if (row < N){
      float dv = dinv[row];
      #pragma unroll
      for (int nt = 0; nt < NT; nt++){
        int col = nt * 16 + lm;
        if (col < Cout)
          outb[row * Cout + col] = f2bfbits(acc[nt][r] * dv);
      }
    }
  }
}

// ================= aggregation (128 ch, bf16, rows pre-scaled by dinv) ===========
#define ACC4(U) do{ uint2 _u = (U); \
  a0 += bfbits2f((unsigned short)(_u.x & 0xffffu)); \
  a1 += bfbits2f((unsigned short)(_u.x >> 16)); \
  a2 += bfbits2f((unsigned short)(_u.y & 0xffffu)); \
  a3 += bfbits2f((unsigned short)(_u.y >> 16)); }while(0)

__global__ __launch_bounds__(256) void k_agg128b(const unsigned short* __restrict__ hw,
                                                 const int* __restrict__ rs,
                                                 const int* __restrict__ csr,
                                                 const float* __restrict__ dinv,
                                                 unsigned short* __restrict__ outb,
                                                 int N)
{
  int half = (threadIdx.x >> 5) & 1;
  int sl = threadIdx.x & 31;
  int v = blockIdx.x * 8 + threadIdx.y * 2 + half;
  if (v >= N) return;
  const uint2* h4 = (const uint2*)hw;              // row = 32 uint2 (256 B)
  float a0 = 0.f, a1 = 0.f, a2 = 0.f, a3 = 0.f;
  ACC4(h4[(size_t)v * 32 + sl]);
  int e0 = rs[v], e1 = rs[v + 1];
  int i = e0;
  for (; i + 4 <= e1; i += 4){
    int s0 = csr[i], s1 = csr[i+1], s2 = csr[i+2], s3 = csr[i+3];
    uint2 m0 = h4[(size_t)s0 * 32 + sl];
    uint2 m1 = h4[(size_t)s1 * 32 + sl];
    uint2 m2 = h4[(size_t)s2 * 32 + sl];
    uint2 m3 = h4[(size_t)s3 * 32 + sl];
    ACC4(m0); ACC4(m1); ACC4(m2); ACC4(m3);
  }
  for (; i < e1; i++){
    ACC4(h4[(size_t)csr[i] * 32 + sl]);
  }
  float dv = dinv[v];
  a0 *= dv; a1 *= dv; a2 *= dv; a3 *= dv;
  uint2 o;
  o.x = (unsigned)f2bfbits(a0) | ((unsigned)f2bfbits(a1) << 16);
  o.y = (unsigned)f2bfbits(a2) | ((unsigned)f2bfbits(a3) << 16);
  ((uint2*)outb)[(size_t)v * 32 + sl] = o;
}

// ================= BatchNorm stats =================
__global__ __launch_bounds__(128) void k_bnstatsb(const unsigned short* __restrict__ h,
                                                  float* __restrict__ sums,
                                                  float* __restrict__ sumsq, int N)
{
  int c = threadIdx.x;
  float s = 0.f, qq = 0.f;
  for (int r = blockIdx.x; r < N; r += gridDim.x){
    float v = bfbits2f(h[(size_t)r * 128 + c]);
    s += v; qq = fmaf(v, v, qq);
  }
  atomicAdd(&sums[c], s);
  atomicAdd(&sumsq[c], qq);
}

// ============ layer-3 agg (40 ch bf16 pre-scaled) + bias + log_softmax ============
#define ACC2(U) do{ unsigned _u = (U); \
  acx += bfbits2f((unsigned short)(_u & 0xffffu)); \
  acy += bfbits2f((unsigned short)(_u >> 16)); }while(0)

__global__ __launch_bounds__(256) void k_agg40lsm(const unsigned short* __restrict__ hw,
                                                  const int* __restrict__ rs,
                                                  const int* __restrict__ csr,
                                                  const float* __restrict__ dinv,
                                                  const float* __restrict__ b3,
                                                  float* __restrict__ out, int N)
{
  int half = (threadIdx.x >> 5) & 1;
  int sl = threadIdx.x & 31;
  int v = blockIdx.x * 8 + threadIdx.y * 2 + half;
  bool nact = (v < N);
  bool act = nact && (sl < 20);
  const unsigned* h2 = (const unsigned*)hw;        // row = 20 u32 (80 B)
  float acx = 0.f, acy = 0.f, dv = 1.f;
  if (act){
    dv = dinv[v];
    ACC2(h2[(size_t)v * 20 + sl]);
    int e0 = rs[v], e1 = rs[v + 1];
    int i = e0;
    for (; i + 4 <= e1; i += 4){
      int s0 = csr[i], s1 = csr[i+1], s2 = csr[i+2], s3 = csr[i+3];
      unsigned u0 = h2[(size_t)s0 * 20 + sl];
      unsigned u1 = h2[(size_t)s1 * 20 + sl];
      unsigned u2 = h2[(size_t)s2 * 20 + sl];
      unsigned u3 = h2[(size_t)s3 * 20 + sl];
      ACC2(u0); ACC2(u1); ACC2(u2); ACC2(u3);
    }
    for (; i < e1; i++){
      ACC2(h2[(size_t)csr[i] * 20 + sl]);
    }
  }
  float x0 = act ? fmaf(acx, dv, b3[2 * sl])     : -INFINITY;
  float x1 = act ? fmaf(acy, dv, b3[2 * sl + 1]) : -INFINITY;
  float m = fmaxf(x0, x1);
  #pragma unroll
  for (int off = 16; off; off >>= 1) m = fmaxf(m, __shfl_xor(m, off, 32));
  float e = act ? (expf(x0 - m) + expf(x1 - m)) : 0.f;
  #pragma unroll
  for (int off = 16; off; off >>= 1) e += __shfl_xor(e, off, 32);
  float lse = m + logf(e);
  if (act){
    float2 o; o.x = x0 - lse; o.y = x1 - lse;
    *reinterpret_cast<float2*>(out + (size_t)v * 40 + 2 * sl) = o;
  }
}

// ================= launch =================
extern "C" void kernel_launch(void* const* d_in, const int* in_sizes, int n_in,
                              void* d_out, int out_size, void* d_ws, size_t ws_size,
                              hipStream_t stream)
{
  const float* x  = (const float*)d_in[0];
  const int* ei   = (const int*)d_in[1];
  const float* W1 = (const float*)d_in[2];
  const float* g1 = (const float*)d_in[4];
  const float* be1= (const float*)d_in[5];
  const float* W2 = (const float*)d_in[6];
  const float* g2 = (const float*)d_in[8];
  const float* be2= (const float*)d_in[9];
  const float* W3 = (const float*)d_in[10];
  const float* b3 = (const float*)d_in[11];
  float* out = (float*)d_out;
  // b1, b2 unused: per-channel constants cancel exactly in training-mode BN.

  const int N = in_sizes[0] / 128;
  const int E = in_sizes[1] / 2;
  const int* srcv = ei;
  const int* dstv = ei + E;

  char* ws = (char*)d_ws;
  size_t off = 0;
  auto take = [&](size_t bytes) -> void* {
    void* p = ws + off;
    off = (off + bytes + 255) & ~(size_t)255;
    return p;
  };
  int*   cnt      = (int*)  take((size_t)N * 4);
  int*   pos      = (int*)  take((size_t)E * 4);
  int*   rowstart = (int*)  take((size_t)(N + 1) * 4);
  int*   csr      = (int*)  take((size_t)E * 4);
  float* dinv     = (float*)take((size_t)N * 4);
  int*   bsum     = (int*)  take(256 * 4);
  int*   boff     = (int*)  take(256 * 4);
  float* sums     = (float*)take(256 * 4);             // sums | sumsq, one memset
  float* sumsq    = sums + 128;
  unsigned short* WT1 = (unsigned short*)take(128 * 136 * 2);
  unsigned short* WT2 = (unsigned short*)take(128 * 136 * 2);
  unsigned short* WT3 = (unsigned short*)take(48 * 136 * 2);
  unsigned short* bufX = (unsigned short*)take((size_t)N * 128 * 2);
  unsigned short* bufY = (unsigned short*)take((size_t)N * 128 * 2);
  (void)ws_size; (void)n_in; (void)out_size;

  // dropout subkeys: jax.random.split(key(42), 2), partitionable fold
  unsigned l1k0, l1k1, l2k0, l2k1;
  tf2x32(0u, 42u, 0u, 0u, l1k0, l1k1);
  tf2x32(0u, 42u, 0u, 1u, l2k0, l2k1);

  const float invN = 1.0f / (float)N;
  const int NB = (N + 1023) / 1024;
  dim3 wgrid8((N + 7) / 8), wblk(64, 4);
  const int ggrid = (N + 63) / 64;
  const int egrid = (E + 1023) / 1024;

  // ---- graph structure ----
  hipMemsetAsync(cnt, 0, (size_t)N * 4, stream);
  k_countpos<<<egrid, 256, 0, stream>>>(dstv, cnt, pos, E);
  k_blocksum<<<NB, 256, 0, stream>>>(cnt, bsum, N);
  k_scansums<<<1, 256, 0, stream>>>(bsum, boff, rowstart, NB, N);
  k_scanfinal<<<NB, 256, 0, stream>>>(cnt, boff, rowstart, dinv, N);
  k_fill<<<egrid, 256, 0, stream>>>(srcv, dstv, pos, rowstart, csr, E);
  k_wt<<<3, 256, 0, stream>>>(W1, W2, W3, WT1, WT2, WT3);

  // ---- layer 1 ----
  k_gemm_mfma<8, 0><<<ggrid, 256, 0, stream>>>(x, WT1, dinv,
      nullptr, nullptr, nullptr, nullptr, 0u, 0u, invN, bufX, N, 128);
  k_agg128b<<<wgrid8, wblk, 0, stream>>>(bufX, rowstart, csr, dinv, bufY, N);
  hipMemsetAsync(sums, 0, 256 * 4, stream);
  k_bnstatsb<<<512, 128, 0, stream>>>(bufY, sums, sumsq, N);

  // ---- layer 2 (BN1+ReLU+dropout fused into A staging) ----
  k_gemm_mfma<8, 2><<<ggrid, 256, 0, stream>>>(bufY, WT2, dinv,
      sums, sumsq, g1, be1, l1k0, l1k1, invN, bufX, N, 128);
  k_agg128b<<<wgrid8, wblk, 0, stream>>>(bufX, rowstart, csr, dinv, bufY, N);
  hipMemsetAsync(sums, 0, 256 * 4, stream);
  k_bnstatsb<<<512, 128, 0, stream>>>(bufY, sums, sumsq, N);

  // ---- layer 3 (BN2+ReLU+dropout fused) + log_softmax ----
  k_gemm_mfma<3, 2><<<ggrid, 256, 0, stream>>>(bufY, WT3, dinv,
      sums, sumsq, g2, be2, l2k0, l2k1, invN, bufX, N, 40);
  k_agg40lsm<<<wgrid8, wblk, 0, stream>>>(bufX, rowstart, csr, dinv, b3, out, N);
}

// Round 7
// 486.056 us; speedup vs baseline: 2.0381x; 1.1117x over previous
//
#include <hip/hip_runtime.h>
#include <math.h>

typedef __attribute__((ext_vector_type(8))) short bf16x8;
typedef __attribute__((ext_vector_type(4))) float f32x4;

__device__ __forceinline__ float bfbits2f(unsigned short b){
  return __uint_as_float(((unsigned)b) << 16);
}
__device__ __forceinline__ unsigned short f2bfbits(float f){
  unsigned u = __float_as_uint(f);
  unsigned r = u + 0x7fffu + ((u >> 16) & 1u);
  return (unsigned short)(r >> 16);
}

// ================= Threefry-2x32 (JAX partitionable) =================
__host__ __device__ __forceinline__ unsigned rotl32(unsigned v, int d){
  return (v << d) | (v >> (32 - d));
}
__host__ __device__ __forceinline__ void tf2x32(unsigned k0, unsigned k1,
                                                unsigned c0, unsigned c1,
                                                unsigned &o0, unsigned &o1)
{
  unsigned ks2 = k0 ^ k1 ^ 0x1BD11BDAu;
  unsigned x0 = c0 + k0, x1 = c1 + k1;
#define TFR(r) x0 += x1; x1 = rotl32(x1, r); x1 ^= x0;
  TFR(13) TFR(15) TFR(26) TFR(6)
  x0 += k1;  x1 += ks2 + 1u;
  TFR(17) TFR(29) TFR(16) TFR(24)
  x0 += ks2; x1 += k0 + 2u;
  TFR(13) TFR(15) TFR(26) TFR(6)
  x0 += k0;  x1 += k1 + 3u;
  TFR(17) TFR(29) TFR(16) TFR(24)
  x0 += k1;  x1 += ks2 + 4u;
  TFR(13) TFR(15) TFR(26) TFR(6)
  x0 += ks2; x1 += k0 + 5u;
#undef TFR
  o0 = x0; o1 = x1;
}

// ================= CSR build =================
__global__ __launch_bounds__(256) void k_countpos(const int* __restrict__ dst,
                                                  int* __restrict__ cnt,
                                                  int* __restrict__ pos, int E)
{
  int g = blockIdx.x * 256 + threadIdx.x;
  int base = g * 4;
  if (base + 3 < E){
    int4 d = ((const int4*)dst)[g];
    int4 p;
    p.x = atomicAdd(&cnt[d.x], 1);
    p.y = atomicAdd(&cnt[d.y], 1);
    p.z = atomicAdd(&cnt[d.z], 1);
    p.w = atomicAdd(&cnt[d.w], 1);
    ((int4*)pos)[g] = p;
  } else {
    for (int j = 0; j < 4; j++){
      int e = base + j;
      if (e < E) pos[e] = atomicAdd(&cnt[dst[e]], 1);
    }
  }
}

__global__ __launch_bounds__(256) void k_blocksum(const int* __restrict__ cnt,
                                                  int* __restrict__ bsum, int N)
{
  __shared__ int sh[256];
  int t = threadIdx.x;
  int base = blockIdx.x * 1024 + t * 4;
  int s = 0;
  #pragma unroll
  for (int j = 0; j < 4; j++){ int i = base + j; if (i < N) s += cnt[i]; }
  sh[t] = s; __syncthreads();
  for (int off = 128; off; off >>= 1){
    if (t < off) sh[t] += sh[t + off];
    __syncthreads();
  }
  if (t == 0) bsum[blockIdx.x] = sh[0];
}

__global__ __launch_bounds__(256) void k_scansums(const int* __restrict__ bsum,
                                                  int* __restrict__ boff,
                                                  int* __restrict__ rowstart,
                                                  int NB, int N)
{
  __shared__ int sh[256];
  int t = threadIdx.x;
  int v = (t < NB) ? bsum[t] : 0;
  sh[t] = v; __syncthreads();
  for (int off = 1; off < 256; off <<= 1){
    int x = sh[t];
    int y = (t >= off) ? sh[t - off] : 0;
    __syncthreads();
    sh[t] = x + y;
    __syncthreads();
  }
  if (t < NB) boff[t] = sh[t] - v;
  if (t == NB - 1) rowstart[N] = sh[t];
}

__global__ __launch_bounds__(256) void k_scanfinal(const int* __restrict__ cnt,
                                                   const int* __restrict__ boff,
                                                   int* __restrict__ rowstart,
                                                   float* __restrict__ dinv, int N)
{
  __shared__ int sh[256];
  int t = threadIdx.x;
  int base = blockIdx.x * 1024 + t * 4;
  int c0 = 0, c1 = 0, c2 = 0, c3 = 0;
  if (base + 0 < N) c0 = cnt[base + 0];
  if (base + 1 < N) c1 = cnt[base + 1];
  if (base + 2 < N) c2 = cnt[base + 2];
  if (base + 3 < N) c3 = cnt[base + 3];
  int s = c0 + c1 + c2 + c3;
  sh[t] = s; __syncthreads();
  for (int off = 1; off < 256; off <<= 1){
    int x = sh[t];
    int y = (t >= off) ? sh[t - off] : 0;
    __syncthreads();
    sh[t] = x + y;
    __syncthreads();
  }
  int excl = sh[t] - s + boff[blockIdx.x];
  if (base + 0 < N){ rowstart[base+0] = excl;          dinv[base+0] = rsqrtf((float)c0 + 1.f); }
  if (base + 1 < N){ rowstart[base+1] = excl+c0;       dinv[base+1] = rsqrtf((float)c1 + 1.f); }
  if (base + 2 < N){ rowstart[base+2] = excl+c0+c1;    dinv[base+2] = rsqrtf((float)c2 + 1.f); }
  if (base + 3 < N){ rowstart[base+3] = excl+c0+c1+c2; dinv[base+3] = rsqrtf((float)c3 + 1.f); }
}

__global__ __launch_bounds__(256) void k_fill(const int* __restrict__ src,
                                              const int* __restrict__ dst,
                                              const int* __restrict__ pos,
                                              const int* __restrict__ rowstart,
                                              int* __restrict__ csr, int E)
{
  int g = blockIdx.x * 256 + threadIdx.x;
  int base = g * 4;
  if (base + 3 < E){
    int4 d = ((const int4*)dst)[g];
    int4 p = ((const int4*)pos)[g];
    int4 s = ((const int4*)src)[g];
    int r0 = rowstart[d.x], r1 = rowstart[d.y], r2 = rowstart[d.z], r3 = rowstart[d.w];
    csr[r0 + p.x] = s.x;
    csr[r1 + p.y] = s.y;
    csr[r2 + p.z] = s.z;
    csr[r3 + p.w] = s.w;
  } else {
    for (int j = 0; j < 4; j++){
      int e = base + j;
      if (e < E) csr[rowstart[dst[e]] + pos[e]] = src[e];
    }
  }
}

// ================= weight transpose: WT[n][k] bf16, row stride 136 =================
__global__ __launch_bounds__(256) void k_wt(const float* __restrict__ W1,
                                            const float* __restrict__ W2,
                                            const float* __restrict__ W3,
                                            unsigned short* __restrict__ WT1,
                                            unsigned short* __restrict__ WT2,
                                            unsigned short* __restrict__ WT3)
{
  const float* W; unsigned short* WT; int Cout, Cpad;
  if (blockIdx.x == 0){ W = W1; WT = WT1; Cout = 128; Cpad = 128; }
  else if (blockIdx.x == 1){ W = W2; WT = WT2; Cout = 128; Cpad = 128; }
  else { W = W3; WT = WT3; Cout = 40; Cpad = 48; }
  int tot = Cpad * 136;
  for (int i = threadIdx.x; i < tot; i += 256){
    int n = i / 136, k = i - n * 136;
    float v = (k < 128 && n < Cout) ? W[k * Cout + n] : 0.f;
    WT[i] = f2bfbits(v);
  }
}

// ================= MFMA GEMM, LDS-staged A =================
// MODE 0: A fp32 raw (layer 1). MODE 2: A bf16 + fused BN/ReLU/dropout.
template<int NT, int MODE>
__global__ __launch_bounds__(256) void k_gemm_mfma(const void* __restrict__ Ap,
                                                   const unsigned short* __restrict__ WT,
                                                   const float* __restrict__ dinv,
                                                   const float* __restrict__ sums,
                                                   const float* __restrict__ sumsq,
                                                   const float* __restrict__ g,
                                                   const float* __restrict__ be,
                                                   unsigned k0, unsigned k1, float invN,
                                                   unsigned short* __restrict__ outb,
                                                   int N, int Cout)
{
  __shared__ uint4 Wl4[NT * 16 * 17];          // NT*16 rows x 136 shorts
  __shared__ uint4 Al4[64 * 16];               // 64 rows x 16 chunks (swizzled)
  __shared__ float bnS[128], bnB[128];
  unsigned short* Wl = (unsigned short*)Wl4;
  const int t = threadIdx.x;
  const long rb0 = (long)blockIdx.x * 64;

  {
    const uint4* s4 = (const uint4*)WT;
    const int tot = NT * 16 * 17;
    for (int i = t; i < tot; i += 256) Wl4[i] = s4[i];
  }
  if (MODE == 2 && t < 128){
    float mean = sums[t] * invN;
    float var = fmaxf(sumsq[t] * invN - mean * mean, 0.f);
    float rstd = rsqrtf(var + 1e-5f);
    float sc = g[t] * rstd;
    bnS[t] = sc;
    bnB[t] = be[t] - mean * sc;
  }
  if (MODE == 2) __syncthreads();              // bnS/bnB ready for staging

  // ---- stage A: 1024 chunks, coalesced global reads, swizzled LDS writes ----
  #pragma unroll
  for (int i = 0; i < 4; i++){
    int idx = i * 256 + t;
    int r = idx >> 4, c = idx & 15;
    long grow = rb0 + r;
    uint4 chunk = make_uint4(0u, 0u, 0u, 0u);
    if (grow < N){
      if (MODE == 0){
        const float* ap = (const float*)Ap + grow * 128 + c * 8;
        float4 f0 = *(const float4*)ap;
        float4 f1 = *(const float4*)(ap + 4);
        chunk.x = (unsigned)f2bfbits(f0.x) | ((unsigned)f2bfbits(f0.y) << 16);
        chunk.y = (unsigned)f2bfbits(f0.z) | ((unsigned)f2bfbits(f0.w) << 16);
        chunk.z = (unsigned)f2bfbits(f1.x) | ((unsigned)f2bfbits(f1.y) << 16);
        chunk.w = (unsigned)f2bfbits(f1.z) | ((unsigned)f2bfbits(f1.w) << 16);
      } else {
        uint4 raw = *(const uint4*)((const unsigned short*)Ap + grow * 128 + c * 8);
        unsigned idxb = (unsigned)grow * 128u + (unsigned)(c * 8);
        const unsigned* rw = &raw.x;
        unsigned* cw = &chunk.x;
        #pragma unroll
        for (int h = 0; h < 4; h++){
          int ch = c * 8 + 2 * h;
          float f0 = bfbits2f((unsigned short)(rw[h] & 0xffffu));
          float f1 = bfbits2f((unsigned short)(rw[h] >> 16));
          f0 = fmaxf(fmaf(f0, bnS[ch],     bnB[ch]),     0.f);
          f1 = fmaxf(fmaf(f1, bnS[ch + 1], bnB[ch + 1]), 0.f);
          unsigned w0, w1;
          tf2x32(k0, k1, 0u, idxb + 2u * h,      w0, w1);
          f0 = ((w0 ^ w1) & 0x80000000u) ? 0.f : f0 * 2.f;
          tf2x32(k0, k1, 0u, idxb + 2u * h + 1u, w0, w1);
          f1 = ((w0 ^ w1) & 0x80000000u) ? 0.f : f1 * 2.f;
          cw[h] = (unsigned)f2bfbits(f0) | ((unsigned)f2bfbits(f1) << 16);
        }
      }
    }
    Al4[r * 16 + (c ^ (r & 15))] = chunk;
  }
  __syncthreads();

  const int w = t >> 6, l = t & 63;
  const int lm = l & 15, q = l >> 4;

  f32x4 acc[NT];
  #pragma unroll
  for (int nt = 0; nt < NT; nt++){
    acc[nt][0] = 0.f; acc[nt][1] = 0.f; acc[nt][2] = 0.f; acc[nt][3] = 0.f;
  }

  const int arow = w * 16 + lm;
  #pragma unroll
  for (int kt = 0; kt < 4; kt++){
    const int koff = kt * 32 + q * 8;
    bf16x8 a = *(const bf16x8*)&((const unsigned short*)Al4)[arow * 128 + (((kt * 4 + q) ^ lm) * 8)];
    #pragma unroll
    for (int nt = 0; nt < NT; nt++){
      bf16x8 b = *(const bf16x8*)(&Wl[(nt * 16 + lm) * 136 + koff]);
      acc[nt] = __builtin_amdgcn_mfma_f32_16x16x32_bf16(a, b, acc[nt], 0, 0, 0);
    }
  }

  #pragma unroll
  for (int r = 0; r < 4; r++){
    long row = rb0 + w * 16 + q * 4 + r;
    if (row < N){
      float dv = dinv[row];
      #pragma unroll
      for (int nt = 0; nt < NT; nt++){
        int col = nt * 16 + lm;
        if (col < Cout)
          outb[row * Cout + col] = f2bfbits(acc[nt][r] * dv);
      }
    }
  }
}

// ====== aggregation (128 ch) + fused BN-stat accumulation ======
// Block = 256 thr = 8 node-lanes (2 halves x 4 ty) x 32 sublanes; 64 nodes/block
// via 8 groups. Stats kept in registers across groups, reduced via LDS, then
// one global atomicAdd per channel per block (1563 blocks -> ~1.5k/address).
#define ACC4(U) do{ uint2 _u = (U); \
  a0 += bfbits2f((unsigned short)(_u.x & 0xffffu)); \
  a1 += bfbits2f((unsigned short)(_u.x >> 16)); \
  a2 += bfbits2f((unsigned short)(_u.y & 0xffffu)); \
  a3 += bfbits2f((unsigned short)(_u.y >> 16)); }while(0)

__global__ __launch_bounds__(256) void k_agg128s(const unsigned short* __restrict__ hw,
                                                 const int* __restrict__ rs,
                                                 const int* __restrict__ csr,
                                                 const float* __restrict__ dinv,
                                                 unsigned short* __restrict__ outb,
                                                 float* __restrict__ sums,
                                                 float* __restrict__ sumsq,
                                                 int N)
{
  const int half = (threadIdx.x >> 5) & 1;
  const int sl = threadIdx.x & 31;
  const int ty = threadIdx.y;
  const uint2* h4 = (const uint2*)hw;              // row = 32 uint2 (256 B)
  const int base = blockIdx.x * 64;

  float s0 = 0.f, s1 = 0.f, s2 = 0.f, s3 = 0.f;
  float q0 = 0.f, q1 = 0.f, q2 = 0.f, q3 = 0.f;

  #pragma unroll 1
  for (int it = 0; it < 8; it++){
    int v = base + it * 8 + ty * 2 + half;
    if (v < N){
      float a0 = 0.f, a1 = 0.f, a2 = 0.f, a3 = 0.f;
      ACC4(h4[(size_t)v * 32 + sl]);
      int e0 = rs[v], e1 = rs[v + 1];
      int i = e0;
      for (; i + 4 <= e1; i += 4){
        int sa = csr[i], sb = csr[i+1], sc = csr[i+2], sd = csr[i+3];
        uint2 m0 = h4[(size_t)sa * 32 + sl];
        uint2 m1 = h4[(size_t)sb * 32 + sl];
        uint2 m2 = h4[(size_t)sc * 32 + sl];
        uint2 m3 = h4[(size_t)sd * 32 + sl];
        ACC4(m0); ACC4(m1); ACC4(m2); ACC4(m3);
      }
      for (; i < e1; i++){
        ACC4(h4[(size_t)csr[i] * 32 + sl]);
      }
      float dv = dinv[v];
      a0 *= dv; a1 *= dv; a2 *= dv; a3 *= dv;
      uint2 o;
      o.x = (unsigned)f2bfbits(a0) | ((unsigned)f2bfbits(a1) << 16);
      o.y = (unsigned)f2bfbits(a2) | ((unsigned)f2bfbits(a3) << 16);
      ((uint2*)outb)[(size_t)v * 32 + sl] = o;
      s0 += a0; q0 = fmaf(a0, a0, q0);
      s1 += a1; q1 = fmaf(a1, a1, q1);
      s2 += a2; q2 = fmaf(a2, a2, q2);
      s3 += a3; q3 = fmaf(a3, a3, q3);
    }
  }

  // block reduction: 8 node-lane groups x 128 channels
  __shared__ float shS[8][132], shQ[8][132];
  int grp = ty * 2 + half;
  shS[grp][sl * 4 + 0] = s0; shQ[grp][sl * 4 + 0] = q0;
  shS[grp][sl * 4 + 1] = s1; shQ[grp][sl * 4 + 1] = q1;
  shS[grp][sl * 4 + 2] = s2; shQ[grp][sl * 4 + 2] = q2;
  shS[grp][sl * 4 + 3] = s3; shQ[grp][sl * 4 + 3] = q3;
  __syncthreads();
  int t = ty * 64 + threadIdx.x;
  if (t < 128){
    float ss = 0.f, qq = 0.f;
    #pragma unroll
    for (int g2 = 0; g2 < 8; g2++){ ss += shS[g2][t]; qq += shQ[g2][t]; }
    atomicAdd(&sums[t], ss);
    atomicAdd(&sumsq[t], qq);
  }
}

// ============ layer-3 agg (40 ch bf16 pre-scaled) + bias + log_softmax ============
#define ACC2(U) do{ unsigned _u = (U); \
  acx += bfbits2f((unsigned short)(_u & 0xffffu)); \
  acy += bfbits2f((unsigned short)(_u >> 16)); }while(0)

__global__ __launch_bounds__(256) void k_agg40lsm(const unsigned short* __restrict__ hw,
                                                  const int* __restrict__ rs,
                                                  const int* __restrict__ csr,
                                                  const float* __restrict__ dinv,
                                                  const float* __restrict__ b3,
                                                  float* __restrict__ out, int N)
{
  int half = (threadIdx.x >> 5) & 1;
  int sl = threadIdx.x & 31;
  int v = blockIdx.x * 8 + threadIdx.y * 2 + half;
  bool nact = (v < N);
  bool act = nact && (sl < 20);
  const unsigned* h2 = (const unsigned*)hw;        // row = 20 u32 (80 B)
  float acx = 0.f, acy = 0.f, dv = 1.f;
  if (act){
    dv = dinv[v];
    ACC2(h2[(size_t)v * 20 + sl]);
    int e0 = rs[v], e1 = rs[v + 1];
    int i = e0;
    for (; i + 4 <= e1; i += 4){
      int s0 = csr[i], s1 = csr[i+1], s2 = csr[i+2], s3 = csr[i+3];
      unsigned u0 = h2[(size_t)s0 * 20 + sl];
      unsigned u1 = h2[(size_t)s1 * 20 + sl];
      unsigned u2 = h2[(size_t)s2 * 20 + sl];
      unsigned u3 = h2[(size_t)s3 * 20 + sl];
      ACC2(u0); ACC2(u1); ACC2(u2); ACC2(u3);
    }
    for (; i < e1; i++){
      ACC2(h2[(size_t)csr[i] * 20 + sl]);
    }
  }
  float x0 = act ? fmaf(acx, dv, b3[2 * sl])     : -INFINITY;
  float x1 = act ? fmaf(acy, dv, b3[2 * sl + 1]) : -INFINITY;
  float m = fmaxf(x0, x1);
  #pragma unroll
  for (int off = 16; off; off >>= 1) m = fmaxf(m, __shfl_xor(m, off, 32));
  float e = act ? (expf(x0 - m) + expf(x1 - m)) : 0.f;
  #pragma unroll
  for (int off = 16; off; off >>= 1) e += __shfl_xor(e, off, 32);
  float lse = m + logf(e);
  if (act){
    float2 o; o.x = x0 - lse; o.y = x1 - lse;
    *reinterpret_cast<float2*>(out + (size_t)v * 40 + 2 * sl) = o;
  }
}

// ================= launch =================
extern "C" void kernel_launch(void* const* d_in, const int* in_sizes, int n_in,
                              void* d_out, int out_size, void* d_ws, size_t ws_size,
                              hipStream_t stream)
{
  const float* x  = (const float*)d_in[0];
  const int* ei   = (const int*)d_in[1];
  const float* W1 = (const float*)d_in[2];
  const float* g1 = (const float*)d_in[4];
  const float* be1= (const float*)d_in[5];
  const float* W2 = (const float*)d_in[6];
  const float* g2 = (const float*)d_in[8];
  const float* be2= (const float*)d_in[9];
  const float* W3 = (const float*)d_in[10];
  const float* b3 = (const float*)d_in[11];
  float* out = (float*)d_out;
  // b1, b2 unused: per-channel constants cancel exactly in training-mode BN.

  const int N = in_sizes[0] / 128;
  const int E = in_sizes[1] / 2;
  const int* srcv = ei;
  const int* dstv = ei + E;

  char* ws = (char*)d_ws;
  size_t off = 0;
  auto take = [&](size_t bytes) -> void* {
    void* p = ws + off;
    off = (off + bytes + 255) & ~(size_t)255;
    return p;
  };
  int*   cnt      = (int*)  take((size_t)N * 4);
  int*   pos      = (int*)  take((size_t)E * 4);
  int*   rowstart = (int*)  take((size_t)(N + 1) * 4);
  int*   csr      = (int*)  take((size_t)E * 4);
  float* dinv     = (float*)take((size_t)N * 4);
  int*   bsum     = (int*)  take(256 * 4);
  int*   boff     = (int*)  take(256 * 4);
  float* sums     = (float*)take(256 * 4);             // sums | sumsq, one memset
  float* sumsq    = sums + 128;
  unsigned short* WT1 = (unsigned short*)take(128 * 136 * 2);
  unsigned short* WT2 = (unsigned short*)take(128 * 136 * 2);
  unsigned short* WT3 = (unsigned short*)take(48 * 136 * 2);
  unsigned short* bufX = (unsigned short*)take((size_t)N * 128 * 2);
  unsigned short* bufY = (unsigned short*)take((size_t)N * 128 * 2);
  (void)ws_size; (void)n_in; (void)out_size;

  // dropout subkeys: jax.random.split(key(42), 2), partitionable fold
  unsigned l1k0, l1k1, l2k0, l2k1;
  tf2x32(0u, 42u, 0u, 0u, l1k0, l1k1);
  tf2x32(0u, 42u, 0u, 1u, l2k0, l2k1);

  const float invN = 1.0f / (float)N;
  const int NB = (N + 1023) / 1024;
  dim3 wgrid8((N + 7) / 8), wblk(64, 4);
  dim3 wgrid64((N + 63) / 64);
  const int ggrid = (N + 63) / 64;
  const int egrid = (E + 1023) / 1024;

  // ---- graph structure ----
  hipMemsetAsync(cnt, 0, (size_t)N * 4, stream);
  k_countpos<<<egrid, 256, 0, stream>>>(dstv, cnt, pos, E);
  k_blocksum<<<NB, 256, 0, stream>>>(cnt, bsum, N);
  k_scansums<<<1, 256, 0, stream>>>(bsum, boff, rowstart, NB, N);
  k_scanfinal<<<NB, 256, 0, stream>>>(cnt, boff, rowstart, dinv, N);
  k_fill<<<egrid, 256, 0, stream>>>(srcv, dstv, pos, rowstart, csr, E);
  k_wt<<<3, 256, 0, stream>>>(W1, W2, W3, WT1, WT2, WT3);

  // ---- layer 1 ----
  k_gemm_mfma<8, 0><<<ggrid, 256, 0, stream>>>(x, WT1, dinv,
      nullptr, nullptr, nullptr, nullptr, 0u, 0u, invN, bufX, N, 128);
  hipMemsetAsync(sums, 0, 256 * 4, stream);
  k_agg128s<<<wgrid64, wblk, 0, stream>>>(bufX, rowstart, csr, dinv, bufY, sums, sumsq, N);

  // ---- layer 2 (BN1+ReLU+dropout fused into A staging) ----
  k_gemm_mfma<8, 2><<<ggrid, 256, 0, stream>>>(bufY, WT2, dinv,
      sums, sumsq, g1, be1, l1k0, l1k1, invN, bufX, N, 128);
  hipMemsetAsync(sums, 0, 256 * 4, stream);
  k_agg128s<<<wgrid64, wblk, 0, stream>>>(bufX, rowstart, csr, dinv, bufY, sums, sumsq, N);

  // ---- layer 3 (BN2+ReLU+dropout fused) + log_softmax ----
  k_gemm_mfma<3, 2><<<ggrid, 256, 0, stream>>>(bufY, WT3, dinv,
      sums, sumsq, g2, be2, l2k0, l2k1, invN, bufX, N, 40);
  k_agg40lsm<<<wgrid8, wblk, 0, stream>>>(bufX, rowstart, csr, dinv, b3, out, N);
}

// Round 8
// 422.472 us; speedup vs baseline: 2.3449x; 1.1505x over previous
//
#include <hip/hip_runtime.h>
#include <math.h>

typedef __attribute__((ext_vector_type(8))) short bf16x8;
typedef __attribute__((ext_vector_type(4))) float f32x4;

__device__ __forceinline__ float bfbits2f(unsigned short b){
  return __uint_as_float(((unsigned)b) << 16);
}
__device__ __forceinline__ unsigned short f2bfbits(float f){
  unsigned u = __float_as_uint(f);
  unsigned r = u + 0x7fffu + ((u >> 16) & 1u);
  return (unsigned short)(r >> 16);
}

// ================= Threefry-2x32 (JAX partitionable) =================
__host__ __device__ __forceinline__ unsigned rotl32(unsigned v, int d){
  return (v << d) | (v >> (32 - d));
}
__host__ __device__ __forceinline__ void tf2x32(unsigned k0, unsigned k1,
                                                unsigned c0, unsigned c1,
                                                unsigned &o0, unsigned &o1)
{
  unsigned ks2 = k0 ^ k1 ^ 0x1BD11BDAu;
  unsigned x0 = c0 + k0, x1 = c1 + k1;
#define TFR(r) x0 += x1; x1 = rotl32(x1, r); x1 ^= x0;
  TFR(13) TFR(15) TFR(26) TFR(6)
  x0 += k1;  x1 += ks2 + 1u;
  TFR(17) TFR(29) TFR(16) TFR(24)
  x0 += ks2; x1 += k0 + 2u;
  TFR(13) TFR(15) TFR(26) TFR(6)
  x0 += k0;  x1 += k1 + 3u;
  TFR(17) TFR(29) TFR(16) TFR(24)
  x0 += k1;  x1 += ks2 + 4u;
  TFR(13) TFR(15) TFR(26) TFR(6)
  x0 += ks2; x1 += k0 + 5u;
#undef TFR
  o0 = x0; o1 = x1;
}

// ================= CSR build =================
__global__ __launch_bounds__(256) void k_countpos(const int* __restrict__ dst,
                                                  int* __restrict__ cnt,
                                                  int* __restrict__ pos, int E)
{
  int g = blockIdx.x * 256 + threadIdx.x;
  int base = g * 4;
  if (base + 3 < E){
    int4 d = ((const int4*)dst)[g];
    int4 p;
    p.x = atomicAdd(&cnt[d.x], 1);
    p.y = atomicAdd(&cnt[d.y], 1);
    p.z = atomicAdd(&cnt[d.z], 1);
    p.w = atomicAdd(&cnt[d.w], 1);
    ((int4*)pos)[g] = p;
  } else {
    for (int j = 0; j < 4; j++){
      int e = base + j;
      if (e < E) pos[e] = atomicAdd(&cnt[dst[e]], 1);
    }
  }
}

__global__ __launch_bounds__(256) void k_blocksum(const int* __restrict__ cnt,
                                                  int* __restrict__ bsum, int N)
{
  __shared__ int sh[256];
  int t = threadIdx.x;
  int base = blockIdx.x * 1024 + t * 4;
  int s = 0;
  #pragma unroll
  for (int j = 0; j < 4; j++){ int i = base + j; if (i < N) s += cnt[i]; }
  sh[t] = s; __syncthreads();
  for (int off = 128; off; off >>= 1){
    if (t < off) sh[t] += sh[t + off];
    __syncthreads();
  }
  if (t == 0) bsum[blockIdx.x] = sh[0];
}

__global__ __launch_bounds__(256) void k_scansums(const int* __restrict__ bsum,
                                                  int* __restrict__ boff,
                                                  int* __restrict__ rowstart,
                                                  int NB, int N)
{
  __shared__ int sh[256];
  int t = threadIdx.x;
  int v = (t < NB) ? bsum[t] : 0;
  sh[t] = v; __syncthreads();
  for (int off = 1; off < 256; off <<= 1){
    int x = sh[t];
    int y = (t >= off) ? sh[t - off] : 0;
    __syncthreads();
    sh[t] = x + y;
    __syncthreads();
  }
  if (t < NB) boff[t] = sh[t] - v;
  if (t == NB - 1) rowstart[N] = sh[t];
}

__global__ __launch_bounds__(256) void k_scanfinal(const int* __restrict__ cnt,
                                                   const int* __restrict__ boff,
                                                   int* __restrict__ rowstart,
                                                   float* __restrict__ dinv, int N)
{
  __shared__ int sh[256];
  int t = threadIdx.x;
  int base = blockIdx.x * 1024 + t * 4;
  int c0 = 0, c1 = 0, c2 = 0, c3 = 0;
  if (base + 0 < N) c0 = cnt[base + 0];
  if (base + 1 < N) c1 = cnt[base + 1];
  if (base + 2 < N) c2 = cnt[base + 2];
  if (base + 3 < N) c3 = cnt[base + 3];
  int s = c0 + c1 + c2 + c3;
  sh[t] = s; __syncthreads();
  for (int off = 1; off < 256; off <<= 1){
    int x = sh[t];
    int y = (t >= off) ? sh[t - off] : 0;
    __syncthreads();
    sh[t] = x + y;
    __syncthreads();
  }
  int excl = sh[t] - s + boff[blockIdx.x];
  if (base + 0 < N){ rowstart[base+0] = excl;          dinv[base+0] = rsqrtf((float)c0 + 1.f); }
  if (base + 1 < N){ rowstart[base+1] = excl+c0;       dinv[base+1] = rsqrtf((float)c1 + 1.f); }
  if (base + 2 < N){ rowstart[base+2] = excl+c0+c1;    dinv[base+2] = rsqrtf((float)c2 + 1.f); }
  if (base + 3 < N){ rowstart[base+3] = excl+c0+c1+c2; dinv[base+3] = rsqrtf((float)c3 + 1.f); }
}

__global__ __launch_bounds__(256) void k_fill(const int* __restrict__ src,
                                              const int* __restrict__ dst,
                                              const int* __restrict__ pos,
                                              const int* __restrict__ rowstart,
                                              int* __restrict__ csr, int E)
{
  int g = blockIdx.x * 256 + threadIdx.x;
  int base = g * 4;
  if (base + 3 < E){
    int4 d = ((const int4*)dst)[g];
    int4 p = ((const int4*)pos)[g];
    int4 s = ((const int4*)src)[g];
    int r0 = rowstart[d.x], r1 = rowstart[d.y], r2 = rowstart[d.z], r3 = rowstart[d.w];
    csr[r0 + p.x] = s.x;
    csr[r1 + p.y] = s.y;
    csr[r2 + p.z] = s.z;
    csr[r3 + p.w] = s.w;
  } else {
    for (int j = 0; j < 4; j++){
      int e = base + j;
      if (e < E) csr[rowstart[dst[e]] + pos[e]] = src[e];
    }
  }
}

// ================= weight transpose: WT[n][k] bf16, row stride 136 =================
__global__ __launch_bounds__(256) void k_wt(const float* __restrict__ W1,
                                            const float* __restrict__ W2,
                                            const float* __restrict__ W3,
                                            unsigned short* __restrict__ WT1,
                                            unsigned short* __restrict__ WT2,
                                            unsigned short* __restrict__ WT3)
{
  const float* W; unsigned short* WT; int Cout, Cpad;
  if (blockIdx.x == 0){ W = W1; WT = WT1; Cout = 128; Cpad = 128; }
  else if (blockIdx.x == 1){ W = W2; WT = WT2; Cout = 128; Cpad = 128; }
  else { W = W3; WT = WT3; Cout = 40; Cpad = 48; }
  int tot = Cpad * 136;
  for (int i = threadIdx.x; i < tot; i += 256){
    int n = i / 136, k = i - n * 136;
    float v = (k < 128 && n < Cout) ? W[k * Cout + n] : 0.f;
    WT[i] = f2bfbits(v);
  }
}

// ================= MFMA GEMM, LDS-staged A =================
// MODE 0: A fp32 raw (layer 1). MODE 2: A bf16 + fused BN/ReLU/dropout.
// stats = 16 banked copies of [sums(128) || sumsq(128)].
template<int NT, int MODE>
__global__ __launch_bounds__(256) void k_gemm_mfma(const void* __restrict__ Ap,
                                                   const unsigned short* __restrict__ WT,
                                                   const float* __restrict__ dinv,
                                                   const float* __restrict__ stats,
                                                   const float* __restrict__ g,
                                                   const float* __restrict__ be,
                                                   unsigned k0, unsigned k1, float invN,
                                                   unsigned short* __restrict__ outb,
                                                   int N, int Cout)
{
  __shared__ uint4 Wl4[NT * 16 * 17];          // NT*16 rows x 136 shorts
  __shared__ uint4 Al4[64 * 16];               // 64 rows x 16 chunks (swizzled)
  __shared__ float bnS[128], bnB[128];
  unsigned short* Wl = (unsigned short*)Wl4;
  const int t = threadIdx.x;
  const long rb0 = (long)blockIdx.x * 64;

  {
    const uint4* s4 = (const uint4*)WT;
    const int tot = NT * 16 * 17;
    for (int i = t; i < tot; i += 256) Wl4[i] = s4[i];
  }
  if (MODE == 2 && t < 128){
    float ss = 0.f, qq = 0.f;
    #pragma unroll
    for (int i = 0; i < 16; i++){
      ss += stats[i * 256 + t];
      qq += stats[i * 256 + 128 + t];
    }
    float mean = ss * invN;
    float var = fmaxf(qq * invN - mean * mean, 0.f);
    float rstd = rsqrtf(var + 1e-5f);
    float sc = g[t] * rstd;
    bnS[t] = sc;
    bnB[t] = be[t] - mean * sc;
  }
  if (MODE == 2) __syncthreads();              // bnS/bnB ready for staging

  // ---- stage A: 1024 chunks, coalesced global reads, swizzled LDS writes ----
  #pragma unroll
  for (int i = 0; i < 4; i++){
    int idx = i * 256 + t;
    int r = idx >> 4, c = idx & 15;
    long grow = rb0 + r;
    uint4 chunk = make_uint4(0u, 0u, 0u, 0u);
    if (grow < N){
      if (MODE == 0){
        const float* ap = (const float*)Ap + grow * 128 + c * 8;
        float4 f0 = *(const float4*)ap;
        float4 f1 = *(const float4*)(ap + 4);
        chunk.x = (unsigned)f2bfbits(f0.x) | ((unsigned)f2bfbits(f0.y) << 16);
        chunk.y = (unsigned)f2bfbits(f0.z) | ((unsigned)f2bfbits(f0.w) << 16);
        chunk.z = (unsigned)f2bfbits(f1.x) | ((unsigned)f2bfbits(f1.y) << 16);
        chunk.w = (unsigned)f2bfbits(f1.z) | ((unsigned)f2bfbits(f1.w) << 16);
      } else {
        uint4 raw = *(const uint4*)((const unsigned short*)Ap + grow * 128 + c * 8);
        unsigned idxb = (unsigned)grow * 128u + (unsigned)(c * 8);
        const unsigned* rw = &raw.x;
        unsigned* cw = &chunk.x;
        #pragma unroll
        for (int h = 0; h < 4; h++){
          int ch = c * 8 + 2 * h;
          float f0 = bfbits2f((unsigned short)(rw[h] & 0xffffu));
          float f1 = bfbits2f((unsigned short)(rw[h] >> 16));
          f0 = fmaxf(fmaf(f0, bnS[ch],     bnB[ch]),     0.f);
          f1 = fmaxf(fmaf(f1, bnS[ch + 1], bnB[ch + 1]), 0.f);
          unsigned w0, w1;
          tf2x32(k0, k1, 0u, idxb + 2u * h,      w0, w1);
          f0 = ((w0 ^ w1) & 0x80000000u) ? 0.f : f0 * 2.f;
          tf2x32(k0, k1, 0u, idxb + 2u * h + 1u, w0, w1);
          f1 = ((w0 ^ w1) & 0x80000000u) ? 0.f : f1 * 2.f;
          cw[h] = (unsigned)f2bfbits(f0) | ((unsigned)f2bfbits(f1) << 16);
        }
      }
    }
    Al4[r * 16 + (c ^ (r & 15))] = chunk;
  }
  __syncthreads();

  const int w = t >> 6, l = t & 63;
  const int lm = l & 15, q = l >> 4;

  f32x4 acc[NT];
  #pragma unroll
  for (int nt = 0; nt < NT; nt++){
    acc[nt][0] = 0.f; acc[nt][1] = 0.f; acc[nt][2] = 0.f; acc[nt][3] = 0.f;
  }

  const int arow = w * 16 + lm;
  #pragma unroll
  for (int kt = 0; kt < 4; kt++){
    const int koff = kt * 32 + q * 8;
    bf16x8 a = *(const bf16x8*)&((const unsigned short*)Al4)[arow * 128 + (((kt * 4 + q) ^ lm) * 8)];
    #pragma unroll
    for (int nt = 0; nt < NT; nt++){
      bf16x8 b = *(const bf16x8*)(&Wl[(nt * 16 + lm) * 136 + koff]);
      acc[nt] = __builtin_amdgcn_mfma_f32_16x16x32_bf16(a, b, acc[nt], 0, 0, 0);
    }
  }

  #pragma unroll
  for (int r = 0; r < 4; r++){
    long row = rb0 + w * 16 + q * 4 + r;
    if (row < N){
      float dv = dinv[row];
      #pragma unroll
      for (int nt = 0; nt < NT; nt++){
        int col = nt * 16 + lm;
        if (col < Cout)
          outb[row * Cout + col] = f2bfbits(acc[nt][r] * dv);
      }
    }
  }
}

// ====== aggregation (128 ch) + fused BN-stat accumulation, v2 ======
// Wave = 4 nodes x 16 sublanes; sublane owns 8 channels (uint4, 16 B).
// Block = (64,4) = 16 chains; 2 groups -> 32 nodes/block; grid=(N+31)/32.
// Stats: LDS-reduce 16 chains -> atomicAdd into banked stats[blockIdx&15].
#define ACC8(U) do{ uint4 _u = (U); \
  a0 += bfbits2f((unsigned short)(_u.x & 0xffffu)); \
  a1 += bfbits2f((unsigned short)(_u.x >> 16)); \
  a2 += bfbits2f((unsigned short)(_u.y & 0xffffu)); \
  a3 += bfbits2f((unsigned short)(_u.y >> 16)); \
  a4 += bfbits2f((unsigned short)(_u.z & 0xffffu)); \
  a5 += bfbits2f((unsigned short)(_u.z >> 16)); \
  a6 += bfbits2f((unsigned short)(_u.w & 0xffffu)); \
  a7 += bfbits2f((unsigned short)(_u.w >> 16)); }while(0)

__global__ __launch_bounds__(256) void k_agg128s(const unsigned short* __restrict__ hw,
                                                 const int* __restrict__ rs,
                                                 const int* __restrict__ csr,
                                                 const float* __restrict__ dinv,
                                                 unsigned short* __restrict__ outb,
                                                 float* __restrict__ stats,
                                                 int N)
{
  const int l = threadIdx.x;
  const int ns = l >> 4;                 // node-sub 0..3
  const int sl = l & 15;                 // sublane 0..15
  const int ty = threadIdx.y;
  const int grp = ty * 4 + ns;           // 0..15 chain id
  const uint4* h16 = (const uint4*)hw;   // row = 16 uint4 (256 B)
  const int base = blockIdx.x * 32;

  float s0=0.f,s1=0.f,s2=0.f,s3=0.f,s4=0.f,s5=0.f,s6=0.f,s7=0.f;
  float q0=0.f,q1=0.f,q2=0.f,q3=0.f,q4=0.f,q5=0.f,q6=0.f,q7=0.f;

  #pragma unroll 1
  for (int it = 0; it < 2; it++){
    int v = base + it * 16 + grp;
    if (v < N){
      float a0=0.f,a1=0.f,a2=0.f,a3=0.f,a4=0.f,a5=0.f,a6=0.f,a7=0.f;
      ACC8(h16[(size_t)v * 16 + sl]);
      int e0 = rs[v], e1 = rs[v + 1];
      int i = e0;
      for (; i + 4 <= e1; i += 4){
        int sa = csr[i], sb = csr[i+1], sc = csr[i+2], sd = csr[i+3];
        uint4 m0 = h16[(size_t)sa * 16 + sl];
        uint4 m1 = h16[(size_t)sb * 16 + sl];
        uint4 m2 = h16[(size_t)sc * 16 + sl];
        uint4 m3 = h16[(size_t)sd * 16 + sl];
        ACC8(m0); ACC8(m1); ACC8(m2); ACC8(m3);
      }
      for (; i < e1; i++){
        ACC8(h16[(size_t)csr[i] * 16 + sl]);
      }
      float dv = dinv[v];
      a0*=dv; a1*=dv; a2*=dv; a3*=dv; a4*=dv; a5*=dv; a6*=dv; a7*=dv;
      uint4 o;
      o.x = (unsigned)f2bfbits(a0) | ((unsigned)f2bfbits(a1) << 16);
      o.y = (unsigned)f2bfbits(a2) | ((unsigned)f2bfbits(a3) << 16);
      o.z = (unsigned)f2bfbits(a4) | ((unsigned)f2bfbits(a5) << 16);
      o.w = (unsigned)f2bfbits(a6) | ((unsigned)f2bfbits(a7) << 16);
      ((uint4*)outb)[(size_t)v * 16 + sl] = o;
      s0+=a0; q0=fmaf(a0,a0,q0);  s1+=a1; q1=fmaf(a1,a1,q1);
      s2+=a2; q2=fmaf(a2,a2,q2);  s3+=a3; q3=fmaf(a3,a3,q3);
      s4+=a4; q4=fmaf(a4,a4,q4);  s5+=a5; q5=fmaf(a5,a5,q5);
      s6+=a6; q6=fmaf(a6,a6,q6);  s7+=a7; q7=fmaf(a7,a7,q7);
    }
  }

  // block reduction: 16 chains x 128 channels (channel = sl*8 + j)
  __shared__ float shS[16][128], shQ[16][128];
  *(float4*)&shS[grp][sl * 8]     = make_float4(s0, s1, s2, s3);
  *(float4*)&shS[grp][sl * 8 + 4] = make_float4(s4, s5, s6, s7);
  *(float4*)&shQ[grp][sl * 8]     = make_float4(q0, q1, q2, q3);
  *(float4*)&shQ[grp][sl * 8 + 4] = make_float4(q4, q5, q6, q7);
  __syncthreads();
  int t = ty * 64 + threadIdx.x;
  if (t < 128){
    float ss = 0.f, qq = 0.f;
    #pragma unroll
    for (int g2 = 0; g2 < 16; g2++){ ss += shS[g2][t]; qq += shQ[g2][t]; }
    float* dstat = stats + (blockIdx.x & 15) * 256;
    atomicAdd(&dstat[t], ss);
    atomicAdd(&dstat[128 + t], qq);
  }
}

// ============ layer-3 agg (40 ch bf16 pre-scaled) + bias + log_softmax ============
#define ACC2(U) do{ unsigned _u = (U); \
  acx += bfbits2f((unsigned short)(_u & 0xffffu)); \
  acy += bfbits2f((unsigned short)(_u >> 16)); }while(0)

__global__ __launch_bounds__(256) void k_agg40lsm(const unsigned short* __restrict__ hw,
                                                  const int* __restrict__ rs,
                                                  const int* __restrict__ csr,
                                                  const float* __restrict__ dinv,
                                                  const float* __restrict__ b3,
                                                  float* __restrict__ out, int N)
{
  int half = (threadIdx.x >> 5) & 1;
  int sl = threadIdx.x & 31;
  int v = blockIdx.x * 8 + threadIdx.y * 2 + half;
  bool nact = (v < N);
  bool act = nact && (sl < 20);
  const unsigned* h2 = (const unsigned*)hw;        // row = 20 u32 (80 B)
  float acx = 0.f, acy = 0.f, dv = 1.f;
  if (act){
    dv = dinv[v];
    ACC2(h2[(size_t)v * 20 + sl]);
    int e0 = rs[v], e1 = rs[v + 1];
    int i = e0;
    for (; i + 4 <= e1; i += 4){
      int s0 = csr[i], s1 = csr[i+1], s2 = csr[i+2], s3 = csr[i+3];
      unsigned u0 = h2[(size_t)s0 * 20 + sl];
      unsigned u1 = h2[(size_t)s1 * 20 + sl];
      unsigned u2 = h2[(size_t)s2 * 20 + sl];
      unsigned u3 = h2[(size_t)s3 * 20 + sl];
      ACC2(u0); ACC2(u1); ACC2(u2); ACC2(u3);
    }
    for (; i < e1; i++){
      ACC2(h2[(size_t)csr[i] * 20 + sl]);
    }
  }
  float x0 = act ? fmaf(acx, dv, b3[2 * sl])     : -INFINITY;
  float x1 = act ? fmaf(acy, dv, b3[2 * sl + 1]) : -INFINITY;
  float m = fmaxf(x0, x1);
  #pragma unroll
  for (int off = 16; off; off >>= 1) m = fmaxf(m, __shfl_xor(m, off, 32));
  float e = act ? (expf(x0 - m) + expf(x1 - m)) : 0.f;
  #pragma unroll
  for (int off = 16; off; off >>= 1) e += __shfl_xor(e, off, 32);
  float lse = m + logf(e);
  if (act){
    float2 o; o.x = x0 - lse; o.y = x1 - lse;
    *reinterpret_cast<float2*>(out + (size_t)v * 40 + 2 * sl) = o;
  }
}

// ================= launch =================
extern "C" void kernel_launch(void* const* d_in, const int* in_sizes, int n_in,
                              void* d_out, int out_size, void* d_ws, size_t ws_size,
                              hipStream_t stream)
{
  const float* x  = (const float*)d_in[0];
  const int* ei   = (const int*)d_in[1];
  const float* W1 = (const float*)d_in[2];
  const float* g1 = (const float*)d_in[4];
  const float* be1= (const float*)d_in[5];
  const float* W2 = (const float*)d_in[6];
  const float* g2 = (const float*)d_in[8];
  const float* be2= (const float*)d_in[9];
  const float* W3 = (const float*)d_in[10];
  const float* b3 = (const float*)d_in[11];
  float* out = (float*)d_out;
  // b1, b2 unused: per-channel constants cancel exactly in training-mode BN.

  const int N = in_sizes[0] / 128;
  const int E = in_sizes[1] / 2;
  const int* srcv = ei;
  const int* dstv = ei + E;

  char* ws = (char*)d_ws;
  size_t off = 0;
  auto take = [&](size_t bytes) -> void* {
    void* p = ws + off;
    off = (off + bytes + 255) & ~(size_t)255;
    return p;
  };
  int*   cnt      = (int*)  take((size_t)N * 4);
  int*   pos      = (int*)  take((size_t)E * 4);
  int*   rowstart = (int*)  take((size_t)(N + 1) * 4);
  int*   csr      = (int*)  take((size_t)E * 4);
  float* dinv     = (float*)take((size_t)N * 4);
  int*   bsum     = (int*)  take(256 * 4);
  int*   boff     = (int*)  take(256 * 4);
  float* stats    = (float*)take(16 * 256 * 4);        // 16 banked copies
  unsigned short* WT1 = (unsigned short*)take(128 * 136 * 2);
  unsigned short* WT2 = (unsigned short*)take(128 * 136 * 2);
  unsigned short* WT3 = (unsigned short*)take(48 * 136 * 2);
  unsigned short* bufX = (unsigned short*)take((size_t)N * 128 * 2);
  unsigned short* bufY = (unsigned short*)take((size_t)N * 128 * 2);
  (void)ws_size; (void)n_in; (void)out_size;

  // dropout subkeys: jax.random.split(key(42), 2), partitionable fold
  unsigned l1k0, l1k1, l2k0, l2k1;
  tf2x32(0u, 42u, 0u, 0u, l1k0, l1k1);
  tf2x32(0u, 42u, 0u, 1u, l2k0, l2k1);

  const float invN = 1.0f / (float)N;
  const int NB = (N + 1023) / 1024;
  dim3 wgrid8((N + 7) / 8), wblk(64, 4);
  dim3 wgrid32((N + 31) / 32);
  const int ggrid = (N + 63) / 64;
  const int egrid = (E + 1023) / 1024;

  // ---- graph structure ----
  hipMemsetAsync(cnt, 0, (size_t)N * 4, stream);
  k_countpos<<<egrid, 256, 0, stream>>>(dstv, cnt, pos, E);
  k_blocksum<<<NB, 256, 0, stream>>>(cnt, bsum, N);
  k_scansums<<<1, 256, 0, stream>>>(bsum, boff, rowstart, NB, N);
  k_scanfinal<<<NB, 256, 0, stream>>>(cnt, boff, rowstart, dinv, N);
  k_fill<<<egrid, 256, 0, stream>>>(srcv, dstv, pos, rowstart, csr, E);
  k_wt<<<3, 256, 0, stream>>>(W1, W2, W3, WT1, WT2, WT3);

  // ---- layer 1 ----
  k_gemm_mfma<8, 0><<<ggrid, 256, 0, stream>>>(x, WT1, dinv,
      nullptr, nullptr, nullptr, 0u, 0u, invN, bufX, N, 128);
  hipMemsetAsync(stats, 0, 16 * 256 * 4, stream);
  k_agg128s<<<wgrid32, wblk, 0, stream>>>(bufX, rowstart, csr, dinv, bufY, stats, N);

  // ---- layer 2 (BN1+ReLU+dropout fused into A staging) ----
  k_gemm_mfma<8, 2><<<ggrid, 256, 0, stream>>>(bufY, WT2, dinv,
      stats, g1, be1, l1k0, l1k1, invN, bufX, N, 128);
  hipMemsetAsync(stats, 0, 16 * 256 * 4, stream);
  k_agg128s<<<wgrid32, wblk, 0, stream>>>(bufX, rowstart, csr, dinv, bufY, stats, N);

  // ---- layer 3 (BN2+ReLU+dropout fused) + log_softmax ----
  k_gemm_mfma<3, 2><<<ggrid, 256, 0, stream>>>(bufY, WT3, dinv,
      stats, g2, be2, l2k0, l2k1, invN, bufX, N, 40);
  k_agg40lsm<<<wgrid8, wblk, 0, stream>>>(bufX, rowstart, csr, dinv, b3, out, N);
}

// Round 9
// 418.947 us; speedup vs baseline: 2.3646x; 1.0084x over previous
//
#include <hip/hip_runtime.h>
#include <math.h>

typedef __attribute__((ext_vector_type(8))) short bf16x8;
typedef __attribute__((ext_vector_type(4))) float f32x4;

__device__ __forceinline__ float bfbits2f(unsigned short b){
  return __uint_as_float(((unsigned)b) << 16);
}
__device__ __forceinline__ unsigned short f2bfbits(float f){
  unsigned u = __float_as_uint(f);
  unsigned r = u + 0x7fffu + ((u >> 16) & 1u);
  return (unsigned short)(r >> 16);
}

// ================= Threefry-2x32 (JAX partitionable) =================
__host__ __device__ __forceinline__ unsigned rotl32(unsigned v, int d){
  return (v << d) | (v >> (32 - d));
}
__host__ __device__ __forceinline__ void tf2x32(unsigned k0, unsigned k1,
                                                unsigned c0, unsigned c1,
                                                unsigned &o0, unsigned &o1)
{
  unsigned ks2 = k0 ^ k1 ^ 0x1BD11BDAu;
  unsigned x0 = c0 + k0, x1 = c1 + k1;
#define TFR(r) x0 += x1; x1 = rotl32(x1, r); x1 ^= x0;
  TFR(13) TFR(15) TFR(26) TFR(6)
  x0 += k1;  x1 += ks2 + 1u;
  TFR(17) TFR(29) TFR(16) TFR(24)
  x0 += ks2; x1 += k0 + 2u;
  TFR(13) TFR(15) TFR(26) TFR(6)
  x0 += k0;  x1 += k1 + 3u;
  TFR(17) TFR(29) TFR(16) TFR(24)
  x0 += k1;  x1 += ks2 + 4u;
  TFR(13) TFR(15) TFR(26) TFR(6)
  x0 += ks2; x1 += k0 + 5u;
#undef TFR
  o0 = x0; o1 = x1;
}

// ================= CSR build =================
__global__ __launch_bounds__(256) void k_countpos(const int* __restrict__ dst,
                                                  int* __restrict__ cnt,
                                                  int* __restrict__ pos, int E)
{
  int g = blockIdx.x * 256 + threadIdx.x;
  int base = g * 4;
  if (base + 3 < E){
    int4 d = ((const int4*)dst)[g];
    int4 p;
    p.x = atomicAdd(&cnt[d.x], 1);
    p.y = atomicAdd(&cnt[d.y], 1);
    p.z = atomicAdd(&cnt[d.z], 1);
    p.w = atomicAdd(&cnt[d.w], 1);
    ((int4*)pos)[g] = p;
  } else {
    for (int j = 0; j < 4; j++){
      int e = base + j;
      if (e < E) pos[e] = atomicAdd(&cnt[dst[e]], 1);
    }
  }
}

__global__ __launch_bounds__(256) void k_blocksum(const int* __restrict__ cnt,
                                                  int* __restrict__ bsum, int N)
{
  __shared__ int sh[256];
  int t = threadIdx.x;
  int base = blockIdx.x * 1024 + t * 4;
  int s = 0;
  #pragma unroll
  for (int j = 0; j < 4; j++){ int i = base + j; if (i < N) s += cnt[i]; }
  sh[t] = s; __syncthreads();
  for (int off = 128; off; off >>= 1){
    if (t < off) sh[t] += sh[t + off];
    __syncthreads();
  }
  if (t == 0) bsum[blockIdx.x] = sh[0];
}

__global__ __launch_bounds__(256) void k_scansums(const int* __restrict__ bsum,
                                                  int* __restrict__ boff,
                                                  int* __restrict__ rowstart,
                                                  int NB, int N)
{
  __shared__ int sh[256];
  int t = threadIdx.x;
  int v = (t < NB) ? bsum[t] : 0;
  sh[t] = v; __syncthreads();
  for (int off = 1; off < 256; off <<= 1){
    int x = sh[t];
    int y = (t >= off) ? sh[t - off] : 0;
    __syncthreads();
    sh[t] = x + y;
    __syncthreads();
  }
  if (t < NB) boff[t] = sh[t] - v;
  if (t == NB - 1) rowstart[N] = sh[t];
}

__global__ __launch_bounds__(256) void k_scanfinal(const int* __restrict__ cnt,
                                                   const int* __restrict__ boff,
                                                   int* __restrict__ rowstart,
                                                   float* __restrict__ dinv, int N)
{
  __shared__ int sh[256];
  int t = threadIdx.x;
  int base = blockIdx.x * 1024 + t * 4;
  int c0 = 0, c1 = 0, c2 = 0, c3 = 0;
  if (base + 0 < N) c0 = cnt[base + 0];
  if (base + 1 < N) c1 = cnt[base + 1];
  if (base + 2 < N) c2 = cnt[base + 2];
  if (base + 3 < N) c3 = cnt[base + 3];
  int s = c0 + c1 + c2 + c3;
  sh[t] = s; __syncthreads();
  for (int off = 1; off < 256; off <<= 1){
    int x = sh[t];
    int y = (t >= off) ? sh[t - off] : 0;
    __syncthreads();
    sh[t] = x + y;
    __syncthreads();
  }
  int excl = sh[t] - s + boff[blockIdx.x];
  if (base + 0 < N){ rowstart[base+0] = excl;          dinv[base+0] = rsqrtf((float)c0 + 1.f); }
  if (base + 1 < N){ rowstart[base+1] = excl+c0;       dinv[base+1] = rsqrtf((float)c1 + 1.f); }
  if (base + 2 < N){ rowstart[base+2] = excl+c0+c1;    dinv[base+2] = rsqrtf((float)c2 + 1.f); }
  if (base + 3 < N){ rowstart[base+3] = excl+c0+c1+c2; dinv[base+3] = rsqrtf((float)c3 + 1.f); }
}

__global__ __launch_bounds__(256) void k_fill(const int* __restrict__ src,
                                              const int* __restrict__ dst,
                                              const int* __restrict__ pos,
                                              const int* __restrict__ rowstart,
                                              int* __restrict__ csr, int E)
{
  int g = blockIdx.x * 256 + threadIdx.x;
  int base = g * 4;
  if (base + 3 < E){
    int4 d = ((const int4*)dst)[g];
    int4 p = ((const int4*)pos)[g];
    int4 s = ((const int4*)src)[g];
    int r0 = rowstart[d.x], r1 = rowstart[d.y], r2 = rowstart[d.z], r3 = rowstart[d.w];
    csr[r0 + p.x] = s.x;
    csr[r1 + p.y] = s.y;
    csr[r2 + p.z] = s.z;
    csr[r3 + p.w] = s.w;
  } else {
    for (int j = 0; j < 4; j++){
      int e = base + j;
      if (e < E) csr[rowstart[dst[e]] + pos[e]] = src[e];
    }
  }
}

// ====== weight transpose: WT[n][k] bf16, row stride 128 (unpadded) ======
__global__ __launch_bounds__(256) void k_wt(const float* __restrict__ W1,
                                            const float* __restrict__ W2,
                                            const float* __restrict__ W3,
                                            unsigned short* __restrict__ WT1,
                                            unsigned short* __restrict__ WT2,
                                            unsigned short* __restrict__ WT3)
{
  const float* W; unsigned short* WT; int Cout, Cpad;
  if (blockIdx.x == 0){ W = W1; WT = WT1; Cout = 128; Cpad = 128; }
  else if (blockIdx.x == 1){ W = W2; WT = WT2; Cout = 128; Cpad = 128; }
  else { W = W3; WT = WT3; Cout = 40; Cpad = 48; }
  int tot = Cpad * 128;
  for (int i = threadIdx.x; i < tot; i += 256){
    int n = i >> 7, k = i & 127;
    float v = (n < Cout) ? W[k * Cout + n] : 0.f;
    WT[i] = f2bfbits(v);
  }
}

// ================= MFMA GEMM v3: wave-private A staging, no stage->MFMA barrier ====
// MODE 0: A fp32 raw (layer 1). MODE 2: A bf16 + fused BN/ReLU/dropout.
// 256 thr = 4 waves x 16 rows = 64 rows/block. Wave w stages ONLY its own 16
// LDS rows, so the only __syncthreads is after the shared W/bn stage; the
// stage->MFMA dependency is intra-wave (compiler lgkmcnt). XOR chunk swizzle
// (c^r) on both tiles -> 2-way bank aliasing (free, m136).
template<int NT, int MODE>
__global__ __launch_bounds__(256) void k_gemm_mfma(const void* __restrict__ Ap,
                                                   const unsigned short* __restrict__ WT,
                                                   const float* __restrict__ dinv,
                                                   const float* __restrict__ stats,
                                                   const float* __restrict__ g,
                                                   const float* __restrict__ be,
                                                   unsigned k0, unsigned k1, float invN,
                                                   unsigned short* __restrict__ outb,
                                                   int N, int Cout)
{
  __shared__ uint4 Wl4[NT * 16 * 16];          // NT*16 rows x 16 chunks, swizzled
  __shared__ uint4 Al4[64 * 16];               // 64 rows x 16 chunks, swizzled
  __shared__ float bnS[128], bnB[128];
  const int t = threadIdx.x;
  const int w = t >> 6, l = t & 63;
  const long rb0 = (long)blockIdx.x * 64;
  const int wrow0 = w * 16;

  // ---- issue raw A loads first (latency hidden behind W/bn stage) ----
  uint4 rawU[4];
  float4 rawF[4][2];
  int rr[4], cc[4];
  bool inr[4];
  #pragma unroll
  for (int i = 0; i < 4; i++){
    int idx = i * 64 + l;
    int r = idx >> 4, c = idx & 15;
    long grow = rb0 + wrow0 + r;
    rr[i] = r; cc[i] = c; inr[i] = (grow < N);
    if (inr[i]){
      if (MODE == 0){
        const float* ap = (const float*)Ap + grow * 128 + c * 8;
        rawF[i][0] = *(const float4*)ap;
        rawF[i][1] = *(const float4*)(ap + 4);
      } else {
        rawU[i] = *(const uint4*)((const unsigned short*)Ap + grow * 128 + c * 8);
      }
    }
  }

  // ---- shared W stage (+ BN prep), single block barrier ----
  {
    const uint4* s4 = (const uint4*)WT;
    const int tot = NT * 16 * 16;
    for (int i = t; i < tot; i += 256){
      int n = i >> 4, c = i & 15;
      Wl4[n * 16 + (c ^ (n & 15))] = s4[i];
    }
  }
  if (MODE == 2 && t < 128){
    float ss = 0.f, qq = 0.f;
    #pragma unroll
    for (int i = 0; i < 16; i++){
      ss += stats[i * 256 + t];
      qq += stats[i * 256 + 128 + t];
    }
    float mean = ss * invN;
    float var = fmaxf(qq * invN - mean * mean, 0.f);
    float rstd = rsqrtf(var + 1e-5f);
    float sc = g[t] * rstd;
    bnS[t] = sc;
    bnB[t] = be[t] - mean * sc;
  }
  __syncthreads();

  // ---- transform + wave-private LDS write (no block barrier needed) ----
  #pragma unroll
  for (int i = 0; i < 4; i++){
    uint4 chunk = make_uint4(0u, 0u, 0u, 0u);
    if (inr[i]){
      if (MODE == 0){
        chunk.x = (unsigned)f2bfbits(rawF[i][0].x) | ((unsigned)f2bfbits(rawF[i][0].y) << 16);
        chunk.y = (unsigned)f2bfbits(rawF[i][0].z) | ((unsigned)f2bfbits(rawF[i][0].w) << 16);
        chunk.z = (unsigned)f2bfbits(rawF[i][1].x) | ((unsigned)f2bfbits(rawF[i][1].y) << 16);
        chunk.w = (unsigned)f2bfbits(rawF[i][1].z) | ((unsigned)f2bfbits(rawF[i][1].w) << 16);
      } else {
        long grow = rb0 + wrow0 + rr[i];
        unsigned idxb = (unsigned)grow * 128u + (unsigned)(cc[i] * 8);
        const unsigned* rw = &rawU[i].x;
        unsigned* cw = &chunk.x;
        #pragma unroll
        for (int h = 0; h < 4; h++){
          int ch = cc[i] * 8 + 2 * h;
          float f0 = bfbits2f((unsigned short)(rw[h] & 0xffffu));
          float f1 = bfbits2f((unsigned short)(rw[h] >> 16));
          f0 = fmaxf(fmaf(f0, bnS[ch],     bnB[ch]),     0.f);
          f1 = fmaxf(fmaf(f1, bnS[ch + 1], bnB[ch + 1]), 0.f);
          unsigned w0, w1;
          tf2x32(k0, k1, 0u, idxb + 2u * h,      w0, w1);
          f0 = ((w0 ^ w1) & 0x80000000u) ? 0.f : f0 * 2.f;
          tf2x32(k0, k1, 0u, idxb + 2u * h + 1u, w0, w1);
          f1 = ((w0 ^ w1) & 0x80000000u) ? 0.f : f1 * 2.f;
          cw[h] = (unsigned)f2bfbits(f0) | ((unsigned)f2bfbits(f1) << 16);
        }
      }
    }
    Al4[(wrow0 + rr[i]) * 16 + (cc[i] ^ rr[i])] = chunk;
  }

  const int lm = l & 15, q = l >> 4;

  f32x4 acc[NT];
  #pragma unroll
  for (int nt = 0; nt < NT; nt++){
    acc[nt][0] = 0.f; acc[nt][1] = 0.f; acc[nt][2] = 0.f; acc[nt][3] = 0.f;
  }

  #pragma unroll
  for (int kt = 0; kt < 4; kt++){
    const int x = kt * 4 + q;
    bf16x8 a = *(const bf16x8*)&Al4[(wrow0 + lm) * 16 + (x ^ lm)];
    #pragma unroll
    for (int nt = 0; nt < NT; nt++){
      int brow = nt * 16 + lm;
      bf16x8 b = *(const bf16x8*)&Wl4[brow * 16 + (x ^ (brow & 15))];
      acc[nt] = __builtin_amdgcn_mfma_f32_16x16x32_bf16(a, b, acc[nt], 0, 0, 0);
    }
  }

  #pragma unroll
  for (int r = 0; r < 4; r++){
    long row = rb0 + wrow0 + q * 4 + r;
    if (row < N){
      float dv = dinv[row];
      #pragma unroll
      for (int nt = 0; nt < NT; nt++){
        int col = nt * 16 + lm;
        if (col < Cout)
          outb[row * Cout + col] = f2bfbits(acc[nt][r] * dv);
      }
    }
  }
}

// ====== aggregation (128 ch) + fused BN-stat accumulation ======
#define ACC8(U) do{ uint4 _u = (U); \
  a0 += bfbits2f((unsigned short)(_u.x & 0xffffu)); \
  a1 += bfbits2f((unsigned short)(_u.x >> 16)); \
  a2 += bfbits2f((unsigned short)(_u.y & 0xffffu)); \
  a3 += bfbits2f((unsigned short)(_u.y >> 16)); \
  a4 += bfbits2f((unsigned short)(_u.z & 0xffffu)); \
  a5 += bfbits2f((unsigned short)(_u.z >> 16)); \
  a6 += bfbits2f((unsigned short)(_u.w & 0xffffu)); \
  a7 += bfbits2f((unsigned short)(_u.w >> 16)); }while(0)

__global__ __launch_bounds__(256) void k_agg128s(const unsigned short* __restrict__ hw,
                                                 const int* __restrict__ rs,
                                                 const int* __restrict__ csr,
                                                 const float* __restrict__ dinv,
                                                 unsigned short* __restrict__ outb,
                                                 float* __restrict__ stats,
                                                 int N)
{
  const int l = threadIdx.x;
  const int ns = l >> 4;                 // node-sub 0..3
  const int sl = l & 15;                 // sublane 0..15
  const int ty = threadIdx.y;
  const int grp = ty * 4 + ns;           // 0..15 chain id
  const uint4* h16 = (const uint4*)hw;   // row = 16 uint4 (256 B)
  const int base = blockIdx.x * 32;

  float s0=0.f,s1=0.f,s2=0.f,s3=0.f,s4=0.f,s5=0.f,s6=0.f,s7=0.f;
  float q0=0.f,q1=0.f,q2=0.f,q3=0.f,q4=0.f,q5=0.f,q6=0.f,q7=0.f;

  #pragma unroll 1
  for (int it = 0; it < 2; it++){
    int v = base + it * 16 + grp;
    if (v < N){
      float a0=0.f,a1=0.f,a2=0.f,a3=0.f,a4=0.f,a5=0.f,a6=0.f,a7=0.f;
      ACC8(h16[(size_t)v * 16 + sl]);
      int e0 = rs[v], e1 = rs[v + 1];
      int i = e0;
      for (; i + 4 <= e1; i += 4){
        int sa = csr[i], sb = csr[i+1], sc = csr[i+2], sd = csr[i+3];
        uint4 m0 = h16[(size_t)sa * 16 + sl];
        uint4 m1 = h16[(size_t)sb * 16 + sl];
        uint4 m2 = h16[(size_t)sc * 16 + sl];
        uint4 m3 = h16[(size_t)sd * 16 + sl];
        ACC8(m0); ACC8(m1); ACC8(m2); ACC8(m3);
      }
      for (; i < e1; i++){
        ACC8(h16[(size_t)csr[i] * 16 + sl]);
      }
      float dv = dinv[v];
      a0*=dv; a1*=dv; a2*=dv; a3*=dv; a4*=dv; a5*=dv; a6*=dv; a7*=dv;
      uint4 o;
      o.x = (unsigned)f2bfbits(a0) | ((unsigned)f2bfbits(a1) << 16);
      o.y = (unsigned)f2bfbits(a2) | ((unsigned)f2bfbits(a3) << 16);
      o.z = (unsigned)f2bfbits(a4) | ((unsigned)f2bfbits(a5) << 16);
      o.w = (unsigned)f2bfbits(a6) | ((unsigned)f2bfbits(a7) << 16);
      ((uint4*)outb)[(size_t)v * 16 + sl] = o;
      s0+=a0; q0=fmaf(a0,a0,q0);  s1+=a1; q1=fmaf(a1,a1,q1);
      s2+=a2; q2=fmaf(a2,a2,q2);  s3+=a3; q3=fmaf(a3,a3,q3);
      s4+=a4; q4=fmaf(a4,a4,q4);  s5+=a5; q5=fmaf(a5,a5,q5);
      s6+=a6; q6=fmaf(a6,a6,q6);  s7+=a7; q7=fmaf(a7,a7,q7);
    }
  }

  __shared__ float shS[16][128], shQ[16][128];
  *(float4*)&shS[grp][sl * 8]     = make_float4(s0, s1, s2, s3);
  *(float4*)&shS[grp][sl * 8 + 4] = make_float4(s4, s5, s6, s7);
  *(float4*)&shQ[grp][sl * 8]     = make_float4(q0, q1, q2, q3);
  *(float4*)&shQ[grp][sl * 8 + 4] = make_float4(q4, q5, q6, q7);
  __syncthreads();
  int t = ty * 64 + threadIdx.x;
  if (t < 128){
    float ss = 0.f, qq = 0.f;
    #pragma unroll
    for (int g2 = 0; g2 < 16; g2++){ ss += shS[g2][t]; qq += shQ[g2][t]; }
    float* dstat = stats + (blockIdx.x & 15) * 256;
    atomicAdd(&dstat[t], ss);
    atomicAdd(&dstat[128 + t], qq);
  }
}

// ============ layer-3 agg (40 ch bf16 pre-scaled) + bias + log_softmax ============
#define ACC2(U) do{ unsigned _u = (U); \
  acx += bfbits2f((unsigned short)(_u & 0xffffu)); \
  acy += bfbits2f((unsigned short)(_u >> 16)); }while(0)

__global__ __launch_bounds__(256) void k_agg40lsm(const unsigned short* __restrict__ hw,
                                                  const int* __restrict__ rs,
                                                  const int* __restrict__ csr,
                                                  const float* __restrict__ dinv,
                                                  const float* __restrict__ b3,
                                                  float* __restrict__ out, int N)
{
  int half = (threadIdx.x >> 5) & 1;
  int sl = threadIdx.x & 31;
  int v = blockIdx.x * 8 + threadIdx.y * 2 + half;
  bool nact = (v < N);
  bool act = nact && (sl < 20);
  const unsigned* h2 = (const unsigned*)hw;        // row = 20 u32 (80 B)
  float acx = 0.f, acy = 0.f, dv = 1.f;
  if (act){
    dv = dinv[v];
    ACC2(h2[(size_t)v * 20 + sl]);
    int e0 = rs[v], e1 = rs[v + 1];
    int i = e0;
    for (; i + 4 <= e1; i += 4){
      int s0 = csr[i], s1 = csr[i+1], s2 = csr[i+2], s3 = csr[i+3];
      unsigned u0 = h2[(size_t)s0 * 20 + sl];
      unsigned u1 = h2[(size_t)s1 * 20 + sl];
      unsigned u2 = h2[(size_t)s2 * 20 + sl];
      unsigned u3 = h2[(size_t)s3 * 20 + sl];
      ACC2(u0); ACC2(u1); ACC2(u2); ACC2(u3);
    }
    for (; i < e1; i++){
      ACC2(h2[(size_t)csr[i] * 20 + sl]);
    }
  }
  float x0 = act ? fmaf(acx, dv, b3[2 * sl])     : -INFINITY;
  float x1 = act ? fmaf(acy, dv, b3[2 * sl + 1]) : -INFINITY;
  float m = fmaxf(x0, x1);
  #pragma unroll
  for (int off = 16; off; off >>= 1) m = fmaxf(m, __shfl_xor(m, off, 32));
  float e = act ? (expf(x0 - m) + expf(x1 - m)) : 0.f;
  #pragma unroll
  for (int off = 16; off; off >>= 1) e += __shfl_xor(e, off, 32);
  float lse = m + logf(e);
  if (act){
    float2 o; o.x = x0 - lse; o.y = x1 - lse;
    *reinterpret_cast<float2*>(out + (size_t)v * 40 + 2 * sl) = o;
  }
}

// ================= launch =================
extern "C" void kernel_launch(void* const* d_in, const int* in_sizes, int n_in,
                              void* d_out, int out_size, void* d_ws, size_t ws_size,
                              hipStream_t stream)
{
  const float* x  = (const float*)d_in[0];
  const int* ei   = (const int*)d_in[1];
  const float* W1 = (const float*)d_in[2];
  const float* g1 = (const float*)d_in[4];
  const float* be1= (const float*)d_in[5];
  const float* W2 = (const float*)d_in[6];
  const float* g2 = (const float*)d_in[8];
  const float* be2= (const float*)d_in[9];
  const float* W3 = (const float*)d_in[10];
  const float* b3 = (const float*)d_in[11];
  float* out = (float*)d_out;
  // b1, b2 unused: per-channel constants cancel exactly in training-mode BN.

  const int N = in_sizes[0] / 128;
  const int E = in_sizes[1] / 2;
  const int* srcv = ei;
  const int* dstv = ei + E;

  char* ws = (char*)d_ws;
  size_t off = 0;
  auto take = [&](size_t bytes) -> void* {
    void* p = ws + off;
    off = (off + bytes + 255) & ~(size_t)255;
    return p;
  };
  int*   cnt      = (int*)  take((size_t)N * 4);
  int*   pos      = (int*)  take((size_t)E * 4);
  int*   rowstart = (int*)  take((size_t)(N + 1) * 4);
  int*   csr      = (int*)  take((size_t)E * 4);
  float* dinv     = (float*)take((size_t)N * 4);
  int*   bsum     = (int*)  take(256 * 4);
  int*   boff     = (int*)  take(256 * 4);
  float* stats    = (float*)take(16 * 256 * 4);        // 16 banked copies
  unsigned short* WT1 = (unsigned short*)take(128 * 128 * 2);
  unsigned short* WT2 = (unsigned short*)take(128 * 128 * 2);
  unsigned short* WT3 = (unsigned short*)take(48 * 128 * 2);
  unsigned short* bufX = (unsigned short*)take((size_t)N * 128 * 2);
  unsigned short* bufY = (unsigned short*)take((size_t)N * 128 * 2);
  (void)ws_size; (void)n_in; (void)out_size;

  // dropout subkeys: jax.random.split(key(42), 2), partitionable fold
  unsigned l1k0, l1k1, l2k0, l2k1;
  tf2x32(0u, 42u, 0u, 0u, l1k0, l1k1);
  tf2x32(0u, 42u, 0u, 1u, l2k0, l2k1);

  const float invN = 1.0f / (float)N;
  const int NB = (N + 1023) / 1024;
  dim3 wgrid8((N + 7) / 8), wblk(64, 4);
  dim3 wgrid32((N + 31) / 32);
  const int ggrid = (N + 63) / 64;
  const int egrid = (E + 1023) / 1024;

  // ---- graph structure ----
  hipMemsetAsync(cnt, 0, (size_t)N * 4, stream);
  k_countpos<<<egrid, 256, 0, stream>>>(dstv, cnt, pos, E);
  k_blocksum<<<NB, 256, 0, stream>>>(cnt, bsum, N);
  k_scansums<<<1, 256, 0, stream>>>(bsum, boff, rowstart, NB, N);
  k_scanfinal<<<NB, 256, 0, stream>>>(cnt, boff, rowstart, dinv, N);
  k_fill<<<egrid, 256, 0, stream>>>(srcv, dstv, pos, rowstart, csr, E);
  k_wt<<<3, 256, 0, stream>>>(W1, W2, W3, WT1, WT2, WT3);

  // ---- layer 1 ----
  k_gemm_mfma<8, 0><<<ggrid, 256, 0, stream>>>(x, WT1, dinv,
      nullptr, nullptr, nullptr, 0u, 0u, invN, bufX, N, 128);
  hipMemsetAsync(stats, 0, 16 * 256 * 4, stream);
  k_agg128s<<<wgrid32, wblk, 0, stream>>>(bufX, rowstart, csr, dinv, bufY, stats, N);

  // ---- layer 2 (BN1+ReLU+dropout fused into A staging) ----
  k_gemm_mfma<8, 2><<<ggrid, 256, 0, stream>>>(bufY, WT2, dinv,
      stats, g1, be1, l1k0, l1k1, invN, bufX, N, 128);
  hipMemsetAsync(stats, 0, 16 * 256 * 4, stream);
  k_agg128s<<<wgrid32, wblk, 0, stream>>>(bufX, rowstart, csr, dinv, bufY, stats, N);

  // ---- layer 3 (BN2+ReLU+dropout fused) + log_softmax ----
  k_gemm_mfma<3, 2><<<ggrid, 256, 0, stream>>>(bufY, WT3, dinv,
      stats, g2, be2, l2k0, l2k1, invN, bufX, N, 40);
  k_agg40lsm<<<wgrid8, wblk, 0, stream>>>(bufX, rowstart, csr, dinv, b3, out, N);
}

// Round 10
// 415.614 us; speedup vs baseline: 2.3835x; 1.0080x over previous
//
#include <hip/hip_runtime.h>
#include <math.h>

typedef __attribute__((ext_vector_type(8))) short bf16x8;
typedef __attribute__((ext_vector_type(4))) float f32x4;

__device__ __forceinline__ float bfbits2f(unsigned short b){
  return __uint_as_float(((unsigned)b) << 16);
}
__device__ __forceinline__ unsigned short f2bfbits(float f){
  unsigned u = __float_as_uint(f);
  unsigned r = u + 0x7fffu + ((u >> 16) & 1u);
  return (unsigned short)(r >> 16);
}

// ================= Threefry-2x32 (JAX partitionable) =================
__host__ __device__ __forceinline__ unsigned rotl32(unsigned v, int d){
  return (v << d) | (v >> (32 - d));
}
__host__ __device__ __forceinline__ void tf2x32(unsigned k0, unsigned k1,
                                                unsigned c0, unsigned c1,
                                                unsigned &o0, unsigned &o1)
{
  unsigned ks2 = k0 ^ k1 ^ 0x1BD11BDAu;
  unsigned x0 = c0 + k0, x1 = c1 + k1;
#define TFR(r) x0 += x1; x1 = rotl32(x1, r); x1 ^= x0;
  TFR(13) TFR(15) TFR(26) TFR(6)
  x0 += k1;  x1 += ks2 + 1u;
  TFR(17) TFR(29) TFR(16) TFR(24)
  x0 += ks2; x1 += k0 + 2u;
  TFR(13) TFR(15) TFR(26) TFR(6)
  x0 += k0;  x1 += k1 + 3u;
  TFR(17) TFR(29) TFR(16) TFR(24)
  x0 += k1;  x1 += ks2 + 4u;
  TFR(13) TFR(15) TFR(26) TFR(6)
  x0 += ks2; x1 += k0 + 5u;
#undef TFR
  o0 = x0; o1 = x1;
}

// drop-mask generator: word wi covers elements wi*32..wi*32+31; bit = sign of
// partitionable random_bits (drop if set). Grid-stride; unroll 4 bounds VGPRs.
__device__ __forceinline__ void gen_mask(unsigned* __restrict__ mask,
                                         unsigned mk0, unsigned mk1,
                                         int g, int total, int M)
{
  for (int wi = g; wi < M; wi += total){
    unsigned bits = 0u;
    #pragma unroll 4
    for (int j = 0; j < 32; j++){
      unsigned w0, w1;
      tf2x32(mk0, mk1, 0u, (unsigned)wi * 32u + (unsigned)j, w0, w1);
      bits |= (((w0 ^ w1) >> 31) << j);
    }
    mask[wi] = bits;
  }
}

// ================= CSR build (+ hidden mask generation) =================
__global__ __launch_bounds__(256) void k_countpos(const int* __restrict__ dst,
                                                  int* __restrict__ cnt,
                                                  int* __restrict__ pos, int E,
                                                  unsigned* __restrict__ mask,
                                                  unsigned mk0, unsigned mk1, int M)
{
  int g = blockIdx.x * 256 + threadIdx.x;
  int base = g * 4;
  if (base + 3 < E){
    int4 d = ((const int4*)dst)[g];
    int4 p;
    p.x = atomicAdd(&cnt[d.x], 1);
    p.y = atomicAdd(&cnt[d.y], 1);
    p.z = atomicAdd(&cnt[d.z], 1);
    p.w = atomicAdd(&cnt[d.w], 1);
    ((int4*)pos)[g] = p;
  } else {
    for (int j = 0; j < 4; j++){
      int e = base + j;
      if (e < E) pos[e] = atomicAdd(&cnt[dst[e]], 1);
    }
  }
  gen_mask(mask, mk0, mk1, g, gridDim.x * 256, M);
}

__global__ __launch_bounds__(256) void k_blocksum(const int* __restrict__ cnt,
                                                  int* __restrict__ bsum, int N)
{
  __shared__ int sh[256];
  int t = threadIdx.x;
  int base = blockIdx.x * 1024 + t * 4;
  int s = 0;
  #pragma unroll
  for (int j = 0; j < 4; j++){ int i = base + j; if (i < N) s += cnt[i]; }
  sh[t] = s; __syncthreads();
  for (int off = 128; off; off >>= 1){
    if (t < off) sh[t] += sh[t + off];
    __syncthreads();
  }
  if (t == 0) bsum[blockIdx.x] = sh[0];
}

__global__ __launch_bounds__(256) void k_scansums(const int* __restrict__ bsum,
                                                  int* __restrict__ boff,
                                                  int* __restrict__ rowstart,
                                                  int NB, int N)
{
  __shared__ int sh[256];
  int t = threadIdx.x;
  int v = (t < NB) ? bsum[t] : 0;
  sh[t] = v; __syncthreads();
  for (int off = 1; off < 256; off <<= 1){
    int x = sh[t];
    int y = (t >= off) ? sh[t - off] : 0;
    __syncthreads();
    sh[t] = x + y;
    __syncthreads();
  }
  if (t < NB) boff[t] = sh[t] - v;
  if (t == NB - 1) rowstart[N] = sh[t];
}

__global__ __launch_bounds__(256) void k_scanfinal(const int* __restrict__ cnt,
                                                   const int* __restrict__ boff,
                                                   int* __restrict__ rowstart,
                                                   float* __restrict__ dinv, int N)
{
  __shared__ int sh[256];
  int t = threadIdx.x;
  int base = blockIdx.x * 1024 + t * 4;
  int c0 = 0, c1 = 0, c2 = 0, c3 = 0;
  if (base + 0 < N) c0 = cnt[base + 0];
  if (base + 1 < N) c1 = cnt[base + 1];
  if (base + 2 < N) c2 = cnt[base + 2];
  if (base + 3 < N) c3 = cnt[base + 3];
  int s = c0 + c1 + c2 + c3;
  sh[t] = s; __syncthreads();
  for (int off = 1; off < 256; off <<= 1){
    int x = sh[t];
    int y = (t >= off) ? sh[t - off] : 0;
    __syncthreads();
    sh[t] = x + y;
    __syncthreads();
  }
  int excl = sh[t] - s + boff[blockIdx.x];
  if (base + 0 < N){ rowstart[base+0] = excl;          dinv[base+0] = rsqrtf((float)c0 + 1.f); }
  if (base + 1 < N){ rowstart[base+1] = excl+c0;       dinv[base+1] = rsqrtf((float)c1 + 1.f); }
  if (base + 2 < N){ rowstart[base+2] = excl+c0+c1;    dinv[base+2] = rsqrtf((float)c2 + 1.f); }
  if (base + 3 < N){ rowstart[base+3] = excl+c0+c1+c2; dinv[base+3] = rsqrtf((float)c3 + 1.f); }
}

__global__ __launch_bounds__(256) void k_fill(const int* __restrict__ src,
                                              const int* __restrict__ dst,
                                              const int* __restrict__ pos,
                                              const int* __restrict__ rowstart,
                                              int* __restrict__ csr, int E,
                                              unsigned* __restrict__ mask,
                                              unsigned mk0, unsigned mk1, int M)
{
  int g = blockIdx.x * 256 + threadIdx.x;
  int base = g * 4;
  if (base + 3 < E){
    int4 d = ((const int4*)dst)[g];
    int4 p = ((const int4*)pos)[g];
    int4 s = ((const int4*)src)[g];
    int r0 = rowstart[d.x], r1 = rowstart[d.y], r2 = rowstart[d.z], r3 = rowstart[d.w];
    csr[r0 + p.x] = s.x;
    csr[r1 + p.y] = s.y;
    csr[r2 + p.z] = s.z;
    csr[r3 + p.w] = s.w;
  } else {
    for (int j = 0; j < 4; j++){
      int e = base + j;
      if (e < E) csr[rowstart[dst[e]] + pos[e]] = src[e];
    }
  }
  gen_mask(mask, mk0, mk1, g, gridDim.x * 256, M);
}

// ====== weight transpose: WT[n][k] bf16, row stride 128 (unpadded) ======
__global__ __launch_bounds__(256) void k_wt(const float* __restrict__ W1,
                                            const float* __restrict__ W2,
                                            const float* __restrict__ W3,
                                            unsigned short* __restrict__ WT1,
                                            unsigned short* __restrict__ WT2,
                                            unsigned short* __restrict__ WT3)
{
  const float* W; unsigned short* WT; int Cout, Cpad;
  if (blockIdx.x == 0){ W = W1; WT = WT1; Cout = 128; Cpad = 128; }
  else if (blockIdx.x == 1){ W = W2; WT = WT2; Cout = 128; Cpad = 128; }
  else { W = W3; WT = WT3; Cout = 40; Cpad = 48; }
  int tot = Cpad * 128;
  for (int i = threadIdx.x; i < tot; i += 256){
    int n = i >> 7, k = i & 127;
    float v = (n < Cout) ? W[k * Cout + n] : 0.f;
    WT[i] = f2bfbits(v);
  }
}

// ================= MFMA GEMM: wave-private A staging + precomputed drop mask ======
// MODE 0: A fp32 raw (layer 1). MODE 2: A bf16 + BN/ReLU + mask-based dropout.
template<int NT, int MODE>
__global__ __launch_bounds__(256) void k_gemm_mfma(const void* __restrict__ Ap,
                                                   const unsigned short* __restrict__ WT,
                                                   const float* __restrict__ dinv,
                                                   const float* __restrict__ stats,
                                                   const float* __restrict__ g,
                                                   const float* __restrict__ be,
                                                   const unsigned* __restrict__ mask,
                                                   float invN,
                                                   unsigned short* __restrict__ outb,
                                                   int N, int Cout)
{
  __shared__ uint4 Wl4[NT * 16 * 16];          // NT*16 rows x 16 chunks, swizzled
  __shared__ uint4 Al4[64 * 16];               // 64 rows x 16 chunks, swizzled
  __shared__ float bnS[128], bnB[128];
  const int t = threadIdx.x;
  const int w = t >> 6, l = t & 63;
  const long rb0 = (long)blockIdx.x * 64;
  const int wrow0 = w * 16;

  // ---- issue raw A (+mask) loads first (latency hidden behind W/bn stage) ----
  uint4 rawU[4];
  float4 rawF[4][2];
  unsigned mword[4];
  int rr[4], cc[4];
  bool inr[4];
  #pragma unroll
  for (int i = 0; i < 4; i++){
    int idx = i * 64 + l;
    int r = idx >> 4, c = idx & 15;
    long grow = rb0 + wrow0 + r;
    rr[i] = r; cc[i] = c; inr[i] = (grow < N);
    if (inr[i]){
      if (MODE == 0){
        const float* ap = (const float*)Ap + grow * 128 + c * 8;
        rawF[i][0] = *(const float4*)ap;
        rawF[i][1] = *(const float4*)(ap + 4);
      } else {
        rawU[i] = *(const uint4*)((const unsigned short*)Ap + grow * 128 + c * 8);
        mword[i] = mask[((unsigned)grow << 2) + (c >> 2)];
      }
    }
  }

  // ---- shared W stage (+ BN prep), single block barrier ----
  {
    const uint4* s4 = (const uint4*)WT;
    const int tot = NT * 16 * 16;
    for (int i = t; i < tot; i += 256){
      int n = i >> 4, c = i & 15;
      Wl4[n * 16 + (c ^ (n & 15))] = s4[i];
    }
  }
  if (MODE == 2 && t < 128){
    float ss = 0.f, qq = 0.f;
    #pragma unroll
    for (int i = 0; i < 16; i++){
      ss += stats[i * 256 + t];
      qq += stats[i * 256 + 128 + t];
    }
    float mean = ss * invN;
    float var = fmaxf(qq * invN - mean * mean, 0.f);
    float rstd = rsqrtf(var + 1e-5f);
    float sc = g[t] * rstd;
    bnS[t] = sc;
    bnB[t] = be[t] - mean * sc;
  }
  __syncthreads();

  // ---- transform + wave-private LDS write (no block barrier needed) ----
  #pragma unroll
  for (int i = 0; i < 4; i++){
    uint4 chunk = make_uint4(0u, 0u, 0u, 0u);
    if (inr[i]){
      if (MODE == 0){
        chunk.x = (unsigned)f2bfbits(rawF[i][0].x) | ((unsigned)f2bfbits(rawF[i][0].y) << 16);
        chunk.y = (unsigned)f2bfbits(rawF[i][0].z) | ((unsigned)f2bfbits(rawF[i][0].w) << 16);
        chunk.z = (unsigned)f2bfbits(rawF[i][1].x) | ((unsigned)f2bfbits(rawF[i][1].y) << 16);
        chunk.w = (unsigned)f2bfbits(rawF[i][1].z) | ((unsigned)f2bfbits(rawF[i][1].w) << 16);
      } else {
        unsigned mb = mword[i] >> ((cc[i] & 3) * 8);   // 8 drop bits for this chunk
        const unsigned* rw = &rawU[i].x;
        unsigned* cw = &chunk.x;
        #pragma unroll
        for (int h = 0; h < 4; h++){
          int ch = cc[i] * 8 + 2 * h;
          float f0 = bfbits2f((unsigned short)(rw[h] & 0xffffu));
          float f1 = bfbits2f((unsigned short)(rw[h] >> 16));
          f0 = fmaxf(fmaf(f0, bnS[ch],     bnB[ch]),     0.f);
          f1 = fmaxf(fmaf(f1, bnS[ch + 1], bnB[ch + 1]), 0.f);
          f0 = ((mb >> (2 * h))     & 1u) ? 0.f : f0 * 2.f;
          f1 = ((mb >> (2 * h + 1)) & 1u) ? 0.f : f1 * 2.f;
          cw[h] = (unsigned)f2bfbits(f0) | ((unsigned)f2bfbits(f1) << 16);
        }
      }
    }
    Al4[(wrow0 + rr[i]) * 16 + (cc[i] ^ rr[i])] = chunk;
  }

  const int lm = l & 15, q = l >> 4;

  f32x4 acc[NT];
  #pragma unroll
  for (int nt = 0; nt < NT; nt++){
    acc[nt][0] = 0.f; acc[nt][1] = 0.f; acc[nt][2] = 0.f; acc[nt][3] = 0.f;
  }

  #pragma unroll
  for (int kt = 0; kt < 4; kt++){
    const int x = kt * 4 + q;
    bf16x8 a = *(const bf16x8*)&Al4[(wrow0 + lm) * 16 + (x ^ lm)];
    #pragma unroll
    for (int nt = 0; nt < NT; nt++){
      int brow = nt * 16 + lm;
      bf16x8 b = *(const bf16x8*)&Wl4[brow * 16 + (x ^ (brow & 15))];
      acc[nt] = __builtin_amdgcn_mfma_f32_16x16x32_bf16(a, b, acc[nt], 0, 0, 0);
    }
  }

  #pragma unroll
  for (int r = 0; r < 4; r++){
    long row = rb0 + wrow0 + q * 4 + r;
    if (row < N){
      float dv = dinv[row];
      #pragma unroll
      for (int nt = 0; nt < NT; nt++){
        int col = nt * 16 + lm;
        if (col < Cout)
          outb[row * Cout + col] = f2bfbits(acc[nt][r] * dv);
      }
    }
  }
}

// ====== aggregation (128 ch) + fused BN-stat accumulation ======
#define ACC8(U) do{ uint4 _u = (U); \
  a0 += bfbits2f((unsigned short)(_u.x & 0xffffu)); \
  a1 += bfbits2f((unsigned short)(_u.x >> 16)); \
  a2 += bfbits2f((unsigned short)(_u.y & 0xffffu)); \
  a3 += bfbits2f((unsigned short)(_u.y >> 16)); \
  a4 += bfbits2f((unsigned short)(_u.z & 0xffffu)); \
  a5 += bfbits2f((unsigned short)(_u.z >> 16)); \
  a6 += bfbits2f((unsigned short)(_u.w & 0xffffu)); \
  a7 += bfbits2f((unsigned short)(_u.w >> 16)); }while(0)

__global__ __launch_bounds__(256) void k_agg128s(const unsigned short* __restrict__ hw,
                                                 const int* __restrict__ rs,
                                                 const int* __restrict__ csr,
                                                 const float* __restrict__ dinv,
                                                 unsigned short* __restrict__ outb,
                                                 float* __restrict__ stats,
                                                 int N)
{
  const int l = threadIdx.x;
  const int ns = l >> 4;                 // node-sub 0..3
  const int sl = l & 15;                 // sublane 0..15
  const int ty = threadIdx.y;
  const int grp = ty * 4 + ns;           // 0..15 chain id
  const uint4* h16 = (const uint4*)hw;   // row = 16 uint4 (256 B)
  const int base = blockIdx.x * 32;

  float s0=0.f,s1=0.f,s2=0.f,s3=0.f,s4=0.f,s5=0.f,s6=0.f,s7=0.f;
  float q0=0.f,q1=0.f,q2=0.f,q3=0.f,q4=0.f,q5=0.f,q6=0.f,q7=0.f;

  #pragma unroll 1
  for (int it = 0; it < 2; it++){
    int v = base + it * 16 + grp;
    if (v < N){
      float a0=0.f,a1=0.f,a2=0.f,a3=0.f,a4=0.f,a5=0.f,a6=0.f,a7=0.f;
      ACC8(h16[(size_t)v * 16 + sl]);
      int e0 = rs[v], e1 = rs[v + 1];
      int i = e0;
      for (; i + 4 <= e1; i += 4){
        int sa = csr[i], sb = csr[i+1], sc = csr[i+2], sd = csr[i+3];
        uint4 m0 = h16[(size_t)sa * 16 + sl];
        uint4 m1 = h16[(size_t)sb * 16 + sl];
        uint4 m2 = h16[(size_t)sc * 16 + sl];
        uint4 m3 = h16[(size_t)sd * 16 + sl];
        ACC8(m0); ACC8(m1); ACC8(m2); ACC8(m3);
      }
      for (; i < e1; i++){
        ACC8(h16[(size_t)csr[i] * 16 + sl]);
      }
      float dv = dinv[v];
      a0*=dv; a1*=dv; a2*=dv; a3*=dv; a4*=dv; a5*=dv; a6*=dv; a7*=dv;
      uint4 o;
      o.x = (unsigned)f2bfbits(a0) | ((unsigned)f2bfbits(a1) << 16);
      o.y = (unsigned)f2bfbits(a2) | ((unsigned)f2bfbits(a3) << 16);
      o.z = (unsigned)f2bfbits(a4) | ((unsigned)f2bfbits(a5) << 16);
      o.w = (unsigned)f2bfbits(a6) | ((unsigned)f2bfbits(a7) << 16);
      ((uint4*)outb)[(size_t)v * 16 + sl] = o;
      s0+=a0; q0=fmaf(a0,a0,q0);  s1+=a1; q1=fmaf(a1,a1,q1);
      s2+=a2; q2=fmaf(a2,a2,q2);  s3+=a3; q3=fmaf(a3,a3,q3);
      s4+=a4; q4=fmaf(a4,a4,q4);  s5+=a5; q5=fmaf(a5,a5,q5);
      s6+=a6; q6=fmaf(a6,a6,q6);  s7+=a7; q7=fmaf(a7,a7,q7);
    }
  }

  __shared__ float shS[16][128], shQ[16][128];
  *(float4*)&shS[grp][sl * 8]     = make_float4(s0, s1, s2, s3);
  *(float4*)&shS[grp][sl * 8 + 4] = make_float4(s4, s5, s6, s7);
  *(float4*)&shQ[grp][sl * 8]     = make_float4(q0, q1, q2, q3);
  *(float4*)&shQ[grp][sl * 8 + 4] = make_float4(q4, q5, q6, q7);
  __syncthreads();
  int t = ty * 64 + threadIdx.x;
  if (t < 128){
    float ss = 0.f, qq = 0.f;
    #pragma unroll
    for (int g2 = 0; g2 < 16; g2++){ ss += shS[g2][t]; qq += shQ[g2][t]; }
    float* dstat = stats + (blockIdx.x & 15) * 256;
    atomicAdd(&dstat[t], ss);
    atomicAdd(&dstat[128 + t], qq);
  }
}

// ============ layer-3 agg (40 ch bf16 pre-scaled) + bias + log_softmax ============
#define ACC2(U) do{ unsigned _u = (U); \
  acx += bfbits2f((unsigned short)(_u & 0xffffu)); \
  acy += bfbits2f((unsigned short)(_u >> 16)); }while(0)

__global__ __launch_bounds__(256) void k_agg40lsm(const unsigned short* __restrict__ hw,
                                                  const int* __restrict__ rs,
                                                  const int* __restrict__ csr,
                                                  const float* __restrict__ dinv,
                                                  const float* __restrict__ b3,
                                                  float* __restrict__ out, int N)
{
  int half = (threadIdx.x >> 5) & 1;
  int sl = threadIdx.x & 31;
  int v = blockIdx.x * 8 + threadIdx.y * 2 + half;
  bool nact = (v < N);
  bool act = nact && (sl < 20);
  const unsigned* h2 = (const unsigned*)hw;        // row = 20 u32 (80 B)
  float acx = 0.f, acy = 0.f, dv = 1.f;
  if (act){
    dv = dinv[v];
    ACC2(h2[(size_t)v * 20 + sl]);
    int e0 = rs[v], e1 = rs[v + 1];
    int i = e0;
    for (; i + 4 <= e1; i += 4){
      int s0 = csr[i], s1 = csr[i+1], s2 = csr[i+2], s3 = csr[i+3];
      unsigned u0 = h2[(size_t)s0 * 20 + sl];
      unsigned u1 = h2[(size_t)s1 * 20 + sl];
      unsigned u2 = h2[(size_t)s2 * 20 + sl];
      unsigned u3 = h2[(size_t)s3 * 20 + sl];
      ACC2(u0); ACC2(u1); ACC2(u2); ACC2(u3);
    }
    for (; i < e1; i++){
      ACC2(h2[(size_t)csr[i] * 20 + sl]);
    }
  }
  float x0 = act ? fmaf(acx, dv, b3[2 * sl])     : -INFINITY;
  float x1 = act ? fmaf(acy, dv, b3[2 * sl + 1]) : -INFINITY;
  float m = fmaxf(x0, x1);
  #pragma unroll
  for (int off = 16; off; off >>= 1) m = fmaxf(m, __shfl_xor(m, off, 32));
  float e = act ? (expf(x0 - m) + expf(x1 - m)) : 0.f;
  #pragma unroll
  for (int off = 16; off; off >>= 1) e += __shfl_xor(e, off, 32);
  float lse = m + logf(e);
  if (act){
    float2 o; o.x = x0 - lse; o.y = x1 - lse;
    *reinterpret_cast<float2*>(out + (size_t)v * 40 + 2 * sl) = o;
  }
}

// ================= launch =================
extern "C" void kernel_launch(void* const* d_in, const int* in_sizes, int n_in,
                              void* d_out, int out_size, void* d_ws, size_t ws_size,
                              hipStream_t stream)
{
  const float* x  = (const float*)d_in[0];
  const int* ei   = (const int*)d_in[1];
  const float* W1 = (const float*)d_in[2];
  const float* g1 = (const float*)d_in[4];
  const float* be1= (const float*)d_in[5];
  const float* W2 = (const float*)d_in[6];
  const float* g2 = (const float*)d_in[8];
  const float* be2= (const float*)d_in[9];
  const float* W3 = (const float*)d_in[10];
  const float* b3 = (const float*)d_in[11];
  float* out = (float*)d_out;
  // b1, b2 unused: per-channel constants cancel exactly in training-mode BN.

  const int N = in_sizes[0] / 128;
  const int E = in_sizes[1] / 2;
  const int* srcv = ei;
  const int* dstv = ei + E;

  char* ws = (char*)d_ws;
  size_t off = 0;
  auto take = [&](size_t bytes) -> void* {
    void* p = ws + off;
    off = (off + bytes + 255) & ~(size_t)255;
    return p;
  };
  int*   cnt      = (int*)  take((size_t)N * 4);
  int*   pos      = (int*)  take((size_t)E * 4);
  int*   rowstart = (int*)  take((size_t)(N + 1) * 4);
  int*   csr      = (int*)  take((size_t)E * 4);
  float* dinv     = (float*)take((size_t)N * 4);
  int*   bsum     = (int*)  take(256 * 4);
  int*   boff     = (int*)  take(256 * 4);
  float* stats    = (float*)take(16 * 256 * 4);        // 16 banked copies
  unsigned* mask1 = (unsigned*)take((size_t)N * 4 * 4);  // N*128 bits
  unsigned* mask2 = (unsigned*)take((size_t)N * 4 * 4);
  unsigned short* WT1 = (unsigned short*)take(128 * 128 * 2);
  unsigned short* WT2 = (unsigned short*)take(128 * 128 * 2);
  unsigned short* WT3 = (unsigned short*)take(48 * 128 * 2);
  unsigned short* bufX = (unsigned short*)take((size_t)N * 128 * 2);
  unsigned short* bufY = (unsigned short*)take((size_t)N * 128 * 2);
  (void)ws_size; (void)n_in; (void)out_size;

  // dropout subkeys: jax.random.split(key(42), 2), partitionable fold
  unsigned l1k0, l1k1, l2k0, l2k1;
  tf2x32(0u, 42u, 0u, 0u, l1k0, l1k1);
  tf2x32(0u, 42u, 0u, 1u, l2k0, l2k1);

  const float invN = 1.0f / (float)N;
  const int M = N * 4;                  // mask words (N*128/32)
  const int NB = (N + 1023) / 1024;
  dim3 wgrid8((N + 7) / 8), wblk(64, 4);
  dim3 wgrid32((N + 31) / 32);
  const int ggrid = (N + 63) / 64;
  const int egrid = (E + 1023) / 1024;

  // ---- graph structure (+ mask generation hidden under scatter latency) ----
  hipMemsetAsync(cnt, 0, (size_t)N * 4, stream);
  k_countpos<<<egrid, 256, 0, stream>>>(dstv, cnt, pos, E, mask1, l1k0, l1k1, M);
  k_blocksum<<<NB, 256, 0, stream>>>(cnt, bsum, N);
  k_scansums<<<1, 256, 0, stream>>>(bsum, boff, rowstart, NB, N);
  k_scanfinal<<<NB, 256, 0, stream>>>(cnt, boff, rowstart, dinv, N);
  k_fill<<<egrid, 256, 0, stream>>>(srcv, dstv, pos, rowstart, csr, E, mask2, l2k0, l2k1, M);
  k_wt<<<3, 256, 0, stream>>>(W1, W2, W3, WT1, WT2, WT3);

  // ---- layer 1 ----
  k_gemm_mfma<8, 0><<<ggrid, 256, 0, stream>>>(x, WT1, dinv,
      nullptr, nullptr, nullptr, nullptr, invN, bufX, N, 128);
  hipMemsetAsync(stats, 0, 16 * 256 * 4, stream);
  k_agg128s<<<wgrid32, wblk, 0, stream>>>(bufX, rowstart, csr, dinv, bufY, stats, N);

  // ---- layer 2 (BN1+ReLU+dropout-mask fused into A staging) ----
  k_gemm_mfma<8, 2><<<ggrid, 256, 0, stream>>>(bufY, WT2, dinv,
      stats, g1, be1, mask1, invN, bufX, N, 128);
  hipMemsetAsync(stats, 0, 16 * 256 * 4, stream);
  k_agg128s<<<wgrid32, wblk, 0, stream>>>(bufX, rowstart, csr, dinv, bufY, stats, N);

  // ---- layer 3 (BN2+ReLU+dropout-mask fused) + log_softmax ----
  k_gemm_mfma<3, 2><<<ggrid, 256, 0, stream>>>(bufY, WT3, dinv,
      stats, g2, be2, mask2, invN, bufX, N, 40);
  k_agg40lsm<<<wgrid8, wblk, 0, stream>>>(bufX, rowstart, csr, dinv, b3, out, N);
}

// Round 11
// 401.029 us; speedup vs baseline: 2.4702x; 1.0364x over previous
//
#include <hip/hip_runtime.h>
#include <math.h>

typedef __attribute__((ext_vector_type(8))) short bf16x8;
typedef __attribute__((ext_vector_type(4))) float f32x4;

__device__ __forceinline__ float bfbits2f(unsigned short b){
  return __uint_as_float(((unsigned)b) << 16);
}
__device__ __forceinline__ unsigned short f2bfbits(float f){
  unsigned u = __float_as_uint(f);
  unsigned r = u + 0x7fffu + ((u >> 16) & 1u);
  return (unsigned short)(r >> 16);
}

// ================= Threefry-2x32 (JAX partitionable) =================
__host__ __device__ __forceinline__ unsigned rotl32(unsigned v, int d){
  return (v << d) | (v >> (32 - d));
}
__host__ __device__ __forceinline__ void tf2x32(unsigned k0, unsigned k1,
                                                unsigned c0, unsigned c1,
                                                unsigned &o0, unsigned &o1)
{
  unsigned ks2 = k0 ^ k1 ^ 0x1BD11BDAu;
  unsigned x0 = c0 + k0, x1 = c1 + k1;
#define TFR(r) x0 += x1; x1 = rotl32(x1, r); x1 ^= x0;
  TFR(13) TFR(15) TFR(26) TFR(6)
  x0 += k1;  x1 += ks2 + 1u;
  TFR(17) TFR(29) TFR(16) TFR(24)
  x0 += ks2; x1 += k0 + 2u;
  TFR(13) TFR(15) TFR(26) TFR(6)
  x0 += k0;  x1 += k1 + 3u;
  TFR(17) TFR(29) TFR(16) TFR(24)
  x0 += k1;  x1 += ks2 + 4u;
  TFR(13) TFR(15) TFR(26) TFR(6)
  x0 += ks2; x1 += k0 + 5u;
#undef TFR
  o0 = x0; o1 = x1;
}

// drop-mask generator: word wi covers elements wi*32..wi*32+31; bit = sign of
// partitionable random_bits (drop if set). Grid-stride; unroll 4 bounds VGPRs.
__device__ __forceinline__ void gen_mask(unsigned* __restrict__ mask,
                                         unsigned mk0, unsigned mk1,
                                         int g, int total, int M)
{
  for (int wi = g; wi < M; wi += total){
    unsigned bits = 0u;
    #pragma unroll 4
    for (int j = 0; j < 32; j++){
      unsigned w0, w1;
      tf2x32(mk0, mk1, 0u, (unsigned)wi * 32u + (unsigned)j, w0, w1);
      bits |= (((w0 ^ w1) >> 31) << j);
    }
    mask[wi] = bits;
  }
}

// ================= CSR build =================
__global__ __launch_bounds__(256) void k_countpos(const int* __restrict__ dst,
                                                  int* __restrict__ cnt,
                                                  int* __restrict__ pos, int E)
{
  int g = blockIdx.x * 256 + threadIdx.x;
  int base = g * 4;
  if (base + 3 < E){
    int4 d = ((const int4*)dst)[g];
    int4 p;
    p.x = atomicAdd(&cnt[d.x], 1);
    p.y = atomicAdd(&cnt[d.y], 1);
    p.z = atomicAdd(&cnt[d.z], 1);
    p.w = atomicAdd(&cnt[d.w], 1);
    ((int4*)pos)[g] = p;
  } else {
    for (int j = 0; j < 4; j++){
      int e = base + j;
      if (e < E) pos[e] = atomicAdd(&cnt[dst[e]], 1);
    }
  }
}

__global__ __launch_bounds__(256) void k_blocksum(const int* __restrict__ cnt,
                                                  int* __restrict__ bsum, int N)
{
  __shared__ int sh[256];
  int t = threadIdx.x;
  int base = blockIdx.x * 1024 + t * 4;
  int s = 0;
  #pragma unroll
  for (int j = 0; j < 4; j++){ int i = base + j; if (i < N) s += cnt[i]; }
  sh[t] = s; __syncthreads();
  for (int off = 128; off; off >>= 1){
    if (t < off) sh[t] += sh[t + off];
    __syncthreads();
  }
  if (t == 0) bsum[blockIdx.x] = sh[0];
}

__global__ __launch_bounds__(256) void k_scansums(const int* __restrict__ bsum,
                                                  int* __restrict__ boff,
                                                  int* __restrict__ rowstart,
                                                  int NB, int N)
{
  __shared__ int sh[256];
  int t = threadIdx.x;
  int v = (t < NB) ? bsum[t] : 0;
  sh[t] = v; __syncthreads();
  for (int off = 1; off < 256; off <<= 1){
    int x = sh[t];
    int y = (t >= off) ? sh[t - off] : 0;
    __syncthreads();
    sh[t] = x + y;
    __syncthreads();
  }
  if (t < NB) boff[t] = sh[t] - v;
  if (t == NB - 1) rowstart[N] = sh[t];
}

__global__ __launch_bounds__(256) void k_scanfinal(const int* __restrict__ cnt,
                                                   const int* __restrict__ boff,
                                                   int* __restrict__ rowstart,
                                                   float* __restrict__ dinv, int N)
{
  __shared__ int sh[256];
  int t = threadIdx.x;
  int base = blockIdx.x * 1024 + t * 4;
  int c0 = 0, c1 = 0, c2 = 0, c3 = 0;
  if (base + 0 < N) c0 = cnt[base + 0];
  if (base + 1 < N) c1 = cnt[base + 1];
  if (base + 2 < N) c2 = cnt[base + 2];
  if (base + 3 < N) c3 = cnt[base + 3];
  int s = c0 + c1 + c2 + c3;
  sh[t] = s; __syncthreads();
  for (int off = 1; off < 256; off <<= 1){
    int x = sh[t];
    int y = (t >= off) ? sh[t - off] : 0;
    __syncthreads();
    sh[t] = x + y;
    __syncthreads();
  }
  int excl = sh[t] - s + boff[blockIdx.x];
  if (base + 0 < N){ rowstart[base+0] = excl;          dinv[base+0] = rsqrtf((float)c0 + 1.f); }
  if (base + 1 < N){ rowstart[base+1] = excl+c0;       dinv[base+1] = rsqrtf((float)c1 + 1.f); }
  if (base + 2 < N){ rowstart[base+2] = excl+c0+c1;    dinv[base+2] = rsqrtf((float)c2 + 1.f); }
  if (base + 3 < N){ rowstart[base+3] = excl+c0+c1+c2; dinv[base+3] = rsqrtf((float)c3 + 1.f); }
}

__global__ __launch_bounds__(256) void k_fill(const int* __restrict__ src,
                                              const int* __restrict__ dst,
                                              const int* __restrict__ pos,
                                              const int* __restrict__ rowstart,
                                              int* __restrict__ csr, int E)
{
  int g = blockIdx.x * 256 + threadIdx.x;
  int base = g * 4;
  if (base + 3 < E){
    int4 d = ((const int4*)dst)[g];
    int4 p = ((const int4*)pos)[g];
    int4 s = ((const int4*)src)[g];
    int r0 = rowstart[d.x], r1 = rowstart[d.y], r2 = rowstart[d.z], r3 = rowstart[d.w];
    csr[r0 + p.x] = s.x;
    csr[r1 + p.y] = s.y;
    csr[r2 + p.z] = s.z;
    csr[r3 + p.w] = s.w;
  } else {
    for (int j = 0; j < 4; j++){
      int e = base + j;
      if (e < E) csr[rowstart[dst[e]] + pos[e]] = src[e];
    }
  }
}

// ====== weight transpose: WT[n][k] bf16, row stride 128 (unpadded) ======
__global__ __launch_bounds__(256) void k_wt(const float* __restrict__ W1,
                                            const float* __restrict__ W2,
                                            const float* __restrict__ W3,
                                            unsigned short* __restrict__ WT1,
                                            unsigned short* __restrict__ WT2,
                                            unsigned short* __restrict__ WT3)
{
  const float* W; unsigned short* WT; int Cout, Cpad;
  if (blockIdx.x == 0){ W = W1; WT = WT1; Cout = 128; Cpad = 128; }
  else if (blockIdx.x == 1){ W = W2; WT = WT2; Cout = 128; Cpad = 128; }
  else { W = W3; WT = WT3; Cout = 40; Cpad = 48; }
  int tot = Cpad * 128;
  for (int i = threadIdx.x; i < tot; i += 256){
    int n = i >> 7, k = i & 127;
    float v = (n < Cout) ? W[k * Cout + n] : 0.f;
    WT[i] = f2bfbits(v);
  }
}

// ================= MFMA GEMM: wave-private A staging + precomputed drop mask ======
// MODE 0: A fp32 raw (layer 1). MODE 2: A bf16 + BN/ReLU + mask-based dropout.
template<int NT, int MODE>
__global__ __launch_bounds__(256) void k_gemm_mfma(const void* __restrict__ Ap,
                                                   const unsigned short* __restrict__ WT,
                                                   const float* __restrict__ dinv,
                                                   const float* __restrict__ stats,
                                                   const float* __restrict__ g,
                                                   const float* __restrict__ be,
                                                   const unsigned* __restrict__ mask,
                                                   float invN,
                                                   unsigned short* __restrict__ outb,
                                                   int N, int Cout)
{
  __shared__ uint4 Wl4[NT * 16 * 16];          // NT*16 rows x 16 chunks, swizzled
  __shared__ uint4 Al4[64 * 16];               // 64 rows x 16 chunks, swizzled
  __shared__ float bnS[128], bnB[128];
  const int t = threadIdx.x;
  const int w = t >> 6, l = t & 63;
  const long rb0 = (long)blockIdx.x * 64;
  const int wrow0 = w * 16;

  // ---- issue raw A (+mask) loads first (latency hidden behind W/bn stage) ----
  uint4 rawU[4];
  float4 rawF[4][2];
  unsigned mword[4];
  int rr[4], cc[4];
  bool inr[4];
  #pragma unroll
  for (int i = 0; i < 4; i++){
    int idx = i * 64 + l;
    int r = idx >> 4, c = idx & 15;
    long grow = rb0 + wrow0 + r;
    rr[i] = r; cc[i] = c; inr[i] = (grow < N);
    if (inr[i]){
      if (MODE == 0){
        const float* ap = (const float*)Ap + grow * 128 + c * 8;
        rawF[i][0] = *(const float4*)ap;
        rawF[i][1] = *(const float4*)(ap + 4);
      } else {
        rawU[i] = *(const uint4*)((const unsigned short*)Ap + grow * 128 + c * 8);
        mword[i] = mask[((unsigned)grow << 2) + (c >> 2)];
      }
    }
  }

  // ---- shared W stage (+ BN prep), single block barrier ----
  {
    const uint4* s4 = (const uint4*)WT;
    const int tot = NT * 16 * 16;
    for (int i = t; i < tot; i += 256){
      int n = i >> 4, c = i & 15;
      Wl4[n * 16 + (c ^ (n & 15))] = s4[i];
    }
  }
  if (MODE == 2 && t < 128){
    float ss = 0.f, qq = 0.f;
    #pragma unroll
    for (int i = 0; i < 16; i++){
      ss += stats[i * 256 + t];
      qq += stats[i * 256 + 128 + t];
    }
    float mean = ss * invN;
    float var = fmaxf(qq * invN - mean * mean, 0.f);
    float rstd = rsqrtf(var + 1e-5f);
    float sc = g[t] * rstd;
    bnS[t] = sc;
    bnB[t] = be[t] - mean * sc;
  }
  __syncthreads();

  // ---- transform + wave-private LDS write (no block barrier needed) ----
  #pragma unroll
  for (int i = 0; i < 4; i++){
    uint4 chunk = make_uint4(0u, 0u, 0u, 0u);
    if (inr[i]){
      if (MODE == 0){
        chunk.x = (unsigned)f2bfbits(rawF[i][0].x) | ((unsigned)f2bfbits(rawF[i][0].y) << 16);
        chunk.y = (unsigned)f2bfbits(rawF[i][0].z) | ((unsigned)f2bfbits(rawF[i][0].w) << 16);
        chunk.z = (unsigned)f2bfbits(rawF[i][1].x) | ((unsigned)f2bfbits(rawF[i][1].y) << 16);
        chunk.w = (unsigned)f2bfbits(rawF[i][1].z) | ((unsigned)f2bfbits(rawF[i][1].w) << 16);
      } else {
        unsigned mb = mword[i] >> ((cc[i] & 3) * 8);   // 8 drop bits for this chunk
        const unsigned* rw = &rawU[i].x;
        unsigned* cw = &chunk.x;
        #pragma unroll
        for (int h = 0; h < 4; h++){
          int ch = cc[i] * 8 + 2 * h;
          float f0 = bfbits2f((unsigned short)(rw[h] & 0xffffu));
          float f1 = bfbits2f((unsigned short)(rw[h] >> 16));
          f0 = fmaxf(fmaf(f0, bnS[ch],     bnB[ch]),     0.f);
          f1 = fmaxf(fmaf(f1, bnS[ch + 1], bnB[ch + 1]), 0.f);
          f0 = ((mb >> (2 * h))     & 1u) ? 0.f : f0 * 2.f;
          f1 = ((mb >> (2 * h + 1)) & 1u) ? 0.f : f1 * 2.f;
          cw[h] = (unsigned)f2bfbits(f0) | ((unsigned)f2bfbits(f1) << 16);
        }
      }
    }
    Al4[(wrow0 + rr[i]) * 16 + (cc[i] ^ rr[i])] = chunk;
  }

  const int lm = l & 15, q = l >> 4;

  f32x4 acc[NT];
  #pragma unroll
  for (int nt = 0; nt < NT; nt++){
    acc[nt][0] = 0.f; acc[nt][1] = 0.f; acc[nt][2] = 0.f; acc[nt][3] = 0.f;
  }

  #pragma unroll
  for (int kt = 0; kt < 4; kt++){
    const int x = kt * 4 + q;
    bf16x8 a = *(const bf16x8*)&Al4[(wrow0 + lm) * 16 + (x ^ lm)];
    #pragma unroll
    for (int nt = 0; nt < NT; nt++){
      int brow = nt * 16 + lm;
      bf16x8 b = *(const bf16x8*)&Wl4[brow * 16 + (x ^ (brow & 15))];
      acc[nt] = __builtin_amdgcn_mfma_f32_16x16x32_bf16(a, b, acc[nt], 0, 0, 0);
    }
  }

  #pragma unroll
  for (int r = 0; r < 4; r++){
    long row = rb0 + wrow0 + q * 4 + r;
    if (row < N){
      float dv = dinv[row];
      #pragma unroll
      for (int nt = 0; nt < NT; nt++){
        int col = nt * 16 + lm;
        if (col < Cout)
          outb[row * Cout + col] = f2bfbits(acc[nt][r] * dv);
      }
    }
  }
}

// ====== aggregation (128 ch) + fused BN stats + hidden mask generation ======
#define ACC8(U) do{ uint4 _u = (U); \
  a0 += bfbits2f((unsigned short)(_u.x & 0xffffu)); \
  a1 += bfbits2f((unsigned short)(_u.x >> 16)); \
  a2 += bfbits2f((unsigned short)(_u.y & 0xffffu)); \
  a3 += bfbits2f((unsigned short)(_u.y >> 16)); \
  a4 += bfbits2f((unsigned short)(_u.z & 0xffffu)); \
  a5 += bfbits2f((unsigned short)(_u.z >> 16)); \
  a6 += bfbits2f((unsigned short)(_u.w & 0xffffu)); \
  a7 += bfbits2f((unsigned short)(_u.w >> 16)); }while(0)

__global__ __launch_bounds__(256) void k_agg128s(const unsigned short* __restrict__ hw,
                                                 const int* __restrict__ rs,
                                                 const int* __restrict__ csr,
                                                 const float* __restrict__ dinv,
                                                 unsigned short* __restrict__ outb,
                                                 float* __restrict__ stats,
                                                 unsigned* __restrict__ mask,
                                                 unsigned mk0, unsigned mk1, int M,
                                                 int N)
{
  const int l = threadIdx.x;
  const int ns = l >> 4;                 // node-sub 0..3
  const int sl = l & 15;                 // sublane 0..15
  const int ty = threadIdx.y;
  const int grp = ty * 4 + ns;           // 0..15 chain id
  const uint4* h16 = (const uint4*)hw;   // row = 16 uint4 (256 B)
  const int base = blockIdx.x * 32;

  // hidden VALU work: next layer's dropout mask (83% idle VALU slots here)
  gen_mask(mask, mk0, mk1, blockIdx.x * 256 + ty * 64 + l, gridDim.x * 256, M);

  float s0=0.f,s1=0.f,s2=0.f,s3=0.f,s4=0.f,s5=0.f,s6=0.f,s7=0.f;
  float q0=0.f,q1=0.f,q2=0.f,q3=0.f,q4=0.f,q5=0.f,q6=0.f,q7=0.f;

  #pragma unroll 1
  for (int it = 0; it < 2; it++){
    int v = base + it * 16 + grp;
    if (v < N){
      float a0=0.f,a1=0.f,a2=0.f,a3=0.f,a4=0.f,a5=0.f,a6=0.f,a7=0.f;
      ACC8(h16[(size_t)v * 16 + sl]);
      int e0 = rs[v], e1 = rs[v + 1];
      int i = e0;
      for (; i + 4 <= e1; i += 4){
        int sa = csr[i], sb = csr[i+1], sc = csr[i+2], sd = csr[i+3];
        uint4 m0 = h16[(size_t)sa * 16 + sl];
        uint4 m1 = h16[(size_t)sb * 16 + sl];
        uint4 m2 = h16[(size_t)sc * 16 + sl];
        uint4 m3 = h16[(size_t)sd * 16 + sl];
        ACC8(m0); ACC8(m1); ACC8(m2); ACC8(m3);
      }
      for (; i < e1; i++){
        ACC8(h16[(size_t)csr[i] * 16 + sl]);
      }
      float dv = dinv[v];
      a0*=dv; a1*=dv; a2*=dv; a3*=dv; a4*=dv; a5*=dv; a6*=dv; a7*=dv;
      uint4 o;
      o.x = (unsigned)f2bfbits(a0) | ((unsigned)f2bfbits(a1) << 16);
      o.y = (unsigned)f2bfbits(a2) | ((unsigned)f2bfbits(a3) << 16);
      o.z = (unsigned)f2bfbits(a4) | ((unsigned)f2bfbits(a5) << 16);
      o.w = (unsigned)f2bfbits(a6) | ((unsigned)f2bfbits(a7) << 16);
      ((uint4*)outb)[(size_t)v * 16 + sl] = o;
      s0+=a0; q0=fmaf(a0,a0,q0);  s1+=a1; q1=fmaf(a1,a1,q1);
      s2+=a2; q2=fmaf(a2,a2,q2);  s3+=a3; q3=fmaf(a3,a3,q3);
      s4+=a4; q4=fmaf(a4,a4,q4);  s5+=a5; q5=fmaf(a5,a5,q5);
      s6+=a6; q6=fmaf(a6,a6,q6);  s7+=a7; q7=fmaf(a7,a7,q7);
    }
  }

  __shared__ float shS[16][128], shQ[16][128];
  *(float4*)&shS[grp][sl * 8]     = make_float4(s0, s1, s2, s3);
  *(float4*)&shS[grp][sl * 8 + 4] = make_float4(s4, s5, s6, s7);
  *(float4*)&shQ[grp][sl * 8]     = make_float4(q0, q1, q2, q3);
  *(float4*)&shQ[grp][sl * 8 + 4] = make_float4(q4, q5, q6, q7);
  __syncthreads();
  int t = ty * 64 + threadIdx.x;
  if (t < 128){
    float ss = 0.f, qq = 0.f;
    #pragma unroll
    for (int g2 = 0; g2 < 16; g2++){ ss += shS[g2][t]; qq += shQ[g2][t]; }
    float* dstat = stats + (blockIdx.x & 15) * 256;
    atomicAdd(&dstat[t], ss);
    atomicAdd(&dstat[128 + t], qq);
  }
}

// ============ layer-3 agg (40 ch) + bias + log_softmax ============
// 4 nodes/wave: node = 16-lane group, lanes 0..9 hold uint2 (4 ch each).
__global__ __launch_bounds__(256) void k_agg40lsm(const unsigned short* __restrict__ hw,
                                                  const int* __restrict__ rs,
                                                  const int* __restrict__ csr,
                                                  const float* __restrict__ dinv,
                                                  const float* __restrict__ b3,
                                                  float* __restrict__ out, int N)
{
  const int l = threadIdx.x;
  const int ns = l >> 4, sl = l & 15;
  const int v = blockIdx.x * 16 + threadIdx.y * 4 + ns;
  const bool act = (v < N) && (sl < 10);
  const uint2* h2 = (const uint2*)hw;              // row = 10 uint2 (80 B)
  float a0 = 0.f, a1 = 0.f, a2 = 0.f, a3 = 0.f, dv = 1.f;
  if (act){
    dv = dinv[v];
    uint2 u = h2[(size_t)v * 10 + sl];
    a0 = bfbits2f((unsigned short)(u.x & 0xffffu));
    a1 = bfbits2f((unsigned short)(u.x >> 16));
    a2 = bfbits2f((unsigned short)(u.y & 0xffffu));
    a3 = bfbits2f((unsigned short)(u.y >> 16));
    int e0 = rs[v], e1 = rs[v + 1];
    int i = e0;
#define ACCU2(U) do{ uint2 _u = (U); \
    a0 += bfbits2f((unsigned short)(_u.x & 0xffffu)); \
    a1 += bfbits2f((unsigned short)(_u.x >> 16)); \
    a2 += bfbits2f((unsigned short)(_u.y & 0xffffu)); \
    a3 += bfbits2f((unsigned short)(_u.y >> 16)); }while(0)
    for (; i + 4 <= e1; i += 4){
      int sa = csr[i], sb = csr[i+1], sc = csr[i+2], sd = csr[i+3];
      uint2 m0 = h2[(size_t)sa * 10 + sl];
      uint2 m1 = h2[(size_t)sb * 10 + sl];
      uint2 m2 = h2[(size_t)sc * 10 + sl];
      uint2 m3 = h2[(size_t)sd * 10 + sl];
      ACCU2(m0); ACCU2(m1); ACCU2(m2); ACCU2(m3);
    }
    for (; i < e1; i++){
      ACCU2(h2[(size_t)csr[i] * 10 + sl]);
    }
#undef ACCU2
  }
  float x0 = act ? fmaf(a0, dv, b3[sl * 4 + 0]) : -INFINITY;
  float x1 = act ? fmaf(a1, dv, b3[sl * 4 + 1]) : -INFINITY;
  float x2 = act ? fmaf(a2, dv, b3[sl * 4 + 2]) : -INFINITY;
  float x3 = act ? fmaf(a3, dv, b3[sl * 4 + 3]) : -INFINITY;
  float m = fmaxf(fmaxf(x0, x1), fmaxf(x2, x3));
  #pragma unroll
  for (int off = 8; off; off >>= 1) m = fmaxf(m, __shfl_xor(m, off, 16));
  float e = act ? (expf(x0 - m) + expf(x1 - m) + expf(x2 - m) + expf(x3 - m)) : 0.f;
  #pragma unroll
  for (int off = 8; off; off >>= 1) e += __shfl_xor(e, off, 16);
  float lse = m + logf(e);
  if (act){
    float4 o;
    o.x = x0 - lse; o.y = x1 - lse; o.z = x2 - lse; o.w = x3 - lse;
    *reinterpret_cast<float4*>(out + (size_t)v * 40 + sl * 4) = o;
  }
}

// ================= launch =================
extern "C" void kernel_launch(void* const* d_in, const int* in_sizes, int n_in,
                              void* d_out, int out_size, void* d_ws, size_t ws_size,
                              hipStream_t stream)
{
  const float* x  = (const float*)d_in[0];
  const int* ei   = (const int*)d_in[1];
  const float* W1 = (const float*)d_in[2];
  const float* g1 = (const float*)d_in[4];
  const float* be1= (const float*)d_in[5];
  const float* W2 = (const float*)d_in[6];
  const float* g2 = (const float*)d_in[8];
  const float* be2= (const float*)d_in[9];
  const float* W3 = (const float*)d_in[10];
  const float* b3 = (const float*)d_in[11];
  float* out = (float*)d_out;
  // b1, b2 unused: per-channel constants cancel exactly in training-mode BN.

  const int N = in_sizes[0] / 128;
  const int E = in_sizes[1] / 2;
  const int* srcv = ei;
  const int* dstv = ei + E;

  char* ws = (char*)d_ws;
  size_t off = 0;
  auto take = [&](size_t bytes) -> void* {
    void* p = ws + off;
    off = (off + bytes + 255) & ~(size_t)255;
    return p;
  };
  int*   cnt      = (int*)  take((size_t)N * 4);
  int*   pos      = (int*)  take((size_t)E * 4);
  int*   rowstart = (int*)  take((size_t)(N + 1) * 4);
  int*   csr      = (int*)  take((size_t)E * 4);
  float* dinv     = (float*)take((size_t)N * 4);
  int*   bsum     = (int*)  take(256 * 4);
  int*   boff     = (int*)  take(256 * 4);
  float* stats1   = (float*)take(2 * 16 * 256 * 4);    // two banked stat sets
  float* stats2   = stats1 + 16 * 256;
  unsigned* mask1 = (unsigned*)take((size_t)N * 4 * 4);  // N*128 bits
  unsigned* mask2 = (unsigned*)take((size_t)N * 4 * 4);
  unsigned short* WT1 = (unsigned short*)take(128 * 128 * 2);
  unsigned short* WT2 = (unsigned short*)take(128 * 128 * 2);
  unsigned short* WT3 = (unsigned short*)take(48 * 128 * 2);
  unsigned short* bufX = (unsigned short*)take((size_t)N * 128 * 2);
  unsigned short* bufY = (unsigned short*)take((size_t)N * 128 * 2);
  (void)ws_size; (void)n_in; (void)out_size;

  // dropout subkeys: jax.random.split(key(42), 2), partitionable fold
  unsigned l1k0, l1k1, l2k0, l2k1;
  tf2x32(0u, 42u, 0u, 0u, l1k0, l1k1);
  tf2x32(0u, 42u, 0u, 1u, l2k0, l2k1);

  const float invN = 1.0f / (float)N;
  const int M = N * 4;                  // mask words (N*128/32)
  const int NB = (N + 1023) / 1024;
  dim3 wblk(64, 4);
  dim3 wgrid16((N + 15) / 16);
  dim3 wgrid32((N + 31) / 32);
  const int ggrid = (N + 63) / 64;
  const int egrid = (E + 1023) / 1024;

  // ---- graph structure ----
  hipMemsetAsync(cnt, 0, (size_t)N * 4, stream);
  hipMemsetAsync(stats1, 0, 2 * 16 * 256 * 4, stream);
  k_countpos<<<egrid, 256, 0, stream>>>(dstv, cnt, pos, E);
  k_blocksum<<<NB, 256, 0, stream>>>(cnt, bsum, N);
  k_scansums<<<1, 256, 0, stream>>>(bsum, boff, rowstart, NB, N);
  k_scanfinal<<<NB, 256, 0, stream>>>(cnt, boff, rowstart, dinv, N);
  k_fill<<<egrid, 256, 0, stream>>>(srcv, dstv, pos, rowstart, csr, E);
  k_wt<<<3, 256, 0, stream>>>(W1, W2, W3, WT1, WT2, WT3);

  // ---- layer 1 ----
  k_gemm_mfma<8, 0><<<ggrid, 256, 0, stream>>>(x, WT1, dinv,
      nullptr, nullptr, nullptr, nullptr, invN, bufX, N, 128);
  k_agg128s<<<wgrid32, wblk, 0, stream>>>(bufX, rowstart, csr, dinv, bufY, stats1,
      mask1, l1k0, l1k1, M, N);

  // ---- layer 2 (BN1+ReLU+dropout-mask fused into A staging) ----
  k_gemm_mfma<8, 2><<<ggrid, 256, 0, stream>>>(bufY, WT2, dinv,
      stats1, g1, be1, mask1, invN, bufX, N, 128);
  k_agg128s<<<wgrid32, wblk, 0, stream>>>(bufX, rowstart, csr, dinv, bufY, stats2,
      mask2, l2k0, l2k1, M, N);

  // ---- layer 3 (BN2+ReLU+dropout-mask fused) + log_softmax ----
  k_gemm_mfma<3, 2><<<ggrid, 256, 0, stream>>>(bufY, WT3, dinv,
      stats2, g2, be2, mask2, invN, bufX, N, 40);
  k_agg40lsm<<<wgrid16, wblk, 0, stream>>>(bufX, rowstart, csr, dinv, b3, out, N);
}